// Round 2
// baseline (12418.562 us; speedup 1.0000x reference)
//
#include <hip/hip_runtime.h>
#include <cstdint>
#include <cstddef>

#define DEV __device__ __forceinline__

static constexpr int NN = 15000;   // nodes
static constexpr int EE = 150000;  // edges
static constexpr int GG = 64;      // graphs

// ---- float <-> ordered uint (for atomicMax on float) ----
DEV unsigned f2o(float f) {
    unsigned u = __float_as_uint(f);
    return (u & 0x80000000u) ? ~u : (u | 0x80000000u);
}
DEV float o2f(unsigned o) {
    unsigned b = (o & 0x80000000u) ? (o & 0x7fffffffu) : ~o;
    return __uint_as_float(b);
}

// ======================= tiled fp32 GEMM =======================
// C[M,N] = A[M,K] @ B[K,N] (+bias) (+=C if ACCUM) (relu if RELU); ldc = C row stride.
// Requires: N % 64 == 0, K % 16 == 0. M guarded.
template <bool BIAS, bool RELU, bool ACCUM>
__global__ __launch_bounds__(256) void gemm64(const float* __restrict__ A,
                                              const float* __restrict__ B,
                                              const float* __restrict__ bias,
                                              float* __restrict__ C, int M, int N,
                                              int K, int ldc) {
    __shared__ float As[16][68];   // row stride 272B = 16*17 -> float4-aligned
    __shared__ float Bs[16][64];
    const int tid = threadIdx.x;
    const int tx = tid & 15, ty = tid >> 4;
    const int row0 = blockIdx.y * 64, col0 = blockIdx.x * 64;
    float acc[4][4] = {};
    for (int k0 = 0; k0 < K; k0 += 16) {
#pragma unroll
        for (int i = 0; i < 4; i++) {
            int idx = tid + i * 256;
            int r = idx >> 4, kk = idx & 15;
            int gr = row0 + r;
            As[kk][r] = (gr < M) ? A[(size_t)gr * K + k0 + kk] : 0.f;
        }
#pragma unroll
        for (int i = 0; i < 4; i++) {
            int idx = tid + i * 256;
            int kk = idx >> 6, c = idx & 63;
            Bs[kk][c] = B[(size_t)(k0 + kk) * N + col0 + c];
        }
        __syncthreads();
#pragma unroll
        for (int kk = 0; kk < 16; kk++) {
            float4 av = *(const float4*)&As[kk][ty * 4];
            float4 bv = *(const float4*)&Bs[kk][tx * 4];
            float a[4] = {av.x, av.y, av.z, av.w};
            float b[4] = {bv.x, bv.y, bv.z, bv.w};
#pragma unroll
            for (int i = 0; i < 4; i++)
#pragma unroll
                for (int j = 0; j < 4; j++) acc[i][j] = fmaf(a[i], b[j], acc[i][j]);
        }
        __syncthreads();
    }
#pragma unroll
    for (int i = 0; i < 4; i++) {
        int gr = row0 + ty * 4 + i;
        if (gr >= M) continue;
#pragma unroll
        for (int j = 0; j < 4; j++) {
            int gc = col0 + tx * 4 + j;
            float v = acc[i][j];
            if constexpr (BIAS) v += bias[gc];
            if constexpr (ACCUM) v += C[(size_t)gr * ldc + gc];
            if constexpr (RELU) v = fmaxf(v, 0.f);
            C[(size_t)gr * ldc + gc] = v;
        }
    }
}

// ============ build block-diagonal expansion matrices from We ============
// Wu[D][64]: Wu[d][h'*16+f] = (head(d)==h') ? We[f][d] : 0   (U = q @ Wu)
template <int D, int C>
__global__ void build_wu(const float* __restrict__ We, float* __restrict__ Wu) {
    int i = blockIdx.x * 256 + threadIdx.x;
    if (i >= D * 64) return;
    int d = i >> 6, hf = i & 63;
    int hp = hf >> 4, f = hf & 15;
    int h = d / C;
    Wu[i] = (h == hp) ? We[(size_t)f * D + d] : 0.f;
}
// Wt[64][D]: Wt[h'*16+f][d] = (head(d)==h') ? We[f][d] : 0   (h += T @ Wt)
template <int D, int C>
__global__ void build_wt(const float* __restrict__ We, float* __restrict__ Wt) {
    int i = blockIdx.x * 256 + threadIdx.x;
    if (i >= 64 * D) return;
    int hf = i / D, d = i - hf * D;
    int hp = hf >> 4, f = hf & 15;
    int h = d / C;
    Wt[i] = (h == hp) ? We[(size_t)f * D + d] : 0.f;
}

// ======================= edge kernels =======================
// One 64-lane wave per edge. Channel layout [H=4][C]; lane group (lane>>4) = head.
// alpha[e,h] = (q[dst]·k[src] |_h + sum_f ea[e,f]*U[dst,h,f]) / sqrt(C)
template <int C>
__global__ __launch_bounds__(256) void edge_alpha(
    const float* __restrict__ q, const float* __restrict__ k,
    const float* __restrict__ U, const float* __restrict__ ea,
    const int* __restrict__ src, const int* __restrict__ dst,
    float* __restrict__ alpha, unsigned* __restrict__ amax, int E) {
    constexpr int D = 4 * C;
    constexpr int P = D / 64;
    int w = (blockIdx.x * 256 + threadIdx.x) >> 6;
    int lane = threadIdx.x & 63;
    if (w >= E) return;
    int s = src[w], d = dst[w];
    // lane acts as (h = lane>>4, f = lane&15) for the edge-feature term
    float val = ea[(size_t)w * 16 + (lane & 15)] * U[(size_t)d * 64 + lane];
    const float* qr = q + (size_t)d * D + lane * P;
    const float* kr = k + (size_t)s * D + lane * P;
#pragma unroll
    for (int j0 = 0; j0 < P; j0 += 4) {
        float4 qv = *(const float4*)(qr + j0);
        float4 kv = *(const float4*)(kr + j0);
        val = fmaf(qv.x, kv.x, val);
        val = fmaf(qv.y, kv.y, val);
        val = fmaf(qv.z, kv.z, val);
        val = fmaf(qv.w, kv.w, val);
    }
#pragma unroll
    for (int off = 1; off < 16; off <<= 1) val += __shfl_xor(val, off);
    val *= rsqrtf((float)C);
    if ((lane & 15) == 0) {
        int h = lane >> 4;
        alpha[(size_t)w * 4 + h] = val;
        atomicMax(&amax[(size_t)d * 4 + h], f2o(val));
    }
}

// ex = exp(alpha - amax[dst]); den[dst] += ex  (alpha overwritten with ex)
__global__ __launch_bounds__(256) void edge_softmax(float* __restrict__ alpha,
                                                    const unsigned* __restrict__ amax,
                                                    float* __restrict__ den,
                                                    const int* __restrict__ dst, int E) {
    int i = blockIdx.x * 256 + threadIdx.x;
    if (i >= E * 4) return;
    int e = i >> 2, h = i & 3;
    int d = dst[e];
    float am = o2f(amax[(size_t)d * 4 + h]);
    float ex = expf(alpha[i] - am);
    alpha[i] = ex;
    atomicAdd(&den[(size_t)d * 4 + h], ex);
}

// scatter: h[dst] += a * v[src];  T[dst,h,f] += a * ea[e,f]
template <int C>
__global__ __launch_bounds__(256) void edge_scatter(
    const float* __restrict__ v, const float* __restrict__ exv,
    const float* __restrict__ den, const float* __restrict__ ea,
    const int* __restrict__ src, const int* __restrict__ dst,
    float* __restrict__ hout, float* __restrict__ T, int E) {
    constexpr int D = 4 * C;
    constexpr int P = D / 64;
    int w = (blockIdx.x * 256 + threadIdx.x) >> 6;
    int lane = threadIdx.x & 63;
    if (w >= E) return;
    int s = src[w], d = dst[w];
    int h = lane >> 4;
    float a = exv[(size_t)w * 4 + h] / (den[(size_t)d * 4 + h] + 1e-16f);
    atomicAdd(&T[(size_t)d * 64 + lane], a * ea[(size_t)w * 16 + (lane & 15)]);
    const float* vr = v + (size_t)s * D + lane * P;
    float* hr = hout + (size_t)d * D + lane * P;
#pragma unroll
    for (int j = 0; j < P; j++) atomicAdd(&hr[j], a * vr[j]);
}

// ======================= batch norm =======================
__global__ __launch_bounds__(256) void bn_stats(const float* __restrict__ h,
                                                float* __restrict__ s1,
                                                float* __restrict__ s2, int Nrows,
                                                int D) {
    int col = blockIdx.x * 256 + threadIdx.x;
    int chunk = (Nrows + gridDim.y - 1) / gridDim.y;
    int r0 = blockIdx.y * chunk;
    int r1 = min(r0 + chunk, Nrows);
    float a = 0.f, b = 0.f;
    for (int r = r0; r < r1; r++) {
        float v = h[(size_t)r * D + col];
        a += v;
        b += v * v;
    }
    atomicAdd(&s1[col], a);
    atomicAdd(&s2[col], b);
}
__global__ void bn_finalize(float* __restrict__ s1, float* __restrict__ s2,
                            const float* __restrict__ g, const float* __restrict__ b,
                            int Nrows, int D) {
    int c = blockIdx.x * 256 + threadIdx.x;
    if (c >= D) return;
    float mean = s1[c] / (float)Nrows;
    float var = fmaxf(s2[c] / (float)Nrows - mean * mean, 0.f);
    float scale = g[c] / sqrtf(var + 1e-5f);
    s1[c] = scale;
    s2[c] = b[c] - mean * scale;
}
__global__ __launch_bounds__(256) void bn_apply_relu(float* __restrict__ h,
                                                     const float* __restrict__ scale,
                                                     const float* __restrict__ shift,
                                                     int total4, int D) {
    int i = blockIdx.x * 256 + threadIdx.x;
    if (i >= total4) return;
    float4 v = ((float4*)h)[i];
    int c = (i * 4) % D;
    v.x = fmaxf(fmaf(v.x, scale[c], shift[c]), 0.f);
    v.y = fmaxf(fmaf(v.y, scale[c + 1], shift[c + 1]), 0.f);
    v.z = fmaxf(fmaf(v.z, scale[c + 2], shift[c + 2]), 0.f);
    v.w = fmaxf(fmaf(v.w, scale[c + 3], shift[c + 3]), 0.f);
    ((float4*)h)[i] = v;
}

// ======================= pooling (batch is sorted) =======================
__global__ __launch_bounds__(256) void pool_kernel(const float* __restrict__ h,
                                                   const int* __restrict__ batch,
                                                   float* __restrict__ z, int Nrows,
                                                   int D, int ldz) {
    int g = blockIdx.y;
    int c = blockIdx.x * 256 + threadIdx.x;
    int lo = 0, hi = Nrows;
    while (lo < hi) {
        int m = (lo + hi) >> 1;
        if (batch[m] < g) lo = m + 1; else hi = m;
    }
    int s0 = lo;
    hi = Nrows;
    while (lo < hi) {
        int m = (lo + hi) >> 1;
        if (batch[m] < g + 1) lo = m + 1; else hi = m;
    }
    int s1 = lo;
    float sum = 0.f, mx = -3.402823466e38f;
    for (int r = s0; r < s1; r++) {
        float v = h[(size_t)r * D + c];
        sum += v;
        mx = fmaxf(mx, v);
    }
    int cnt = s1 - s0;
    z[(size_t)g * ldz + c] = sum / (float)max(cnt, 1);
    z[(size_t)g * ldz + D + c] = (cnt > 0) ? mx : 0.f;
}

// ======================= tiny MLP head =======================
__global__ __launch_bounds__(128) void bn_small_apply(const float* __restrict__ y,
                                                      const float* __restrict__ g,
                                                      const float* __restrict__ b,
                                                      float* __restrict__ y2) {
    int c = threadIdx.x;  // 128 columns
    float m = 0.f;
    for (int r = 0; r < 64; r++) m += y[r * 128 + c];
    m *= (1.f / 64.f);
    float v = 0.f;
    for (int r = 0; r < 64; r++) {
        float d = y[r * 128 + c] - m;
        v += d * d;
    }
    v *= (1.f / 64.f);
    float sc = g[c] / sqrtf(v + 1e-5f);
    float sh = b[c] - m * sc;
    for (int r = 0; r < 64; r++) y2[r * 128 + c] = fmaxf(fmaf(y[r * 128 + c], sc, sh), 0.f);
}
__global__ __launch_bounds__(128) void fc2_small(const float* __restrict__ y2,
                                                 const float* __restrict__ W,
                                                 const float* __restrict__ b,
                                                 float* __restrict__ out) {
    int t = threadIdx.x;
    int g = t >> 1, o = t & 1;
    float s = b[o];
    for (int kk = 0; kk < 128; kk++) s = fmaf(y2[g * 128 + kk], W[kk * 2 + o], s);
    out[g * 2 + o] = s;
}

// ======================= launch =======================
extern "C" void kernel_launch(void* const* d_in, const int* in_sizes, int n_in,
                              void* d_out, int out_size, void* d_ws, size_t ws_size,
                              hipStream_t stream) {
    const float* x     = (const float*)d_in[0];
    const float* ea    = (const float*)d_in[1];
    const float* sol   = (const float*)d_in[2];
    const int*   eidx  = (const int*)d_in[3];
    const int*   batch = (const int*)d_in[4];
    const float* Wq1 = (const float*)d_in[5];  const float* bq1 = (const float*)d_in[6];
    const float* Wk1 = (const float*)d_in[7];  const float* bk1 = (const float*)d_in[8];
    const float* Wv1 = (const float*)d_in[9];  const float* bv1 = (const float*)d_in[10];
    const float* We1 = (const float*)d_in[11];
    const float* Ws1 = (const float*)d_in[12]; const float* bs1 = (const float*)d_in[13];
    const float* g1  = (const float*)d_in[14]; const float* be1 = (const float*)d_in[15];
    const float* Wq2 = (const float*)d_in[16]; const float* bq2 = (const float*)d_in[17];
    const float* Wk2 = (const float*)d_in[18]; const float* bk2 = (const float*)d_in[19];
    const float* Wv2 = (const float*)d_in[20]; const float* bv2 = (const float*)d_in[21];
    const float* We2 = (const float*)d_in[22];
    const float* Ws2 = (const float*)d_in[23]; const float* bs2 = (const float*)d_in[24];
    const float* g2  = (const float*)d_in[25]; const float* be2 = (const float*)d_in[26];
    const float* Wsol = (const float*)d_in[27]; const float* bsol = (const float*)d_in[28];
    const float* Wfc1 = (const float*)d_in[29]; const float* bfc1 = (const float*)d_in[30];
    const float* gf   = (const float*)d_in[31]; const float* bf = (const float*)d_in[32];
    const float* Wfc2 = (const float*)d_in[33]; const float* bfc2 = (const float*)d_in[34];

    const int* srcp = eidx;
    const int* dstp = eidx + EE;

    // ---------------- workspace layout (tight aliasing; peak ~165 MB) -------
    char* p = (char*)d_ws;
    auto alloc = [&](size_t bytes) -> char* {
        char* r = p;
        p += (bytes + 255) & ~(size_t)255;
        return r;
    };
    const size_t NB512  = (size_t)NN * 512 * 4;
    const size_t NB1024 = (size_t)NN * 1024 * 4;

    float* bufH = (float*)alloc(NB512);    // h1
    float* bufA = (float*)alloc(NB1024);   // q1 -> v1 -> q2 -> v2
    float* bufB = (float*)alloc(NB1024);   // k1 -> k2 -> h2
    // shared aux (re-zeroed between layers)
    float* U     = (float*)alloc((size_t)NN * 64 * 4);
    float* T     = (float*)alloc((size_t)NN * 64 * 4);
    float* alpha = (float*)alloc((size_t)EE * 4 * 4);
    unsigned* amax = (unsigned*)alloc((size_t)NN * 4 * 4);
    float* den   = (float*)alloc((size_t)NN * 4 * 4);
    float* Wu    = (float*)alloc((size_t)1024 * 64 * 4);
    float* Wt    = (float*)alloc((size_t)64 * 1024 * 4);
    float* bnA   = (float*)alloc(1024 * 4);
    float* bnB   = (float*)alloc(1024 * 4);
    float* z  = (float*)alloc((size_t)64 * 2176 * 4);
    float* y  = (float*)alloc((size_t)64 * 128 * 4);
    float* y2 = (float*)alloc((size_t)64 * 128 * 4);

    // refuse to run rather than fault if workspace is too small
    if ((size_t)(p - (char*)d_ws) > ws_size) return;

    float* h1 = bufH;
    float* h2 = bufB;

    const int GR = (NN + 63) / 64;  // 235 row-tiles
    dim3 blk(256);

    // ---------------- layer 1 (D=512, C=128) ----------------
    hipMemsetAsync(amax, 0, (size_t)NN * 4 * 4, stream);
    hipMemsetAsync(den, 0, (size_t)NN * 4 * 4, stream);
    hipMemsetAsync(T, 0, (size_t)NN * 64 * 4, stream);
    hipMemsetAsync(bnA, 0, 1024 * 4, stream);
    hipMemsetAsync(bnB, 0, 1024 * 4, stream);

    build_wu<512, 128><<<(512 * 64 + 255) / 256, blk, 0, stream>>>(We1, Wu);
    gemm64<true, false, false><<<dim3(8, GR), blk, 0, stream>>>(x, Wq1, bq1, bufA, NN, 512, 64, 512); // q1
    gemm64<true, false, false><<<dim3(8, GR), blk, 0, stream>>>(x, Wk1, bk1, bufB, NN, 512, 64, 512); // k1
    gemm64<false, false, false><<<dim3(1, GR), blk, 0, stream>>>(bufA, Wu, nullptr, U, NN, 64, 512, 64);
    edge_alpha<128><<<EE / 4, blk, 0, stream>>>(bufA, bufB, U, ea, srcp, dstp, alpha, amax, EE);
    edge_softmax<<<(EE * 4 + 255) / 256, blk, 0, stream>>>(alpha, amax, den, dstp, EE);
    gemm64<true, false, false><<<dim3(8, GR), blk, 0, stream>>>(x, Wv1, bv1, bufA, NN, 512, 64, 512); // v1 (q1 dead)
    gemm64<true, false, false><<<dim3(8, GR), blk, 0, stream>>>(x, Ws1, bs1, h1, NN, 512, 64, 512);   // skip
    edge_scatter<128><<<EE / 4, blk, 0, stream>>>(bufA, alpha, den, ea, srcp, dstp, h1, T, EE);
    build_wt<512, 128><<<(64 * 512 + 255) / 256, blk, 0, stream>>>(We1, Wt);
    gemm64<false, false, true><<<dim3(8, GR), blk, 0, stream>>>(T, Wt, nullptr, h1, NN, 512, 64, 512);
    bn_stats<<<dim3(2, 64), blk, 0, stream>>>(h1, bnA, bnB, NN, 512);
    bn_finalize<<<2, blk, 0, stream>>>(bnA, bnB, g1, be1, NN, 512);
    bn_apply_relu<<<NN * 512 / 4 / 256, blk, 0, stream>>>(h1, bnA, bnB, NN * 512 / 4, 512);

    // ---------------- layer 2 (D=1024, C=256) ----------------
    hipMemsetAsync(amax, 0, (size_t)NN * 4 * 4, stream);
    hipMemsetAsync(den, 0, (size_t)NN * 4 * 4, stream);
    hipMemsetAsync(T, 0, (size_t)NN * 64 * 4, stream);
    hipMemsetAsync(bnA, 0, 1024 * 4, stream);
    hipMemsetAsync(bnB, 0, 1024 * 4, stream);

    build_wu<1024, 256><<<(1024 * 64 + 255) / 256, blk, 0, stream>>>(We2, Wu);
    gemm64<true, false, false><<<dim3(16, GR), blk, 0, stream>>>(h1, Wq2, bq2, bufA, NN, 1024, 512, 1024); // q2
    gemm64<true, false, false><<<dim3(16, GR), blk, 0, stream>>>(h1, Wk2, bk2, bufB, NN, 1024, 512, 1024); // k2
    gemm64<false, false, false><<<dim3(1, GR), blk, 0, stream>>>(bufA, Wu, nullptr, U, NN, 64, 1024, 64);
    edge_alpha<256><<<EE / 4, blk, 0, stream>>>(bufA, bufB, U, ea, srcp, dstp, alpha, amax, EE);
    edge_softmax<<<(EE * 4 + 255) / 256, blk, 0, stream>>>(alpha, amax, den, dstp, EE);
    gemm64<true, false, false><<<dim3(16, GR), blk, 0, stream>>>(h1, Wv2, bv2, bufA, NN, 1024, 512, 1024); // v2 (q2 dead)
    gemm64<true, false, false><<<dim3(16, GR), blk, 0, stream>>>(h1, Ws2, bs2, h2, NN, 1024, 512, 1024);   // skip (k2 dead)
    edge_scatter<256><<<EE / 4, blk, 0, stream>>>(bufA, alpha, den, ea, srcp, dstp, h2, T, EE);
    build_wt<1024, 256><<<(64 * 1024 + 255) / 256, blk, 0, stream>>>(We2, Wt);
    gemm64<false, false, true><<<dim3(16, GR), blk, 0, stream>>>(T, Wt, nullptr, h2, NN, 1024, 64, 1024);
    bn_stats<<<dim3(4, 64), blk, 0, stream>>>(h2, bnA, bnB, NN, 1024);
    bn_finalize<<<4, blk, 0, stream>>>(bnA, bnB, g2, be2, NN, 1024);
    bn_apply_relu<<<NN * 1024 / 4 / 256, blk, 0, stream>>>(h2, bnA, bnB, NN * 1024 / 4, 1024);

    // ---------------- head ----------------
    pool_kernel<<<dim3(4, 64), blk, 0, stream>>>(h2, batch, z, NN, 1024, 2176);
    gemm64<true, true, false><<<dim3(2, 1), blk, 0, stream>>>(sol, Wsol, bsol, z + 2048, 64, 128, 128, 2176);
    gemm64<true, false, false><<<dim3(2, 1), blk, 0, stream>>>(z, Wfc1, bfc1, y, 64, 128, 2176, 128);
    bn_small_apply<<<1, 128, 0, stream>>>(y, gf, bf, y2);
    fc2_small<<<1, 128, 0, stream>>>(y2, Wfc2, bfc2, (float*)d_out);
}

// Round 4
// 2192.856 us; speedup vs baseline: 5.6632x; 5.6632x over previous
//
#include <hip/hip_runtime.h>
#include <cstdint>
#include <cstddef>

#define DEV __device__ __forceinline__

static constexpr int NN = 15000;   // nodes
static constexpr int EE = 150000;  // edges
static constexpr int GG = 64;      // graphs

// ======================= tiled fp32 GEMM =======================
// C[M,N] = A[M,K] @ B[K,N] (+bias) (+=C if ACCUM) (relu if RELU); ldc = C row stride.
// Requires: N % 64 == 0, K % 16 == 0. M guarded.
template <bool BIAS, bool RELU, bool ACCUM>
__global__ __launch_bounds__(256) void gemm64(const float* __restrict__ A,
                                              const float* __restrict__ B,
                                              const float* __restrict__ bias,
                                              float* __restrict__ C, int M, int N,
                                              int K, int ldc) {
    __shared__ float As[16][68];   // row stride 272B = 16*17 -> float4-aligned
    __shared__ float Bs[16][64];
    const int tid = threadIdx.x;
    const int tx = tid & 15, ty = tid >> 4;
    const int row0 = blockIdx.y * 64, col0 = blockIdx.x * 64;
    float acc[4][4] = {};
    for (int k0 = 0; k0 < K; k0 += 16) {
#pragma unroll
        for (int i = 0; i < 4; i++) {
            int idx = tid + i * 256;
            int r = idx >> 4, kk = idx & 15;
            int gr = row0 + r;
            As[kk][r] = (gr < M) ? A[(size_t)gr * K + k0 + kk] : 0.f;
        }
#pragma unroll
        for (int i = 0; i < 4; i++) {
            int idx = tid + i * 256;
            int kk = idx >> 6, c = idx & 63;
            Bs[kk][c] = B[(size_t)(k0 + kk) * N + col0 + c];
        }
        __syncthreads();
#pragma unroll
        for (int kk = 0; kk < 16; kk++) {
            float4 av = *(const float4*)&As[kk][ty * 4];
            float4 bv = *(const float4*)&Bs[kk][tx * 4];
            float a[4] = {av.x, av.y, av.z, av.w};
            float b[4] = {bv.x, bv.y, bv.z, bv.w};
#pragma unroll
            for (int i = 0; i < 4; i++)
#pragma unroll
                for (int j = 0; j < 4; j++) acc[i][j] = fmaf(a[i], b[j], acc[i][j]);
        }
        __syncthreads();
    }
#pragma unroll
    for (int i = 0; i < 4; i++) {
        int gr = row0 + ty * 4 + i;
        if (gr >= M) continue;
#pragma unroll
        for (int j = 0; j < 4; j++) {
            int gc = col0 + tx * 4 + j;
            float v = acc[i][j];
            if constexpr (BIAS) v += bias[gc];
            if constexpr (ACCUM) v += C[(size_t)gr * ldc + gc];
            if constexpr (RELU) v = fmaxf(v, 0.f);
            C[(size_t)gr * ldc + gc] = v;
        }
    }
}

// ============ build block-diagonal expansion matrices from We ============
// Wu[D][64]: Wu[d][h'*16+f] = (head(d)==h') ? We[f][d] : 0   (U = q @ Wu)
template <int D, int C>
__global__ void build_wu(const float* __restrict__ We, float* __restrict__ Wu) {
    int i = blockIdx.x * 256 + threadIdx.x;
    if (i >= D * 64) return;
    int d = i >> 6, hf = i & 63;
    int hp = hf >> 4, f = hf & 15;
    int h = d / C;
    Wu[i] = (h == hp) ? We[(size_t)f * D + d] : 0.f;
}
// Wt[64][D]: Wt[h'*16+f][d] = (head(d)==h') ? We[f][d] : 0   (h += T @ Wt)
template <int D, int C>
__global__ void build_wt(const float* __restrict__ We, float* __restrict__ Wt) {
    int i = blockIdx.x * 256 + threadIdx.x;
    if (i >= 64 * D) return;
    int hf = i / D, d = i - hf * D;
    int hp = hf >> 4, f = hf & 15;
    int h = d / C;
    Wt[i] = (h == hp) ? We[(size_t)f * D + d] : 0.f;
}

// ======================= CSR build (by dst) =======================
__global__ __launch_bounds__(256) void count_deg(const int* __restrict__ dst,
                                                 int* __restrict__ deg, int E) {
    int e = blockIdx.x * 256 + threadIdx.x;
    if (e < E) atomicAdd(&deg[dst[e]], 1);
}

__global__ __launch_bounds__(1024) void scan_deg(const int* __restrict__ deg,
                                                 int* __restrict__ rs,
                                                 int* __restrict__ cursor, int n) {
    __shared__ int part[1024];
    int t = threadIdx.x;
    int ch = (n + 1023) / 1024;
    int b0 = min(t * ch, n), b1 = min(b0 + ch, n);
    int s = 0;
    for (int i = b0; i < b1; i++) s += deg[i];
    part[t] = s;
    __syncthreads();
    for (int off = 1; off < 1024; off <<= 1) {
        int tmp = (t >= off) ? part[t - off] : 0;
        __syncthreads();
        part[t] += tmp;
        __syncthreads();
    }
    int run = part[t] - s;  // exclusive prefix of this thread's chunk
    for (int i = b0; i < b1; i++) {
        rs[i] = run;
        cursor[i] = run;
        run += deg[i];
    }
    if (t == 1023) rs[n] = part[1023];
}

__global__ __launch_bounds__(256) void fill_csr(const int* __restrict__ dst,
                                                int* __restrict__ cursor,
                                                int* __restrict__ eids, int E) {
    int e = blockIdx.x * 256 + threadIdx.x;
    if (e < E) {
        int pos = atomicAdd(&cursor[dst[e]], 1);
        eids[pos] = e;
    }
}

// ======================= per-node attention (no atomics) =======================
// One 64-lane wave per dst node. Channel layout [H=4][C]; lane covers channels
// [lane*P, lane*P+P), head = lane>>4. Lane also acts as (h=lane>>4, f=lane&15)
// for the 64-wide edge-feature terms.
// Pass A: alpha[e,h] = (q[dst].k[src]|_h + sum_f ea[e,f]*U[dst,h,f]) / sqrt(C);
//         fused softmax -> ab[slot] = exp(alpha - max), den[node,h] = sum.
template <int C>
__global__ __launch_bounds__(256) void node_alpha(
    const float* __restrict__ q, const float* __restrict__ k,
    const float* __restrict__ U, const float* __restrict__ ea,
    const int* __restrict__ src, const int* __restrict__ rs,
    const int* __restrict__ eids, float* __restrict__ ab,
    float* __restrict__ den, int Nn) {
    constexpr int D = 4 * C;
    constexpr int P = D / 64;
    int node = (blockIdx.x * 256 + threadIdx.x) >> 6;
    int lane = threadIdx.x & 63;
    if (node >= Nn) return;
    int e0 = rs[node], e1 = rs[node + 1];
    float qr[P];
    const float* qp = q + (size_t)node * D + lane * P;
#pragma unroll
    for (int j = 0; j < P; j += 4) {
        float4 t4 = *(const float4*)(qp + j);
        qr[j] = t4.x; qr[j + 1] = t4.y; qr[j + 2] = t4.z; qr[j + 3] = t4.w;
    }
    float Urow = U[(size_t)node * 64 + lane];
    const float rsC = rsqrtf((float)C);
    float m = -3.402823466e38f;
    for (int ii = e0; ii < e1; ii++) {
        int e = eids[ii];
        int s = src[e];
        float val = ea[(size_t)e * 16 + (lane & 15)] * Urow;
        const float* kp = k + (size_t)s * D + lane * P;
#pragma unroll
        for (int j = 0; j < P; j += 4) {
            float4 t4 = *(const float4*)(kp + j);
            val = fmaf(qr[j], t4.x, val);
            val = fmaf(qr[j + 1], t4.y, val);
            val = fmaf(qr[j + 2], t4.z, val);
            val = fmaf(qr[j + 3], t4.w, val);
        }
#pragma unroll
        for (int off = 1; off < 16; off <<= 1) val += __shfl_xor(val, off);
        val *= rsC;
        if ((lane & 15) == 0) ab[(size_t)ii * 4 + (lane >> 4)] = val;
        m = fmaxf(m, val);
    }
    float dsum = 0.f;
    for (int ii = e0; ii < e1; ii++) {
        float a = ab[(size_t)ii * 4 + (lane >> 4)];
        float ex = __expf(a - m);
        dsum += ex;
        if ((lane & 15) == 0) ab[(size_t)ii * 4 + (lane >> 4)] = ex;
    }
    if ((lane & 15) == 0) den[(size_t)node * 4 + (lane >> 4)] = dsum;
}

// Pass B: h[node] += (sum_e ex*v[src]) / den;  T[node] = (sum_e ex*ea) / den
template <int C>
__global__ __launch_bounds__(256) void node_scatter(
    const float* __restrict__ v, const float* __restrict__ ea,
    const int* __restrict__ src, const int* __restrict__ rs,
    const int* __restrict__ eids, const float* __restrict__ ab,
    const float* __restrict__ den, float* __restrict__ hout,
    float* __restrict__ T, int Nn) {
    constexpr int D = 4 * C;
    constexpr int P = D / 64;
    int node = (blockIdx.x * 256 + threadIdx.x) >> 6;
    int lane = threadIdx.x & 63;
    if (node >= Nn) return;
    int e0 = rs[node], e1 = rs[node + 1];
    float acc[P] = {};
    float tacc = 0.f;
    for (int ii = e0; ii < e1; ii++) {
        int e = eids[ii];
        int s = src[e];
        float ex = ab[(size_t)ii * 4 + (lane >> 4)];
        tacc = fmaf(ex, ea[(size_t)e * 16 + (lane & 15)], tacc);
        const float* vp = v + (size_t)s * D + lane * P;
#pragma unroll
        for (int j = 0; j < P; j += 4) {
            float4 t4 = *(const float4*)(vp + j);
            acc[j] = fmaf(ex, t4.x, acc[j]);
            acc[j + 1] = fmaf(ex, t4.y, acc[j + 1]);
            acc[j + 2] = fmaf(ex, t4.z, acc[j + 2]);
            acc[j + 3] = fmaf(ex, t4.w, acc[j + 3]);
        }
    }
    float inv = 1.f / (den[(size_t)node * 4 + (lane >> 4)] + 1e-16f);
    T[(size_t)node * 64 + lane] = tacc * inv;
    float* hp = hout + (size_t)node * D + lane * P;
#pragma unroll
    for (int j = 0; j < P; j += 4) {
        float4 t4 = *(float4*)(hp + j);
        t4.x = fmaf(acc[j], inv, t4.x);
        t4.y = fmaf(acc[j + 1], inv, t4.y);
        t4.z = fmaf(acc[j + 2], inv, t4.z);
        t4.w = fmaf(acc[j + 3], inv, t4.w);
        *(float4*)(hp + j) = t4;
    }
}

// ======================= batch norm =======================
__global__ __launch_bounds__(256) void bn_stats(const float* __restrict__ h,
                                                float* __restrict__ s1,
                                                float* __restrict__ s2, int Nrows,
                                                int D) {
    int col = blockIdx.x * 256 + threadIdx.x;
    int chunk = (Nrows + gridDim.y - 1) / gridDim.y;
    int r0 = blockIdx.y * chunk;
    int r1 = min(r0 + chunk, Nrows);
    float a = 0.f, b = 0.f;
    for (int r = r0; r < r1; r++) {
        float v = h[(size_t)r * D + col];
        a += v;
        b += v * v;
    }
    atomicAdd(&s1[col], a);
    atomicAdd(&s2[col], b);
}
__global__ void bn_finalize(float* __restrict__ s1, float* __restrict__ s2,
                            const float* __restrict__ g, const float* __restrict__ b,
                            int Nrows, int D) {
    int c = blockIdx.x * 256 + threadIdx.x;
    if (c >= D) return;
    float mean = s1[c] / (float)Nrows;
    float var = fmaxf(s2[c] / (float)Nrows - mean * mean, 0.f);
    float scale = g[c] / sqrtf(var + 1e-5f);
    s1[c] = scale;
    s2[c] = b[c] - mean * scale;
}
__global__ __launch_bounds__(256) void bn_apply_relu(float* __restrict__ h,
                                                     const float* __restrict__ scale,
                                                     const float* __restrict__ shift,
                                                     int total4, int D) {
    int i = blockIdx.x * 256 + threadIdx.x;
    if (i >= total4) return;
    float4 v = ((float4*)h)[i];
    int c = (i * 4) % D;
    v.x = fmaxf(fmaf(v.x, scale[c], shift[c]), 0.f);
    v.y = fmaxf(fmaf(v.y, scale[c + 1], shift[c + 1]), 0.f);
    v.z = fmaxf(fmaf(v.z, scale[c + 2], shift[c + 2]), 0.f);
    v.w = fmaxf(fmaf(v.w, scale[c + 3], shift[c + 3]), 0.f);
    ((float4*)h)[i] = v;
}

// ======================= pooling (batch is sorted) =======================
__global__ __launch_bounds__(256) void pool_kernel(const float* __restrict__ h,
                                                   const int* __restrict__ batch,
                                                   float* __restrict__ z, int Nrows,
                                                   int D, int ldz) {
    int g = blockIdx.y;
    int c = blockIdx.x * 256 + threadIdx.x;
    int lo = 0, hi = Nrows;
    while (lo < hi) {
        int m = (lo + hi) >> 1;
        if (batch[m] < g) lo = m + 1; else hi = m;
    }
    int s0 = lo;
    hi = Nrows;
    while (lo < hi) {
        int m = (lo + hi) >> 1;
        if (batch[m] < g + 1) lo = m + 1; else hi = m;
    }
    int s1 = lo;
    float sum = 0.f, mx = -3.402823466e38f;
    for (int r = s0; r < s1; r++) {
        float v = h[(size_t)r * D + c];
        sum += v;
        mx = fmaxf(mx, v);
    }
    int cnt = s1 - s0;
    z[(size_t)g * ldz + c] = sum / (float)max(cnt, 1);
    z[(size_t)g * ldz + D + c] = (cnt > 0) ? mx : 0.f;
}

// ======================= tiny MLP head =======================
__global__ __launch_bounds__(128) void bn_small_apply(const float* __restrict__ y,
                                                      const float* __restrict__ g,
                                                      const float* __restrict__ b,
                                                      float* __restrict__ y2) {
    int c = threadIdx.x;  // 128 columns
    float m = 0.f;
    for (int r = 0; r < 64; r++) m += y[r * 128 + c];
    m *= (1.f / 64.f);
    float v = 0.f;
    for (int r = 0; r < 64; r++) {
        float d = y[r * 128 + c] - m;
        v += d * d;
    }
    v *= (1.f / 64.f);
    float sc = g[c] / sqrtf(v + 1e-5f);
    float sh = b[c] - m * sc;
    for (int r = 0; r < 64; r++) y2[r * 128 + c] = fmaxf(fmaf(y[r * 128 + c], sc, sh), 0.f);
}
__global__ __launch_bounds__(128) void fc2_small(const float* __restrict__ y2,
                                                 const float* __restrict__ W,
                                                 const float* __restrict__ b,
                                                 float* __restrict__ out) {
    int t = threadIdx.x;
    int g = t >> 1, o = t & 1;
    float s = b[o];
    for (int kk = 0; kk < 128; kk++) s = fmaf(y2[g * 128 + kk], W[kk * 2 + o], s);
    out[g * 2 + o] = s;
}

// ======================= launch =======================
extern "C" void kernel_launch(void* const* d_in, const int* in_sizes, int n_in,
                              void* d_out, int out_size, void* d_ws, size_t ws_size,
                              hipStream_t stream) {
    const float* x     = (const float*)d_in[0];
    const float* ea    = (const float*)d_in[1];
    const float* sol   = (const float*)d_in[2];
    const int*   eidx  = (const int*)d_in[3];
    const int*   batch = (const int*)d_in[4];
    const float* Wq1 = (const float*)d_in[5];  const float* bq1 = (const float*)d_in[6];
    const float* Wk1 = (const float*)d_in[7];  const float* bk1 = (const float*)d_in[8];
    const float* Wv1 = (const float*)d_in[9];  const float* bv1 = (const float*)d_in[10];
    const float* We1 = (const float*)d_in[11];
    const float* Ws1 = (const float*)d_in[12]; const float* bs1 = (const float*)d_in[13];
    const float* g1  = (const float*)d_in[14]; const float* be1 = (const float*)d_in[15];
    const float* Wq2 = (const float*)d_in[16]; const float* bq2 = (const float*)d_in[17];
    const float* Wk2 = (const float*)d_in[18]; const float* bk2 = (const float*)d_in[19];
    const float* Wv2 = (const float*)d_in[20]; const float* bv2 = (const float*)d_in[21];
    const float* We2 = (const float*)d_in[22];
    const float* Ws2 = (const float*)d_in[23]; const float* bs2 = (const float*)d_in[24];
    const float* g2  = (const float*)d_in[25]; const float* be2 = (const float*)d_in[26];
    const float* Wsol = (const float*)d_in[27]; const float* bsol = (const float*)d_in[28];
    const float* Wfc1 = (const float*)d_in[29]; const float* bfc1 = (const float*)d_in[30];
    const float* gf   = (const float*)d_in[31]; const float* bf = (const float*)d_in[32];
    const float* Wfc2 = (const float*)d_in[33]; const float* bfc2 = (const float*)d_in[34];

    const int* srcp = eidx;
    const int* dstp = eidx + EE;

    // ---------------- workspace layout (tight aliasing; peak ~167 MB) -------
    char* p = (char*)d_ws;
    auto alloc = [&](size_t bytes) -> char* {
        char* r = p;
        p += (bytes + 255) & ~(size_t)255;
        return r;
    };
    const size_t NB512  = (size_t)NN * 512 * 4;
    const size_t NB1024 = (size_t)NN * 1024 * 4;

    float* bufH = (float*)alloc(NB512);    // h1
    float* bufA = (float*)alloc(NB1024);   // q1 -> v1 -> q2 -> v2
    float* bufB = (float*)alloc(NB1024);   // k1 -> (skip1 uses bufH) k2 -> h2
    // shared aux
    float* U     = (float*)alloc((size_t)NN * 64 * 4);
    float* T     = (float*)alloc((size_t)NN * 64 * 4);
    float* ab    = (float*)alloc((size_t)EE * 4 * 4);   // per-slot alpha/ex
    float* den   = (float*)alloc((size_t)NN * 4 * 4);
    float* Wu    = (float*)alloc((size_t)1024 * 64 * 4);
    float* Wt    = (float*)alloc((size_t)64 * 1024 * 4);
    float* bnA   = (float*)alloc(1024 * 4);
    float* bnB   = (float*)alloc(1024 * 4);
    // CSR
    int* deg    = (int*)alloc((size_t)NN * 4);
    int* cursor = (int*)alloc((size_t)NN * 4);
    int* rs     = (int*)alloc((size_t)(NN + 1) * 4);
    int* eids   = (int*)alloc((size_t)EE * 4);
    float* z  = (float*)alloc((size_t)64 * 2176 * 4);
    float* y  = (float*)alloc((size_t)64 * 128 * 4);
    float* y2 = (float*)alloc((size_t)64 * 128 * 4);

    // refuse to run rather than fault if workspace is too small
    if ((size_t)(p - (char*)d_ws) > ws_size) return;

    float* h1 = bufH;
    float* h2 = bufB;

    const int GR = (NN + 63) / 64;  // 235 row-tiles
    const int NWB = (NN * 64 + 255) / 256;  // node-wave blocks
    dim3 blk(256);

    // ---------------- CSR build (shared by both layers) ----------------
    hipMemsetAsync(deg, 0, (size_t)NN * 4, stream);
    count_deg<<<(EE + 255) / 256, blk, 0, stream>>>(dstp, deg, EE);
    scan_deg<<<1, 1024, 0, stream>>>(deg, rs, cursor, NN);
    fill_csr<<<(EE + 255) / 256, blk, 0, stream>>>(dstp, cursor, eids, EE);

    hipMemsetAsync(bnA, 0, 1024 * 4, stream);
    hipMemsetAsync(bnB, 0, 1024 * 4, stream);

    // ---------------- layer 1 (D=512, C=128) ----------------
    build_wu<512, 128><<<(512 * 64 + 255) / 256, blk, 0, stream>>>(We1, Wu);
    gemm64<true, false, false><<<dim3(8, GR), blk, 0, stream>>>(x, Wq1, bq1, bufA, NN, 512, 64, 512); // q1
    gemm64<true, false, false><<<dim3(8, GR), blk, 0, stream>>>(x, Wk1, bk1, bufB, NN, 512, 64, 512); // k1
    gemm64<false, false, false><<<dim3(1, GR), blk, 0, stream>>>(bufA, Wu, nullptr, U, NN, 64, 512, 64);
    node_alpha<128><<<NWB, blk, 0, stream>>>(bufA, bufB, U, ea, srcp, rs, eids, ab, den, NN);
    gemm64<true, false, false><<<dim3(8, GR), blk, 0, stream>>>(x, Wv1, bv1, bufA, NN, 512, 64, 512); // v1 (q1 dead)
    gemm64<true, false, false><<<dim3(8, GR), blk, 0, stream>>>(x, Ws1, bs1, h1, NN, 512, 64, 512);   // skip
    node_scatter<128><<<NWB, blk, 0, stream>>>(bufA, ea, srcp, rs, eids, ab, den, h1, T, NN);
    build_wt<512, 128><<<(64 * 512 + 255) / 256, blk, 0, stream>>>(We1, Wt);
    gemm64<false, false, true><<<dim3(8, GR), blk, 0, stream>>>(T, Wt, nullptr, h1, NN, 512, 64, 512);
    bn_stats<<<dim3(2, 64), blk, 0, stream>>>(h1, bnA, bnB, NN, 512);
    bn_finalize<<<2, blk, 0, stream>>>(bnA, bnB, g1, be1, NN, 512);
    bn_apply_relu<<<NN * 512 / 4 / 256, blk, 0, stream>>>(h1, bnA, bnB, NN * 512 / 4, 512);

    // ---------------- layer 2 (D=1024, C=256) ----------------
    hipMemsetAsync(bnA, 0, 1024 * 4, stream);
    hipMemsetAsync(bnB, 0, 1024 * 4, stream);

    build_wu<1024, 256><<<(1024 * 64 + 255) / 256, blk, 0, stream>>>(We2, Wu);
    gemm64<true, false, false><<<dim3(16, GR), blk, 0, stream>>>(h1, Wq2, bq2, bufA, NN, 1024, 512, 1024); // q2
    gemm64<true, false, false><<<dim3(16, GR), blk, 0, stream>>>(h1, Wk2, bk2, bufB, NN, 1024, 512, 1024); // k2
    gemm64<false, false, false><<<dim3(1, GR), blk, 0, stream>>>(bufA, Wu, nullptr, U, NN, 64, 1024, 64);
    node_alpha<256><<<NWB, blk, 0, stream>>>(bufA, bufB, U, ea, srcp, rs, eids, ab, den, NN);
    gemm64<true, false, false><<<dim3(16, GR), blk, 0, stream>>>(h1, Wv2, bv2, bufA, NN, 1024, 512, 1024); // v2 (q2 dead)
    gemm64<true, false, false><<<dim3(16, GR), blk, 0, stream>>>(h1, Ws2, bs2, h2, NN, 1024, 512, 1024);   // skip (k2 dead)
    node_scatter<256><<<NWB, blk, 0, stream>>>(bufA, ea, srcp, rs, eids, ab, den, h2, T, NN);
    build_wt<1024, 256><<<(64 * 1024 + 255) / 256, blk, 0, stream>>>(We2, Wt);
    gemm64<false, false, true><<<dim3(16, GR), blk, 0, stream>>>(T, Wt, nullptr, h2, NN, 1024, 64, 1024);
    bn_stats<<<dim3(4, 64), blk, 0, stream>>>(h2, bnA, bnB, NN, 1024);
    bn_finalize<<<4, blk, 0, stream>>>(bnA, bnB, g2, be2, NN, 1024);
    bn_apply_relu<<<NN * 1024 / 4 / 256, blk, 0, stream>>>(h2, bnA, bnB, NN * 1024 / 4, 1024);

    // ---------------- head ----------------
    pool_kernel<<<dim3(4, 64), blk, 0, stream>>>(h2, batch, z, NN, 1024, 2176);
    gemm64<true, true, false><<<dim3(2, 1), blk, 0, stream>>>(sol, Wsol, bsol, z + 2048, 64, 128, 128, 2176);
    gemm64<true, false, false><<<dim3(2, 1), blk, 0, stream>>>(z, Wfc1, bfc1, y, 64, 128, 2176, 128);
    bn_small_apply<<<1, 128, 0, stream>>>(y, gf, bf, y2);
    fc2_small<<<1, 128, 0, stream>>>(y2, Wfc2, bfc2, (float*)d_out);
}

// Round 5
// 1434.797 us; speedup vs baseline: 8.6553x; 1.5283x over previous
//
#include <hip/hip_runtime.h>
#include <cstdint>
#include <cstddef>

#define DEV __device__ __forceinline__

static constexpr int NN = 15000;   // nodes
static constexpr int EE = 150000;  // edges
static constexpr int GG = 64;      // graphs

typedef __attribute__((ext_vector_type(8))) short bf16x8;
typedef __attribute__((ext_vector_type(4))) float f32x4;

DEV short f2b1(float f) {  // fp32 -> bf16 bits, round-nearest-even
    unsigned u = __float_as_uint(f);
    unsigned r = (u + 0x7fffu + ((u >> 16) & 1u)) >> 16;
    return (short)r;
}
DEV float b2f(short s) { return __uint_as_float(((unsigned)(unsigned short)s) << 16); }

// ======================= bf16 MFMA GEMM =======================
// C[M,N] = A[M,K](bf16) @ B[K,N] (+bias) (+=C) ; B given TRANSPOSED: Bt[N][K].
// Tile 128x128, BK=32, 256 threads = 4 waves, each wave 64x64 (4x4 frags of 16x16).
// Requires N%128==0, K%32==0; M guarded.
template <bool BIAS, bool ACCUM, bool BF16OUT>
__global__ __launch_bounds__(256) void gemm_mfma(const short* __restrict__ A,
                                                 const short* __restrict__ Bt,
                                                 const float* __restrict__ bias,
                                                 void* __restrict__ Cv, int M, int N,
                                                 int K) {
    __shared__ short As[128][40];  // +8 pad: 80B row stride -> <=2-way bank alias
    __shared__ short Bs[128][40];
    const int tid = threadIdx.x;
    const int wid = tid >> 6, lane = tid & 63;
    const int wr = wid >> 1, wc = wid & 1;
    const int row0 = blockIdx.y * 128, col0 = blockIdx.x * 128;
    const int lrow = tid >> 1;          // 0..127
    const int lk = (tid & 1) * 16;      // 0 or 16
    f32x4 acc[4][4] = {};
    for (int k0 = 0; k0 < K; k0 += 32) {
        {   // stage A tile (zero-fill M tail)
            int gr = row0 + lrow;
            bf16x8 v0 = {}, v1 = {};
            if (gr < M) {
                const short* src = A + (size_t)gr * K + k0 + lk;
                v0 = *(const bf16x8*)(src);
                v1 = *(const bf16x8*)(src + 8);
            }
            *(bf16x8*)&As[lrow][lk] = v0;
            *(bf16x8*)&As[lrow][lk + 8] = v1;
        }
        {   // stage Bt tile (N multiple of 128)
            const short* src = Bt + (size_t)(col0 + lrow) * K + k0 + lk;
            *(bf16x8*)&Bs[lrow][lk] = *(const bf16x8*)(src);
            *(bf16x8*)&Bs[lrow][lk + 8] = *(const bf16x8*)(src + 8);
        }
        __syncthreads();
        const int kg = (lane >> 4) * 8;
        bf16x8 af[4], bf[4];
#pragma unroll
        for (int m = 0; m < 4; m++)
            af[m] = *(const bf16x8*)&As[wr * 64 + m * 16 + (lane & 15)][kg];
#pragma unroll
        for (int n = 0; n < 4; n++)
            bf[n] = *(const bf16x8*)&Bs[wc * 64 + n * 16 + (lane & 15)][kg];
#pragma unroll
        for (int m = 0; m < 4; m++)
#pragma unroll
            for (int n = 0; n < 4; n++)
                acc[m][n] = __builtin_amdgcn_mfma_f32_16x16x32_bf16(af[m], bf[n],
                                                                   acc[m][n], 0, 0, 0);
        __syncthreads();
    }
    // epilogue: C/D frag layout col=lane&15, row=(lane>>4)*4+reg
    const int colb = col0 + wc * 64 + (lane & 15);
    const int rowb = row0 + wr * 64 + (lane >> 4) * 4;
    float* Cf = (float*)Cv;
    short* Cb = (short*)Cv;
#pragma unroll
    for (int n = 0; n < 4; n++) {
        int gc = colb + n * 16;
        float bv = BIAS ? bias[gc] : 0.f;
#pragma unroll
        for (int m = 0; m < 4; m++) {
            int gr = rowb + m * 16;
#pragma unroll
            for (int r = 0; r < 4; r++) {
                if (gr + r < M) {
                    float v = acc[m][n][r] + bv;
                    if constexpr (ACCUM) v += Cf[(size_t)(gr + r) * N + gc];
                    if constexpr (BF16OUT)
                        Cb[(size_t)(gr + r) * N + gc] = f2b1(v);
                    else
                        Cf[(size_t)(gr + r) * N + gc] = v;
                }
            }
        }
    }
}

// ======================= fp32 tiled GEMM (small head GEMMs only) =======================
template <bool BIAS, bool RELU, bool ACCUM>
__global__ __launch_bounds__(256) void gemm64(const float* __restrict__ A,
                                              const float* __restrict__ B,
                                              const float* __restrict__ bias,
                                              float* __restrict__ C, int M, int N,
                                              int K, int ldc) {
    __shared__ float As[16][68];
    __shared__ float Bs[16][64];
    const int tid = threadIdx.x;
    const int tx = tid & 15, ty = tid >> 4;
    const int row0 = blockIdx.y * 64, col0 = blockIdx.x * 64;
    float acc[4][4] = {};
    for (int k0 = 0; k0 < K; k0 += 16) {
#pragma unroll
        for (int i = 0; i < 4; i++) {
            int idx = tid + i * 256;
            int r = idx >> 4, kk = idx & 15;
            int gr = row0 + r;
            As[kk][r] = (gr < M) ? A[(size_t)gr * K + k0 + kk] : 0.f;
        }
#pragma unroll
        for (int i = 0; i < 4; i++) {
            int idx = tid + i * 256;
            int kk = idx >> 6, c = idx & 63;
            Bs[kk][c] = B[(size_t)(k0 + kk) * N + col0 + c];
        }
        __syncthreads();
#pragma unroll
        for (int kk = 0; kk < 16; kk++) {
            float4 av = *(const float4*)&As[kk][ty * 4];
            float4 bv = *(const float4*)&Bs[kk][tx * 4];
            float a[4] = {av.x, av.y, av.z, av.w};
            float b[4] = {bv.x, bv.y, bv.z, bv.w};
#pragma unroll
            for (int i = 0; i < 4; i++)
#pragma unroll
                for (int j = 0; j < 4; j++) acc[i][j] = fmaf(a[i], b[j], acc[i][j]);
        }
        __syncthreads();
    }
#pragma unroll
    for (int i = 0; i < 4; i++) {
        int gr = row0 + ty * 4 + i;
        if (gr >= M) continue;
#pragma unroll
        for (int j = 0; j < 4; j++) {
            int gc = col0 + tx * 4 + j;
            float v = acc[i][j];
            if constexpr (BIAS) v += bias[gc];
            if constexpr (ACCUM) v += C[(size_t)gr * ldc + gc];
            if constexpr (RELU) v = fmaxf(v, 0.f);
            C[(size_t)gr * ldc + gc] = v;
        }
    }
}

// ======================= conversions =======================
__global__ __launch_bounds__(256) void f2b_vec(const float* __restrict__ in,
                                               short* __restrict__ out, int n4) {
    int i = blockIdx.x * 256 + threadIdx.x;
    if (i >= n4) return;
    float4 v = ((const float4*)in)[i];
    short4 o;
    o.x = f2b1(v.x); o.y = f2b1(v.y); o.z = f2b1(v.z); o.w = f2b1(v.w);
    ((short4*)out)[i] = o;
}
// W[K,N] fp32 -> Wt[N,K] bf16 (coalesced reads, scattered 2B writes; small mats)
__global__ __launch_bounds__(256) void f2b_T(const float* __restrict__ in,
                                             short* __restrict__ out, int K, int N) {
    int i = blockIdx.x * 256 + threadIdx.x;
    if (i >= K * N) return;
    int kk = i / N, n = i - kk * N;
    out[(size_t)n * K + kk] = f2b1(in[i]);
}
// block-diag expansion of We as Bt-layout bf16: out[d][h'*16+f] = (head(d)==h')?We[f][d]:0
template <int D, int C>
__global__ __launch_bounds__(256) void build_wub(const float* __restrict__ We,
                                                 short* __restrict__ out) {
    int i = blockIdx.x * 256 + threadIdx.x;
    if (i >= D * 64) return;
    int d = i >> 6, hf = i & 63;
    int hp = hf >> 4, f = hf & 15;
    float v = ((d / C) == hp) ? We[(size_t)f * D + d] : 0.f;
    out[i] = f2b1(v);
}

// ======================= CSR build (by dst) =======================
__global__ __launch_bounds__(256) void count_deg(const int* __restrict__ dst,
                                                 int* __restrict__ deg, int E) {
    int e = blockIdx.x * 256 + threadIdx.x;
    if (e < E) atomicAdd(&deg[dst[e]], 1);
}

__global__ __launch_bounds__(1024) void scan_deg(const int* __restrict__ deg,
                                                 int* __restrict__ rs,
                                                 int* __restrict__ cursor, int n) {
    __shared__ int part[1024];
    int t = threadIdx.x;
    int ch = (n + 1023) / 1024;
    int b0 = min(t * ch, n), b1 = min(b0 + ch, n);
    int s = 0;
    for (int i = b0; i < b1; i++) s += deg[i];
    part[t] = s;
    __syncthreads();
    for (int off = 1; off < 1024; off <<= 1) {
        int tmp = (t >= off) ? part[t - off] : 0;
        __syncthreads();
        part[t] += tmp;
        __syncthreads();
    }
    int run = part[t] - s;
    for (int i = b0; i < b1; i++) {
        rs[i] = run;
        cursor[i] = run;
        run += deg[i];
    }
    if (t == 1023) rs[n] = part[1023];
}

__global__ __launch_bounds__(256) void fill_csr(const int* __restrict__ dst,
                                                int* __restrict__ cursor,
                                                int* __restrict__ eids, int E) {
    int e = blockIdx.x * 256 + threadIdx.x;
    if (e < E) {
        int pos = atomicAdd(&cursor[dst[e]], 1);
        eids[pos] = e;
    }
}

// ======================= per-node kernels =======================
// U[node][h*16+f] = sum_c q[node,h*C+c] * We[f, h*C+c]   (q bf16, We fp32)
template <int C>
__global__ __launch_bounds__(256) void node_u(const short* __restrict__ qb,
                                              const float* __restrict__ We,
                                              float* __restrict__ U, int Nn) {
    constexpr int D = 4 * C;
    int node = (blockIdx.x * 256 + threadIdx.x) >> 6;
    int lane = threadIdx.x & 63;
    if (node >= Nn) return;
    int h = lane >> 4, f = lane & 15;
    const short* qp = qb + (size_t)node * D + h * C;
    const float* wp = We + (size_t)f * D + h * C;
    float s = 0.f;
    for (int c = 0; c < C; c += 8) {
        bf16x8 qv = *(const bf16x8*)(qp + c);
        float4 w0 = *(const float4*)(wp + c);
        float4 w1 = *(const float4*)(wp + c + 4);
        s = fmaf(b2f(qv[0]), w0.x, s);
        s = fmaf(b2f(qv[1]), w0.y, s);
        s = fmaf(b2f(qv[2]), w0.z, s);
        s = fmaf(b2f(qv[3]), w0.w, s);
        s = fmaf(b2f(qv[4]), w1.x, s);
        s = fmaf(b2f(qv[5]), w1.y, s);
        s = fmaf(b2f(qv[6]), w1.z, s);
        s = fmaf(b2f(qv[7]), w1.w, s);
    }
    U[(size_t)node * 64 + lane] = s;
}

// Pass A: fused alpha + segment softmax (per-node wave, no atomics)
template <int C>
__global__ __launch_bounds__(256) void node_alpha(
    const short* __restrict__ q, const short* __restrict__ k,
    const float* __restrict__ U, const float* __restrict__ ea,
    const int* __restrict__ src, const int* __restrict__ rs,
    const int* __restrict__ eids, float* __restrict__ ab,
    float* __restrict__ den, int Nn) {
    constexpr int D = 4 * C;
    constexpr int P = D / 64;
    int node = (blockIdx.x * 256 + threadIdx.x) >> 6;
    int lane = threadIdx.x & 63;
    if (node >= Nn) return;
    int e0 = rs[node], e1 = rs[node + 1];
    float qr[P];
    const short* qp = q + (size_t)node * D + lane * P;
#pragma unroll
    for (int j0 = 0; j0 < P; j0 += 8) {
        bf16x8 v = *(const bf16x8*)(qp + j0);
#pragma unroll
        for (int j = 0; j < 8; j++) qr[j0 + j] = b2f(v[j]);
    }
    float Urow = U[(size_t)node * 64 + lane];
    const float rsC = rsqrtf((float)C);
    float m = -3.402823466e38f;
    for (int ii = e0; ii < e1; ii++) {
        int e = eids[ii];
        int s = src[e];
        float val = ea[(size_t)e * 16 + (lane & 15)] * Urow;
        const short* kp = k + (size_t)s * D + lane * P;
#pragma unroll
        for (int j0 = 0; j0 < P; j0 += 8) {
            bf16x8 kv = *(const bf16x8*)(kp + j0);
#pragma unroll
            for (int j = 0; j < 8; j++) val = fmaf(qr[j0 + j], b2f(kv[j]), val);
        }
#pragma unroll
        for (int off = 1; off < 16; off <<= 1) val += __shfl_xor(val, off);
        val *= rsC;
        if ((lane & 15) == 0) ab[(size_t)ii * 4 + (lane >> 4)] = val;
        m = fmaxf(m, val);
    }
    float dsum = 0.f;
    for (int ii = e0; ii < e1; ii++) {
        float a = ab[(size_t)ii * 4 + (lane >> 4)];
        float ex = __expf(a - m);
        dsum += ex;
        if ((lane & 15) == 0) ab[(size_t)ii * 4 + (lane >> 4)] = ex;
    }
    if ((lane & 15) == 0) den[(size_t)node * 4 + (lane >> 4)] = dsum;
}

// Pass B: h[node] += (sum ex*v[src])/den (fp32);  Tb[node] = (sum ex*ea)/den (bf16)
template <int C>
__global__ __launch_bounds__(256) void node_scatter(
    const short* __restrict__ v, const float* __restrict__ ea,
    const int* __restrict__ src, const int* __restrict__ rs,
    const int* __restrict__ eids, const float* __restrict__ ab,
    const float* __restrict__ den, float* __restrict__ hout,
    short* __restrict__ Tb, int Nn) {
    constexpr int D = 4 * C;
    constexpr int P = D / 64;
    int node = (blockIdx.x * 256 + threadIdx.x) >> 6;
    int lane = threadIdx.x & 63;
    if (node >= Nn) return;
    int e0 = rs[node], e1 = rs[node + 1];
    float acc[P] = {};
    float tacc = 0.f;
    for (int ii = e0; ii < e1; ii++) {
        int e = eids[ii];
        int s = src[e];
        float ex = ab[(size_t)ii * 4 + (lane >> 4)];
        tacc = fmaf(ex, ea[(size_t)e * 16 + (lane & 15)], tacc);
        const short* vp = v + (size_t)s * D + lane * P;
#pragma unroll
        for (int j0 = 0; j0 < P; j0 += 8) {
            bf16x8 t8 = *(const bf16x8*)(vp + j0);
#pragma unroll
            for (int j = 0; j < 8; j++) acc[j0 + j] = fmaf(ex, b2f(t8[j]), acc[j0 + j]);
        }
    }
    float inv = 1.f / (den[(size_t)node * 4 + (lane >> 4)] + 1e-16f);
    Tb[(size_t)node * 64 + lane] = f2b1(tacc * inv);
    float* hp = hout + (size_t)node * D + lane * P;
#pragma unroll
    for (int j = 0; j < P; j += 4) {
        float4 t4 = *(float4*)(hp + j);
        t4.x = fmaf(acc[j], inv, t4.x);
        t4.y = fmaf(acc[j + 1], inv, t4.y);
        t4.z = fmaf(acc[j + 2], inv, t4.z);
        t4.w = fmaf(acc[j + 3], inv, t4.w);
        *(float4*)(hp + j) = t4;
    }
}

// ======================= batch norm =======================
__global__ __launch_bounds__(256) void bn_stats(const float* __restrict__ h,
                                                float* __restrict__ s1,
                                                float* __restrict__ s2, int Nrows,
                                                int D) {
    int col = blockIdx.x * 256 + threadIdx.x;
    int chunk = (Nrows + gridDim.y - 1) / gridDim.y;
    int r0 = blockIdx.y * chunk;
    int r1 = min(r0 + chunk, Nrows);
    float a = 0.f, b = 0.f;
    for (int r = r0; r < r1; r++) {
        float v = h[(size_t)r * D + col];
        a += v;
        b += v * v;
    }
    atomicAdd(&s1[col], a);
    atomicAdd(&s2[col], b);
}
__global__ void bn_finalize(float* __restrict__ s1, float* __restrict__ s2,
                            const float* __restrict__ g, const float* __restrict__ b,
                            int Nrows, int D) {
    int c = blockIdx.x * 256 + threadIdx.x;
    if (c >= D) return;
    float mean = s1[c] / (float)Nrows;
    float var = fmaxf(s2[c] / (float)Nrows - mean * mean, 0.f);
    float scale = g[c] / sqrtf(var + 1e-5f);
    s1[c] = scale;
    s2[c] = b[c] - mean * scale;
}
__global__ __launch_bounds__(256) void bn_apply_relu_f32(float* __restrict__ h,
                                                         const float* __restrict__ scale,
                                                         const float* __restrict__ shift,
                                                         int total4, int D) {
    int i = blockIdx.x * 256 + threadIdx.x;
    if (i >= total4) return;
    float4 v = ((float4*)h)[i];
    int c = (i * 4) % D;
    v.x = fmaxf(fmaf(v.x, scale[c], shift[c]), 0.f);
    v.y = fmaxf(fmaf(v.y, scale[c + 1], shift[c + 1]), 0.f);
    v.z = fmaxf(fmaf(v.z, scale[c + 2], shift[c + 2]), 0.f);
    v.w = fmaxf(fmaf(v.w, scale[c + 3], shift[c + 3]), 0.f);
    ((float4*)h)[i] = v;
}
__global__ __launch_bounds__(256) void bn_apply_relu_b16(const float* __restrict__ h,
                                                         const float* __restrict__ scale,
                                                         const float* __restrict__ shift,
                                                         short* __restrict__ out,
                                                         int total4, int D) {
    int i = blockIdx.x * 256 + threadIdx.x;
    if (i >= total4) return;
    float4 v = ((const float4*)h)[i];
    int c = (i * 4) % D;
    short4 o;
    o.x = f2b1(fmaxf(fmaf(v.x, scale[c], shift[c]), 0.f));
    o.y = f2b1(fmaxf(fmaf(v.y, scale[c + 1], shift[c + 1]), 0.f));
    o.z = f2b1(fmaxf(fmaf(v.z, scale[c + 2], shift[c + 2]), 0.f));
    o.w = f2b1(fmaxf(fmaf(v.w, scale[c + 3], shift[c + 3]), 0.f));
    ((short4*)out)[i] = o;
}

// ======================= pooling (batch is sorted) =======================
__global__ __launch_bounds__(256) void pool_kernel(const float* __restrict__ h,
                                                   const int* __restrict__ batch,
                                                   float* __restrict__ z, int Nrows,
                                                   int D, int ldz) {
    int g = blockIdx.y;
    int c = blockIdx.x * 256 + threadIdx.x;
    int lo = 0, hi = Nrows;
    while (lo < hi) {
        int m = (lo + hi) >> 1;
        if (batch[m] < g) lo = m + 1; else hi = m;
    }
    int s0 = lo;
    hi = Nrows;
    while (lo < hi) {
        int m = (lo + hi) >> 1;
        if (batch[m] < g + 1) lo = m + 1; else hi = m;
    }
    int s1 = lo;
    float sum = 0.f, mx = -3.402823466e38f;
    for (int r = s0; r < s1; r++) {
        float v = h[(size_t)r * D + c];
        sum += v;
        mx = fmaxf(mx, v);
    }
    int cnt = s1 - s0;
    z[(size_t)g * ldz + c] = sum / (float)max(cnt, 1);
    z[(size_t)g * ldz + D + c] = (cnt > 0) ? mx : 0.f;
}

// ======================= tiny MLP head =======================
__global__ __launch_bounds__(128) void bn_small_apply(const float* __restrict__ y,
                                                      const float* __restrict__ g,
                                                      const float* __restrict__ b,
                                                      float* __restrict__ y2) {
    int c = threadIdx.x;
    float m = 0.f;
    for (int r = 0; r < 64; r++) m += y[r * 128 + c];
    m *= (1.f / 64.f);
    float v = 0.f;
    for (int r = 0; r < 64; r++) {
        float d = y[r * 128 + c] - m;
        v += d * d;
    }
    v *= (1.f / 64.f);
    float sc = g[c] / sqrtf(v + 1e-5f);
    float sh = b[c] - m * sc;
    for (int r = 0; r < 64; r++) y2[r * 128 + c] = fmaxf(fmaf(y[r * 128 + c], sc, sh), 0.f);
}
__global__ __launch_bounds__(128) void fc2_small(const float* __restrict__ y2,
                                                 const float* __restrict__ W,
                                                 const float* __restrict__ b,
                                                 float* __restrict__ out) {
    int t = threadIdx.x;
    int g = t >> 1, o = t & 1;
    float s = b[o];
    for (int kk = 0; kk < 128; kk++) s = fmaf(y2[g * 128 + kk], W[kk * 2 + o], s);
    out[g * 2 + o] = s;
}

// ======================= launch =======================
extern "C" void kernel_launch(void* const* d_in, const int* in_sizes, int n_in,
                              void* d_out, int out_size, void* d_ws, size_t ws_size,
                              hipStream_t stream) {
    const float* x     = (const float*)d_in[0];
    const float* ea    = (const float*)d_in[1];
    const float* sol   = (const float*)d_in[2];
    const int*   eidx  = (const int*)d_in[3];
    const int*   batch = (const int*)d_in[4];
    const float* Wq1 = (const float*)d_in[5];  const float* bq1 = (const float*)d_in[6];
    const float* Wk1 = (const float*)d_in[7];  const float* bk1 = (const float*)d_in[8];
    const float* Wv1 = (const float*)d_in[9];  const float* bv1 = (const float*)d_in[10];
    const float* We1 = (const float*)d_in[11];
    const float* Ws1 = (const float*)d_in[12]; const float* bs1 = (const float*)d_in[13];
    const float* g1  = (const float*)d_in[14]; const float* be1 = (const float*)d_in[15];
    const float* Wq2 = (const float*)d_in[16]; const float* bq2 = (const float*)d_in[17];
    const float* Wk2 = (const float*)d_in[18]; const float* bk2 = (const float*)d_in[19];
    const float* Wv2 = (const float*)d_in[20]; const float* bv2 = (const float*)d_in[21];
    const float* We2 = (const float*)d_in[22];
    const float* Ws2 = (const float*)d_in[23]; const float* bs2 = (const float*)d_in[24];
    const float* g2  = (const float*)d_in[25]; const float* be2 = (const float*)d_in[26];
    const float* Wsol = (const float*)d_in[27]; const float* bsol = (const float*)d_in[28];
    const float* Wfc1 = (const float*)d_in[29]; const float* bfc1 = (const float*)d_in[30];
    const float* gf   = (const float*)d_in[31]; const float* bf = (const float*)d_in[32];
    const float* Wfc2 = (const float*)d_in[33]; const float* bfc2 = (const float*)d_in[34];

    const int* srcp = eidx;
    const int* dstp = eidx + EE;

    // ---------------- workspace (peak ~155 MB) ----------------
    char* p = (char*)d_ws;
    auto alloc = [&](size_t bytes) -> char* {
        char* r = p;
        p += (bytes + 255) & ~(size_t)255;
        return r;
    };
    float* R0   = (float*)alloc((size_t)NN * 1024 * 4);  // h1 fp32 (1st half) -> h2 fp32
    short* h1b  = (short*)alloc((size_t)NN * 512 * 2);
    short* bufAb = (short*)alloc((size_t)NN * 1024 * 2); // q1b -> v1b -> q2b -> v2b
    short* bufBb = (short*)alloc((size_t)NN * 1024 * 2); // k1b -> k2b
    float* U    = (float*)alloc((size_t)NN * 64 * 4);
    short* Tb   = (short*)alloc((size_t)NN * 64 * 2);
    float* ab   = (float*)alloc((size_t)EE * 4 * 4);
    float* den  = (float*)alloc((size_t)NN * 4 * 4);
    short* wub  = (short*)alloc((size_t)1024 * 64 * 2);
    short* wq1t = (short*)alloc((size_t)512 * 64 * 2);
    short* wk1t = (short*)alloc((size_t)512 * 64 * 2);
    short* wv1t = (short*)alloc((size_t)512 * 64 * 2);
    short* ws1t = (short*)alloc((size_t)512 * 64 * 2);
    short* wq2t = (short*)alloc((size_t)1024 * 512 * 2);
    short* wk2t = (short*)alloc((size_t)1024 * 512 * 2);
    short* wv2t = (short*)alloc((size_t)1024 * 512 * 2);
    short* ws2t = (short*)alloc((size_t)1024 * 512 * 2);
    short* xb   = (short*)alloc((size_t)NN * 64 * 2);
    int* deg    = (int*)alloc((size_t)NN * 4);
    int* cursor = (int*)alloc((size_t)NN * 4);
    int* rs     = (int*)alloc((size_t)(NN + 1) * 4);
    int* eids   = (int*)alloc((size_t)EE * 4);
    float* bnA  = (float*)alloc(1024 * 4);
    float* bnB  = (float*)alloc(1024 * 4);
    float* z  = (float*)alloc((size_t)64 * 2176 * 4);
    float* y  = (float*)alloc((size_t)64 * 128 * 4);
    float* y2 = (float*)alloc((size_t)64 * 128 * 4);
    if ((size_t)(p - (char*)d_ws) > ws_size) return;  // refuse rather than fault

    float* h1 = R0;   // fp32, dead after bn_apply_relu_b16
    float* h2 = R0;   // fp32, live from skip2 onward

    const int GRM = (NN + 127) / 128;      // 118 MFMA row-tiles
    const int NWB = (NN * 64 + 255) / 256; // node-wave blocks
    dim3 blk(256);

    // ---------------- CSR + conversions ----------------
    hipMemsetAsync(deg, 0, (size_t)NN * 4, stream);
    count_deg<<<(EE + 255) / 256, blk, 0, stream>>>(dstp, deg, EE);
    scan_deg<<<1, 1024, 0, stream>>>(deg, rs, cursor, NN);
    fill_csr<<<(EE + 255) / 256, blk, 0, stream>>>(dstp, cursor, eids, EE);

    f2b_vec<<<(NN * 64 / 4 + 255) / 256, blk, 0, stream>>>(x, xb, NN * 64 / 4);
    f2b_T<<<(512 * 64 + 255) / 256, blk, 0, stream>>>(Wq1, wq1t, 64, 512);
    f2b_T<<<(512 * 64 + 255) / 256, blk, 0, stream>>>(Wk1, wk1t, 64, 512);
    f2b_T<<<(512 * 64 + 255) / 256, blk, 0, stream>>>(Wv1, wv1t, 64, 512);
    f2b_T<<<(512 * 64 + 255) / 256, blk, 0, stream>>>(Ws1, ws1t, 64, 512);
    f2b_T<<<(1024 * 512 + 255) / 256, blk, 0, stream>>>(Wq2, wq2t, 512, 1024);
    f2b_T<<<(1024 * 512 + 255) / 256, blk, 0, stream>>>(Wk2, wk2t, 512, 1024);
    f2b_T<<<(1024 * 512 + 255) / 256, blk, 0, stream>>>(Wv2, wv2t, 512, 1024);
    f2b_T<<<(1024 * 512 + 255) / 256, blk, 0, stream>>>(Ws2, ws2t, 512, 1024);

    hipMemsetAsync(bnA, 0, 1024 * 4, stream);
    hipMemsetAsync(bnB, 0, 1024 * 4, stream);

    // ---------------- layer 1 (D=512, C=128) ----------------
    gemm_mfma<true, false, true><<<dim3(4, GRM), blk, 0, stream>>>(xb, wq1t, bq1, bufAb, NN, 512, 64);  // q1b
    gemm_mfma<true, false, true><<<dim3(4, GRM), blk, 0, stream>>>(xb, wk1t, bk1, bufBb, NN, 512, 64);  // k1b
    node_u<128><<<NWB, blk, 0, stream>>>(bufAb, We1, U, NN);
    node_alpha<128><<<NWB, blk, 0, stream>>>(bufAb, bufBb, U, ea, srcp, rs, eids, ab, den, NN);
    gemm_mfma<true, false, true><<<dim3(4, GRM), blk, 0, stream>>>(xb, wv1t, bv1, bufAb, NN, 512, 64);  // v1b (q1b dead)
    gemm_mfma<true, false, false><<<dim3(4, GRM), blk, 0, stream>>>(xb, ws1t, bs1, h1, NN, 512, 64);    // skip1 fp32
    node_scatter<128><<<NWB, blk, 0, stream>>>(bufAb, ea, srcp, rs, eids, ab, den, h1, Tb, NN);
    build_wub<512, 128><<<(512 * 64 + 255) / 256, blk, 0, stream>>>(We1, wub);
    gemm_mfma<false, true, false><<<dim3(4, GRM), blk, 0, stream>>>(Tb, wub, nullptr, h1, NN, 512, 64); // h1 += T@Wt
    bn_stats<<<dim3(2, 64), blk, 0, stream>>>(h1, bnA, bnB, NN, 512);
    bn_finalize<<<2, blk, 0, stream>>>(bnA, bnB, g1, be1, NN, 512);
    bn_apply_relu_b16<<<NN * 512 / 4 / 256, blk, 0, stream>>>(h1, bnA, bnB, h1b, NN * 512 / 4, 512);

    // ---------------- layer 2 (D=1024, C=256) ----------------
    hipMemsetAsync(bnA, 0, 1024 * 4, stream);
    hipMemsetAsync(bnB, 0, 1024 * 4, stream);
    gemm_mfma<true, false, true><<<dim3(8, GRM), blk, 0, stream>>>(h1b, wq2t, bq2, bufAb, NN, 1024, 512); // q2b
    gemm_mfma<true, false, true><<<dim3(8, GRM), blk, 0, stream>>>(h1b, wk2t, bk2, bufBb, NN, 1024, 512); // k2b
    node_u<256><<<NWB, blk, 0, stream>>>(bufAb, We2, U, NN);
    node_alpha<256><<<NWB, blk, 0, stream>>>(bufAb, bufBb, U, ea, srcp, rs, eids, ab, den, NN);
    gemm_mfma<true, false, true><<<dim3(8, GRM), blk, 0, stream>>>(h1b, wv2t, bv2, bufAb, NN, 1024, 512); // v2b (q2b dead)
    gemm_mfma<true, false, false><<<dim3(8, GRM), blk, 0, stream>>>(h1b, ws2t, bs2, h2, NN, 1024, 512);   // skip2 fp32 (h1 dead)
    node_scatter<256><<<NWB, blk, 0, stream>>>(bufAb, ea, srcp, rs, eids, ab, den, h2, Tb, NN);
    build_wub<1024, 256><<<(1024 * 64 + 255) / 256, blk, 0, stream>>>(We2, wub);
    gemm_mfma<false, true, false><<<dim3(8, GRM), blk, 0, stream>>>(Tb, wub, nullptr, h2, NN, 1024, 64);  // h2 += T@Wt
    bn_stats<<<dim3(4, 64), blk, 0, stream>>>(h2, bnA, bnB, NN, 1024);
    bn_finalize<<<4, blk, 0, stream>>>(bnA, bnB, g2, be2, NN, 1024);
    bn_apply_relu_f32<<<NN * 1024 / 4 / 256, blk, 0, stream>>>(h2, bnA, bnB, NN * 1024 / 4, 1024);

    // ---------------- head (fp32, tiny) ----------------
    pool_kernel<<<dim3(4, 64), blk, 0, stream>>>(h2, batch, z, NN, 1024, 2176);
    gemm64<true, true, false><<<dim3(2, 1), blk, 0, stream>>>(sol, Wsol, bsol, z + 2048, 64, 128, 128, 2176);
    gemm64<true, false, false><<<dim3(2, 1), blk, 0, stream>>>(z, Wfc1, bfc1, y, 64, 128, 2176, 128);
    bn_small_apply<<<1, 128, 0, stream>>>(y, gf, bf, y2);
    fc2_small<<<1, 128, 0, stream>>>(y2, Wfc2, bfc2, (float*)d_out);
}

// Round 6
// 1252.013 us; speedup vs baseline: 9.9189x; 1.1460x over previous
//
#include <hip/hip_runtime.h>
#include <cstdint>
#include <cstddef>

#define DEV __device__ __forceinline__

static constexpr int NN = 15000;   // nodes
static constexpr int EE = 150000;  // edges
static constexpr int GG = 64;      // graphs

typedef __attribute__((ext_vector_type(8))) short bf16x8;
typedef __attribute__((ext_vector_type(4))) float f32x4;

DEV short f2b1(float f) {  // fp32 -> bf16 bits, round-nearest-even
    unsigned u = __float_as_uint(f);
    unsigned r = (u + 0x7fffu + ((u >> 16) & 1u)) >> 16;
    return (short)r;
}
DEV float b2f(short s) { return __uint_as_float(((unsigned)(unsigned short)s) << 16); }

// ======================= bf16 MFMA GEMM =======================
// C[M,N] = A[M,K](bf16) @ B[K,N] (+bias) (+=C) ; B given TRANSPOSED: Bt[N][K].
// Tile 128x128, BK=32, 256 threads = 4 waves, each wave 64x64 (4x4 frags of 16x16).
// Requires N%128==0, K%32==0; M guarded.
template <bool BIAS, bool ACCUM, bool BF16OUT>
__global__ __launch_bounds__(256) void gemm_mfma(const short* __restrict__ A,
                                                 const short* __restrict__ Bt,
                                                 const float* __restrict__ bias,
                                                 void* __restrict__ Cv, int M, int N,
                                                 int K) {
    __shared__ short As[128][40];  // +8 pad: 80B row stride -> <=2-way bank alias
    __shared__ short Bs[128][40];
    const int tid = threadIdx.x;
    const int wid = tid >> 6, lane = tid & 63;
    const int wr = wid >> 1, wc = wid & 1;
    const int row0 = blockIdx.y * 128, col0 = blockIdx.x * 128;
    const int lrow = tid >> 1;          // 0..127
    const int lk = (tid & 1) * 16;      // 0 or 16
    f32x4 acc[4][4] = {};
    for (int k0 = 0; k0 < K; k0 += 32) {
        {   // stage A tile (zero-fill M tail)
            int gr = row0 + lrow;
            bf16x8 v0 = {}, v1 = {};
            if (gr < M) {
                const short* src = A + (size_t)gr * K + k0 + lk;
                v0 = *(const bf16x8*)(src);
                v1 = *(const bf16x8*)(src + 8);
            }
            *(bf16x8*)&As[lrow][lk] = v0;
            *(bf16x8*)&As[lrow][lk + 8] = v1;
        }
        {   // stage Bt tile (N multiple of 128)
            const short* src = Bt + (size_t)(col0 + lrow) * K + k0 + lk;
            *(bf16x8*)&Bs[lrow][lk] = *(const bf16x8*)(src);
            *(bf16x8*)&Bs[lrow][lk + 8] = *(const bf16x8*)(src + 8);
        }
        __syncthreads();
        const int kg = (lane >> 4) * 8;
        bf16x8 af[4], bf[4];
#pragma unroll
        for (int m = 0; m < 4; m++)
            af[m] = *(const bf16x8*)&As[wr * 64 + m * 16 + (lane & 15)][kg];
#pragma unroll
        for (int n = 0; n < 4; n++)
            bf[n] = *(const bf16x8*)&Bs[wc * 64 + n * 16 + (lane & 15)][kg];
#pragma unroll
        for (int m = 0; m < 4; m++)
#pragma unroll
            for (int n = 0; n < 4; n++)
                acc[m][n] = __builtin_amdgcn_mfma_f32_16x16x32_bf16(af[m], bf[n],
                                                                   acc[m][n], 0, 0, 0);
        __syncthreads();
    }
    // epilogue: C/D frag layout col=lane&15, row=(lane>>4)*4+reg
    const int colb = col0 + wc * 64 + (lane & 15);
    const int rowb = row0 + wr * 64 + (lane >> 4) * 4;
    float* Cf = (float*)Cv;
    short* Cb = (short*)Cv;
#pragma unroll
    for (int n = 0; n < 4; n++) {
        int gc = colb + n * 16;
        float bv = BIAS ? bias[gc] : 0.f;
#pragma unroll
        for (int m = 0; m < 4; m++) {
            int gr = rowb + m * 16;
#pragma unroll
            for (int r = 0; r < 4; r++) {
                if (gr + r < M) {
                    float v = acc[m][n][r] + bv;
                    if constexpr (ACCUM) v += Cf[(size_t)(gr + r) * N + gc];
                    if constexpr (BF16OUT)
                        Cb[(size_t)(gr + r) * N + gc] = f2b1(v);
                    else
                        Cf[(size_t)(gr + r) * N + gc] = v;
                }
            }
        }
    }
}

// ======================= small-M row GEMM (head) =======================
// C[M,N] = A[M,K]@B[K,N] + bias (relu opt). One block per row; N==128; 256 thr.
// lanes = 128 cols x 2 K-halves; coalesced B reads; LDS combine.
template <bool RELU>
__global__ __launch_bounds__(256) void gemm_row(const float* __restrict__ A,
                                                const float* __restrict__ B,
                                                const float* __restrict__ bias,
                                                float* __restrict__ C, int N, int K,
                                                int lda, int ldc) {
    int g = blockIdx.x;
    int col = threadIdx.x & 127;
    int half = threadIdx.x >> 7;
    int kh = K >> 1;
    int k0 = half * kh, k1 = k0 + kh;
    const float* a = A + (size_t)g * lda;
    float s0 = 0.f, s1 = 0.f, s2 = 0.f, s3 = 0.f;
    int kk = k0;
    for (; kk + 4 <= k1; kk += 4) {
        s0 = fmaf(a[kk], B[(size_t)kk * N + col], s0);
        s1 = fmaf(a[kk + 1], B[(size_t)(kk + 1) * N + col], s1);
        s2 = fmaf(a[kk + 2], B[(size_t)(kk + 2) * N + col], s2);
        s3 = fmaf(a[kk + 3], B[(size_t)(kk + 3) * N + col], s3);
    }
    for (; kk < k1; kk++) s0 = fmaf(a[kk], B[(size_t)kk * N + col], s0);
    float s = (s0 + s1) + (s2 + s3);
    __shared__ float red[128];
    if (half == 1) red[col] = s;
    __syncthreads();
    if (half == 0) {
        s += red[col] + bias[col];
        if (RELU) s = fmaxf(s, 0.f);
        C[(size_t)g * ldc + col] = s;
    }
}

// ======================= conversions =======================
__global__ __launch_bounds__(256) void f2b_vec(const float* __restrict__ in,
                                               short* __restrict__ out, int n4) {
    int i = blockIdx.x * 256 + threadIdx.x;
    if (i >= n4) return;
    float4 v = ((const float4*)in)[i];
    short4 o;
    o.x = f2b1(v.x); o.y = f2b1(v.y); o.z = f2b1(v.z); o.w = f2b1(v.w);
    ((short4*)out)[i] = o;
}
// W[K,N] fp32 -> Wt[N,K] bf16 via 32x32 LDS tile (coalesced both sides)
__global__ __launch_bounds__(256) void f2b_T(const float* __restrict__ in,
                                             short* __restrict__ out, int K, int N) {
    __shared__ short tile[32][33];
    int kb = blockIdx.y * 32, nb = blockIdx.x * 32;
    int tx = threadIdx.x & 31, ty = threadIdx.x >> 5;  // 8 rows per pass
#pragma unroll
    for (int i = 0; i < 32; i += 8) {
        int kk = kb + ty + i, n = nb + tx;
        if (kk < K && n < N) tile[ty + i][tx] = f2b1(in[(size_t)kk * N + n]);
    }
    __syncthreads();
#pragma unroll
    for (int i = 0; i < 32; i += 8) {
        int n = nb + ty + i, kk = kb + tx;
        if (n < N && kk < K) out[(size_t)n * K + kk] = tile[tx][ty + i];
    }
}
// block-diag expansion of We as Bt-layout bf16: out[d][h'*16+f] = (head(d)==h')?We[f][d]:0
template <int D, int C>
__global__ __launch_bounds__(256) void build_wub(const float* __restrict__ We,
                                                 short* __restrict__ out) {
    int i = blockIdx.x * 256 + threadIdx.x;
    if (i >= D * 64) return;
    int d = i >> 6, hf = i & 63;
    int hp = hf >> 4, f = hf & 15;
    float v = ((d / C) == hp) ? We[(size_t)f * D + d] : 0.f;
    out[i] = f2b1(v);
}

// ======================= CSR build (by dst) =======================
__global__ __launch_bounds__(256) void count_deg(const int* __restrict__ dst,
                                                 int* __restrict__ deg, int E) {
    int e = blockIdx.x * 256 + threadIdx.x;
    if (e < E) atomicAdd(&deg[dst[e]], 1);
}

__global__ __launch_bounds__(1024) void scan_deg(const int* __restrict__ deg,
                                                 int* __restrict__ rs,
                                                 int* __restrict__ cursor, int n) {
    __shared__ int part[1024];
    int t = threadIdx.x;
    int ch = (n + 1023) / 1024;
    int b0 = min(t * ch, n), b1 = min(b0 + ch, n);
    int s = 0;
    for (int i = b0; i < b1; i++) s += deg[i];
    part[t] = s;
    __syncthreads();
    for (int off = 1; off < 1024; off <<= 1) {
        int tmp = (t >= off) ? part[t - off] : 0;
        __syncthreads();
        part[t] += tmp;
        __syncthreads();
    }
    int run = part[t] - s;
    for (int i = b0; i < b1; i++) {
        rs[i] = run;
        cursor[i] = run;
        run += deg[i];
    }
    if (t == 1023) rs[n] = part[1023];
}

__global__ __launch_bounds__(256) void fill_csr(const int* __restrict__ dst,
                                                int* __restrict__ cursor,
                                                int* __restrict__ eids, int E) {
    int e = blockIdx.x * 256 + threadIdx.x;
    if (e < E) {
        int pos = atomicAdd(&cursor[dst[e]], 1);
        eids[pos] = e;
    }
}

// ======================= per-node kernels =======================
// U[node][h*16+f] = sum_c q[node,h*C+c] * We[f, h*C+c]   (q bf16, We fp32)
template <int C>
__global__ __launch_bounds__(256) void node_u(const short* __restrict__ qb,
                                              const float* __restrict__ We,
                                              float* __restrict__ U, int Nn) {
    constexpr int D = 4 * C;
    int node = (blockIdx.x * 256 + threadIdx.x) >> 6;
    int lane = threadIdx.x & 63;
    if (node >= Nn) return;
    int h = lane >> 4, f = lane & 15;
    const short* qp = qb + (size_t)node * D + h * C;
    const float* wp = We + (size_t)f * D + h * C;
    float s = 0.f;
    for (int c = 0; c < C; c += 8) {
        bf16x8 qv = *(const bf16x8*)(qp + c);
        float4 w0 = *(const float4*)(wp + c);
        float4 w1 = *(const float4*)(wp + c + 4);
        s = fmaf(b2f(qv[0]), w0.x, s);
        s = fmaf(b2f(qv[1]), w0.y, s);
        s = fmaf(b2f(qv[2]), w0.z, s);
        s = fmaf(b2f(qv[3]), w0.w, s);
        s = fmaf(b2f(qv[4]), w1.x, s);
        s = fmaf(b2f(qv[5]), w1.y, s);
        s = fmaf(b2f(qv[6]), w1.z, s);
        s = fmaf(b2f(qv[7]), w1.w, s);
    }
    U[(size_t)node * 64 + lane] = s;
}

// Pass A: fused alpha + segment softmax (per-node wave, no atomics)
template <int C>
__global__ __launch_bounds__(256) void node_alpha(
    const short* __restrict__ q, const short* __restrict__ k,
    const float* __restrict__ U, const float* __restrict__ ea,
    const int* __restrict__ src, const int* __restrict__ rs,
    const int* __restrict__ eids, float* __restrict__ ab,
    float* __restrict__ den, int Nn) {
    constexpr int D = 4 * C;
    constexpr int P = D / 64;
    int node = (blockIdx.x * 256 + threadIdx.x) >> 6;
    int lane = threadIdx.x & 63;
    if (node >= Nn) return;
    int e0 = rs[node], e1 = rs[node + 1];
    float qr[P];
    const short* qp = q + (size_t)node * D + lane * P;
#pragma unroll
    for (int j0 = 0; j0 < P; j0 += 8) {
        bf16x8 v = *(const bf16x8*)(qp + j0);
#pragma unroll
        for (int j = 0; j < 8; j++) qr[j0 + j] = b2f(v[j]);
    }
    float Urow = U[(size_t)node * 64 + lane];
    const float rsC = rsqrtf((float)C);
    float m = -3.402823466e38f;
    for (int ii = e0; ii < e1; ii++) {
        int e = eids[ii];
        int s = src[e];
        float val = ea[(size_t)e * 16 + (lane & 15)] * Urow;
        const short* kp = k + (size_t)s * D + lane * P;
#pragma unroll
        for (int j0 = 0; j0 < P; j0 += 8) {
            bf16x8 kv = *(const bf16x8*)(kp + j0);
#pragma unroll
            for (int j = 0; j < 8; j++) val = fmaf(qr[j0 + j], b2f(kv[j]), val);
        }
#pragma unroll
        for (int off = 1; off < 16; off <<= 1) val += __shfl_xor(val, off);
        val *= rsC;
        if ((lane & 15) == 0) ab[(size_t)ii * 4 + (lane >> 4)] = val;
        m = fmaxf(m, val);
    }
    float dsum = 0.f;
    for (int ii = e0; ii < e1; ii++) {
        float a = ab[(size_t)ii * 4 + (lane >> 4)];
        float ex = __expf(a - m);
        dsum += ex;
        if ((lane & 15) == 0) ab[(size_t)ii * 4 + (lane >> 4)] = ex;
    }
    if ((lane & 15) == 0) den[(size_t)node * 4 + (lane >> 4)] = dsum;
}

// Pass B: h[node] += (sum ex*v[src])/den (fp32);  Tb[node] = (sum ex*ea)/den (bf16)
template <int C>
__global__ __launch_bounds__(256) void node_scatter(
    const short* __restrict__ v, const float* __restrict__ ea,
    const int* __restrict__ src, const int* __restrict__ rs,
    const int* __restrict__ eids, const float* __restrict__ ab,
    const float* __restrict__ den, float* __restrict__ hout,
    short* __restrict__ Tb, int Nn) {
    constexpr int D = 4 * C;
    constexpr int P = D / 64;
    int node = (blockIdx.x * 256 + threadIdx.x) >> 6;
    int lane = threadIdx.x & 63;
    if (node >= Nn) return;
    int e0 = rs[node], e1 = rs[node + 1];
    float acc[P] = {};
    float tacc = 0.f;
    for (int ii = e0; ii < e1; ii++) {
        int e = eids[ii];
        int s = src[e];
        float ex = ab[(size_t)ii * 4 + (lane >> 4)];
        tacc = fmaf(ex, ea[(size_t)e * 16 + (lane & 15)], tacc);
        const short* vp = v + (size_t)s * D + lane * P;
#pragma unroll
        for (int j0 = 0; j0 < P; j0 += 8) {
            bf16x8 t8 = *(const bf16x8*)(vp + j0);
#pragma unroll
            for (int j = 0; j < 8; j++) acc[j0 + j] = fmaf(ex, b2f(t8[j]), acc[j0 + j]);
        }
    }
    float inv = 1.f / (den[(size_t)node * 4 + (lane >> 4)] + 1e-16f);
    Tb[(size_t)node * 64 + lane] = f2b1(tacc * inv);
    float* hp = hout + (size_t)node * D + lane * P;
#pragma unroll
    for (int j = 0; j < P; j += 4) {
        float4 t4 = *(float4*)(hp + j);
        t4.x = fmaf(acc[j], inv, t4.x);
        t4.y = fmaf(acc[j + 1], inv, t4.y);
        t4.z = fmaf(acc[j + 2], inv, t4.z);
        t4.w = fmaf(acc[j + 3], inv, t4.w);
        *(float4*)(hp + j) = t4;
    }
}

// ======================= batch norm =======================
__global__ __launch_bounds__(256) void bn_stats(const float* __restrict__ h,
                                                float* __restrict__ s1,
                                                float* __restrict__ s2, int Nrows,
                                                int D) {
    int col = blockIdx.x * 256 + threadIdx.x;
    int chunk = (Nrows + gridDim.y - 1) / gridDim.y;
    int r0 = blockIdx.y * chunk;
    int r1 = min(r0 + chunk, Nrows);
    float a = 0.f, b = 0.f;
    for (int r = r0; r < r1; r++) {
        float v = h[(size_t)r * D + col];
        a += v;
        b += v * v;
    }
    atomicAdd(&s1[col], a);
    atomicAdd(&s2[col], b);
}
__global__ void bn_finalize(float* __restrict__ s1, float* __restrict__ s2,
                            const float* __restrict__ g, const float* __restrict__ b,
                            int Nrows, int D) {
    int c = blockIdx.x * 256 + threadIdx.x;
    if (c >= D) return;
    float mean = s1[c] / (float)Nrows;
    float var = fmaxf(s2[c] / (float)Nrows - mean * mean, 0.f);
    float scale = g[c] / sqrtf(var + 1e-5f);
    s1[c] = scale;
    s2[c] = b[c] - mean * scale;
}
__global__ __launch_bounds__(256) void bn_apply_relu_f32(float* __restrict__ h,
                                                         const float* __restrict__ scale,
                                                         const float* __restrict__ shift,
                                                         int total4, int D) {
    int i = blockIdx.x * 256 + threadIdx.x;
    if (i >= total4) return;
    float4 v = ((float4*)h)[i];
    int c = (i * 4) % D;
    v.x = fmaxf(fmaf(v.x, scale[c], shift[c]), 0.f);
    v.y = fmaxf(fmaf(v.y, scale[c + 1], shift[c + 1]), 0.f);
    v.z = fmaxf(fmaf(v.z, scale[c + 2], shift[c + 2]), 0.f);
    v.w = fmaxf(fmaf(v.w, scale[c + 3], shift[c + 3]), 0.f);
    ((float4*)h)[i] = v;
}
__global__ __launch_bounds__(256) void bn_apply_relu_b16(const float* __restrict__ h,
                                                         const float* __restrict__ scale,
                                                         const float* __restrict__ shift,
                                                         short* __restrict__ out,
                                                         int total4, int D) {
    int i = blockIdx.x * 256 + threadIdx.x;
    if (i >= total4) return;
    float4 v = ((const float4*)h)[i];
    int c = (i * 4) % D;
    short4 o;
    o.x = f2b1(fmaxf(fmaf(v.x, scale[c], shift[c]), 0.f));
    o.y = f2b1(fmaxf(fmaf(v.y, scale[c + 1], shift[c + 1]), 0.f));
    o.z = f2b1(fmaxf(fmaf(v.z, scale[c + 2], shift[c + 2]), 0.f));
    o.w = f2b1(fmaxf(fmaf(v.w, scale[c + 3], shift[c + 3]), 0.f));
    ((short4*)out)[i] = o;
}

// ======================= pooling (batch is sorted) =======================
__global__ __launch_bounds__(256) void pool_kernel(const float* __restrict__ h,
                                                   const int* __restrict__ batch,
                                                   float* __restrict__ z, int Nrows,
                                                   int D, int ldz) {
    int g = blockIdx.y;
    int c = blockIdx.x * 256 + threadIdx.x;
    int lo = 0, hi = Nrows;
    while (lo < hi) {
        int m = (lo + hi) >> 1;
        if (batch[m] < g) lo = m + 1; else hi = m;
    }
    int s0 = lo;
    hi = Nrows;
    while (lo < hi) {
        int m = (lo + hi) >> 1;
        if (batch[m] < g + 1) lo = m + 1; else hi = m;
    }
    int s1 = lo;
    float sum = 0.f, mx = -3.402823466e38f;
    for (int r = s0; r < s1; r++) {
        float v = h[(size_t)r * D + c];
        sum += v;
        mx = fmaxf(mx, v);
    }
    int cnt = s1 - s0;
    z[(size_t)g * ldz + c] = sum / (float)max(cnt, 1);
    z[(size_t)g * ldz + D + c] = (cnt > 0) ? mx : 0.f;
}

// ======================= tiny MLP head =======================
__global__ __launch_bounds__(128) void bn_small_apply(const float* __restrict__ y,
                                                      const float* __restrict__ g,
                                                      const float* __restrict__ b,
                                                      float* __restrict__ y2) {
    int c = threadIdx.x;
    float m = 0.f;
    for (int r = 0; r < 64; r++) m += y[r * 128 + c];
    m *= (1.f / 64.f);
    float v = 0.f;
    for (int r = 0; r < 64; r++) {
        float d = y[r * 128 + c] - m;
        v += d * d;
    }
    v *= (1.f / 64.f);
    float sc = g[c] / sqrtf(v + 1e-5f);
    float sh = b[c] - m * sc;
    for (int r = 0; r < 64; r++) y2[r * 128 + c] = fmaxf(fmaf(y[r * 128 + c], sc, sh), 0.f);
}
__global__ __launch_bounds__(128) void fc2_small(const float* __restrict__ y2,
                                                 const float* __restrict__ W,
                                                 const float* __restrict__ b,
                                                 float* __restrict__ out) {
    int t = threadIdx.x;
    int g = t >> 1, o = t & 1;
    float s = b[o];
    for (int kk = 0; kk < 128; kk++) s = fmaf(y2[g * 128 + kk], W[kk * 2 + o], s);
    out[g * 2 + o] = s;
}

// ======================= launch =======================
extern "C" void kernel_launch(void* const* d_in, const int* in_sizes, int n_in,
                              void* d_out, int out_size, void* d_ws, size_t ws_size,
                              hipStream_t stream) {
    const float* x     = (const float*)d_in[0];
    const float* ea    = (const float*)d_in[1];
    const float* sol   = (const float*)d_in[2];
    const int*   eidx  = (const int*)d_in[3];
    const int*   batch = (const int*)d_in[4];
    const float* Wq1 = (const float*)d_in[5];  const float* bq1 = (const float*)d_in[6];
    const float* Wk1 = (const float*)d_in[7];  const float* bk1 = (const float*)d_in[8];
    const float* Wv1 = (const float*)d_in[9];  const float* bv1 = (const float*)d_in[10];
    const float* We1 = (const float*)d_in[11];
    const float* Ws1 = (const float*)d_in[12]; const float* bs1 = (const float*)d_in[13];
    const float* g1  = (const float*)d_in[14]; const float* be1 = (const float*)d_in[15];
    const float* Wq2 = (const float*)d_in[16]; const float* bq2 = (const float*)d_in[17];
    const float* Wk2 = (const float*)d_in[18]; const float* bk2 = (const float*)d_in[19];
    const float* Wv2 = (const float*)d_in[20]; const float* bv2 = (const float*)d_in[21];
    const float* We2 = (const float*)d_in[22];
    const float* Ws2 = (const float*)d_in[23]; const float* bs2 = (const float*)d_in[24];
    const float* g2  = (const float*)d_in[25]; const float* be2 = (const float*)d_in[26];
    const float* Wsol = (const float*)d_in[27]; const float* bsol = (const float*)d_in[28];
    const float* Wfc1 = (const float*)d_in[29]; const float* bfc1 = (const float*)d_in[30];
    const float* gf   = (const float*)d_in[31]; const float* bf = (const float*)d_in[32];
    const float* Wfc2 = (const float*)d_in[33]; const float* bfc2 = (const float*)d_in[34];

    const int* srcp = eidx;
    const int* dstp = eidx + EE;

    // ---------------- workspace (peak ~155 MB) ----------------
    char* p = (char*)d_ws;
    auto alloc = [&](size_t bytes) -> char* {
        char* r = p;
        p += (bytes + 255) & ~(size_t)255;
        return r;
    };
    float* R0   = (float*)alloc((size_t)NN * 1024 * 4);  // h1 fp32 (1st half) -> h2 fp32
    short* h1b  = (short*)alloc((size_t)NN * 512 * 2);
    short* bufAb = (short*)alloc((size_t)NN * 1024 * 2); // q1b -> v1b -> q2b -> v2b
    short* bufBb = (short*)alloc((size_t)NN * 1024 * 2); // k1b -> k2b
    float* U    = (float*)alloc((size_t)NN * 64 * 4);
    short* Tb   = (short*)alloc((size_t)NN * 64 * 2);
    float* ab   = (float*)alloc((size_t)EE * 4 * 4);
    float* den  = (float*)alloc((size_t)NN * 4 * 4);
    short* wub  = (short*)alloc((size_t)1024 * 64 * 2);
    short* wq1t = (short*)alloc((size_t)512 * 64 * 2);
    short* wk1t = (short*)alloc((size_t)512 * 64 * 2);
    short* wv1t = (short*)alloc((size_t)512 * 64 * 2);
    short* ws1t = (short*)alloc((size_t)512 * 64 * 2);
    short* wq2t = (short*)alloc((size_t)1024 * 512 * 2);
    short* wk2t = (short*)alloc((size_t)1024 * 512 * 2);
    short* wv2t = (short*)alloc((size_t)1024 * 512 * 2);
    short* ws2t = (short*)alloc((size_t)1024 * 512 * 2);
    short* xb   = (short*)alloc((size_t)NN * 64 * 2);
    int* deg    = (int*)alloc((size_t)NN * 4);
    int* cursor = (int*)alloc((size_t)NN * 4);
    int* rs     = (int*)alloc((size_t)(NN + 1) * 4);
    int* eids   = (int*)alloc((size_t)EE * 4);
    float* bnA  = (float*)alloc(1024 * 4);
    float* bnB  = (float*)alloc(1024 * 4);
    float* z  = (float*)alloc((size_t)64 * 2176 * 4);
    float* y  = (float*)alloc((size_t)64 * 128 * 4);
    float* y2 = (float*)alloc((size_t)64 * 128 * 4);
    if ((size_t)(p - (char*)d_ws) > ws_size) return;  // refuse rather than fault

    float* h1 = R0;   // fp32, dead after bn_apply_relu_b16
    float* h2 = R0;   // fp32, live from skip2 onward

    const int GRM = (NN + 127) / 128;      // 118 MFMA row-tiles
    const int NWB = (NN * 64 + 255) / 256; // node-wave blocks
    dim3 blk(256);

    // ---------------- CSR + conversions ----------------
    hipMemsetAsync(deg, 0, (size_t)NN * 4, stream);
    count_deg<<<(EE + 255) / 256, blk, 0, stream>>>(dstp, deg, EE);
    scan_deg<<<1, 1024, 0, stream>>>(deg, rs, cursor, NN);
    fill_csr<<<(EE + 255) / 256, blk, 0, stream>>>(dstp, cursor, eids, EE);

    f2b_vec<<<(NN * 64 / 4 + 255) / 256, blk, 0, stream>>>(x, xb, NN * 64 / 4);
    f2b_T<<<dim3(512 / 32, 2), blk, 0, stream>>>(Wq1, wq1t, 64, 512);
    f2b_T<<<dim3(512 / 32, 2), blk, 0, stream>>>(Wk1, wk1t, 64, 512);
    f2b_T<<<dim3(512 / 32, 2), blk, 0, stream>>>(Wv1, wv1t, 64, 512);
    f2b_T<<<dim3(512 / 32, 2), blk, 0, stream>>>(Ws1, ws1t, 64, 512);
    f2b_T<<<dim3(1024 / 32, 512 / 32), blk, 0, stream>>>(Wq2, wq2t, 512, 1024);
    f2b_T<<<dim3(1024 / 32, 512 / 32), blk, 0, stream>>>(Wk2, wk2t, 512, 1024);
    f2b_T<<<dim3(1024 / 32, 512 / 32), blk, 0, stream>>>(Wv2, wv2t, 512, 1024);
    f2b_T<<<dim3(1024 / 32, 512 / 32), blk, 0, stream>>>(Ws2, ws2t, 512, 1024);

    hipMemsetAsync(bnA, 0, 1024 * 4, stream);
    hipMemsetAsync(bnB, 0, 1024 * 4, stream);

    // ---------------- layer 1 (D=512, C=128) ----------------
    gemm_mfma<true, false, true><<<dim3(4, GRM), blk, 0, stream>>>(xb, wq1t, bq1, bufAb, NN, 512, 64);  // q1b
    gemm_mfma<true, false, true><<<dim3(4, GRM), blk, 0, stream>>>(xb, wk1t, bk1, bufBb, NN, 512, 64);  // k1b
    node_u<128><<<NWB, blk, 0, stream>>>(bufAb, We1, U, NN);
    node_alpha<128><<<NWB, blk, 0, stream>>>(bufAb, bufBb, U, ea, srcp, rs, eids, ab, den, NN);
    gemm_mfma<true, false, true><<<dim3(4, GRM), blk, 0, stream>>>(xb, wv1t, bv1, bufAb, NN, 512, 64);  // v1b (q1b dead)
    gemm_mfma<true, false, false><<<dim3(4, GRM), blk, 0, stream>>>(xb, ws1t, bs1, h1, NN, 512, 64);    // skip1 fp32
    node_scatter<128><<<NWB, blk, 0, stream>>>(bufAb, ea, srcp, rs, eids, ab, den, h1, Tb, NN);
    build_wub<512, 128><<<(512 * 64 + 255) / 256, blk, 0, stream>>>(We1, wub);
    gemm_mfma<false, true, false><<<dim3(4, GRM), blk, 0, stream>>>(Tb, wub, nullptr, h1, NN, 512, 64); // h1 += T@Wt
    bn_stats<<<dim3(2, 64), blk, 0, stream>>>(h1, bnA, bnB, NN, 512);
    bn_finalize<<<2, blk, 0, stream>>>(bnA, bnB, g1, be1, NN, 512);
    bn_apply_relu_b16<<<NN * 512 / 4 / 256, blk, 0, stream>>>(h1, bnA, bnB, h1b, NN * 512 / 4, 512);

    // ---------------- layer 2 (D=1024, C=256) ----------------
    hipMemsetAsync(bnA, 0, 1024 * 4, stream);
    hipMemsetAsync(bnB, 0, 1024 * 4, stream);
    gemm_mfma<true, false, true><<<dim3(8, GRM), blk, 0, stream>>>(h1b, wq2t, bq2, bufAb, NN, 1024, 512); // q2b
    gemm_mfma<true, false, true><<<dim3(8, GRM), blk, 0, stream>>>(h1b, wk2t, bk2, bufBb, NN, 1024, 512); // k2b
    node_u<256><<<NWB, blk, 0, stream>>>(bufAb, We2, U, NN);
    node_alpha<256><<<NWB, blk, 0, stream>>>(bufAb, bufBb, U, ea, srcp, rs, eids, ab, den, NN);
    gemm_mfma<true, false, true><<<dim3(8, GRM), blk, 0, stream>>>(h1b, wv2t, bv2, bufAb, NN, 1024, 512); // v2b (q2b dead)
    gemm_mfma<true, false, false><<<dim3(8, GRM), blk, 0, stream>>>(h1b, ws2t, bs2, h2, NN, 1024, 512);   // skip2 fp32 (h1 dead)
    node_scatter<256><<<NWB, blk, 0, stream>>>(bufAb, ea, srcp, rs, eids, ab, den, h2, Tb, NN);
    build_wub<1024, 256><<<(1024 * 64 + 255) / 256, blk, 0, stream>>>(We2, wub);
    gemm_mfma<false, true, false><<<dim3(8, GRM), blk, 0, stream>>>(Tb, wub, nullptr, h2, NN, 1024, 64);  // h2 += T@Wt
    bn_stats<<<dim3(4, 64), blk, 0, stream>>>(h2, bnA, bnB, NN, 1024);
    bn_finalize<<<4, blk, 0, stream>>>(bnA, bnB, g2, be2, NN, 1024);
    bn_apply_relu_f32<<<NN * 1024 / 4 / 256, blk, 0, stream>>>(h2, bnA, bnB, NN * 1024 / 4, 1024);

    // ---------------- head ----------------
    pool_kernel<<<dim3(4, 64), blk, 0, stream>>>(h2, batch, z, NN, 1024, 2176);
    gemm_row<true><<<64, blk, 0, stream>>>(sol, Wsol, bsol, z + 2048, 128, 128, 128, 2176);
    gemm_row<false><<<64, blk, 0, stream>>>(z, Wfc1, bfc1, y, 128, 2176, 2176, 128);
    bn_small_apply<<<1, 128, 0, stream>>>(y, gf, bf, y2);
    fc2_small<<<1, 128, 0, stream>>>(y2, Wfc2, bfc2, (float*)d_out);
}

// Round 8
// 1127.270 us; speedup vs baseline: 11.0165x; 1.1107x over previous
//
#include <hip/hip_runtime.h>
#include <cstdint>
#include <cstddef>

#define DEV __device__ __forceinline__

static constexpr int NN = 15000;   // nodes
static constexpr int EE = 150000;  // edges
static constexpr int GG = 64;      // graphs

typedef __attribute__((ext_vector_type(8))) short bf16x8;
typedef __attribute__((ext_vector_type(4))) float f32x4;

DEV short f2b1(float f) {  // fp32 -> bf16 bits, round-nearest-even
    unsigned u = __float_as_uint(f);
    unsigned r = (u + 0x7fffu + ((u >> 16) & 1u)) >> 16;
    return (short)r;
}
DEV float b2f(short s) { return __uint_as_float(((unsigned)(unsigned short)s) << 16); }

// ======================= bf16 MFMA GEMM (128x128 tile) =======================
// C[M,N] = A[M,K](bf16) @ B[K,N] (+bias) (+=C) ; B given TRANSPOSED: Bt[N][K].
// 256 threads = 4 waves, each wave 64x64 (4x4 frags of 16x16). N%128==0, K%32==0.
template <bool BIAS, bool ACCUM, bool BF16OUT>
__global__ __launch_bounds__(256) void gemm_mfma(const short* __restrict__ A,
                                                 const short* __restrict__ Bt,
                                                 const float* __restrict__ bias,
                                                 void* __restrict__ Cv, int M, int N,
                                                 int K) {
    __shared__ short As[128][40];  // +8 pad: 80B row stride -> <=2-way bank alias
    __shared__ short Bs[128][40];
    const int tid = threadIdx.x;
    const int wid = tid >> 6, lane = tid & 63;
    const int wr = wid >> 1, wc = wid & 1;
    const int row0 = blockIdx.y * 128, col0 = blockIdx.x * 128;
    const int lrow = tid >> 1;          // 0..127
    const int lk = (tid & 1) * 16;      // 0 or 16
    f32x4 acc[4][4] = {};
    for (int k0 = 0; k0 < K; k0 += 32) {
        {   // stage A tile (zero-fill M tail)
            int gr = row0 + lrow;
            bf16x8 v0 = {}, v1 = {};
            if (gr < M) {
                const short* src = A + (size_t)gr * K + k0 + lk;
                v0 = *(const bf16x8*)(src);
                v1 = *(const bf16x8*)(src + 8);
            }
            *(bf16x8*)&As[lrow][lk] = v0;
            *(bf16x8*)&As[lrow][lk + 8] = v1;
        }
        {   // stage Bt tile (N multiple of 128)
            const short* src = Bt + (size_t)(col0 + lrow) * K + k0 + lk;
            *(bf16x8*)&Bs[lrow][lk] = *(const bf16x8*)(src);
            *(bf16x8*)&Bs[lrow][lk + 8] = *(const bf16x8*)(src + 8);
        }
        __syncthreads();
        const int kg = (lane >> 4) * 8;
        bf16x8 af[4], bf[4];
#pragma unroll
        for (int m = 0; m < 4; m++)
            af[m] = *(const bf16x8*)&As[wr * 64 + m * 16 + (lane & 15)][kg];
#pragma unroll
        for (int n = 0; n < 4; n++)
            bf[n] = *(const bf16x8*)&Bs[wc * 64 + n * 16 + (lane & 15)][kg];
#pragma unroll
        for (int m = 0; m < 4; m++)
#pragma unroll
            for (int n = 0; n < 4; n++)
                acc[m][n] = __builtin_amdgcn_mfma_f32_16x16x32_bf16(af[m], bf[n],
                                                                   acc[m][n], 0, 0, 0);
        __syncthreads();
    }
    // epilogue: C/D frag layout col=lane&15, row=(lane>>4)*4+reg
    const int colb = col0 + wc * 64 + (lane & 15);
    const int rowb = row0 + wr * 64 + (lane >> 4) * 4;
    float* Cf = (float*)Cv;
    short* Cb = (short*)Cv;
#pragma unroll
    for (int n = 0; n < 4; n++) {
        int gc = colb + n * 16;
        float bv = BIAS ? bias[gc] : 0.f;
#pragma unroll
        for (int m = 0; m < 4; m++) {
            int gr = rowb + m * 16;
#pragma unroll
            for (int r = 0; r < 4; r++) {
                if (gr + r < M) {
                    float v = acc[m][n][r] + bv;
                    if constexpr (ACCUM) v += Cf[(size_t)(gr + r) * N + gc];
                    if constexpr (BF16OUT)
                        Cb[(size_t)(gr + r) * N + gc] = f2b1(v);
                    else
                        Cf[(size_t)(gr + r) * N + gc] = v;
                }
            }
        }
    }
}

// ======================= bf16 MFMA GEMM (256x64 tile, fp32 out) =======================
// U[M,64] = A[M,K](bf16) @ Bt[64][K](bf16) + bias. 4 waves stacked in M.
__global__ __launch_bounds__(256) void gemm_mfma_n64(const short* __restrict__ A,
                                                     const short* __restrict__ Bt,
                                                     const float* __restrict__ bias,
                                                     float* __restrict__ C, int M,
                                                     int K) {
    __shared__ short As[256][40];
    __shared__ short Bs[64][40];
    const int tid = threadIdx.x;
    const int wid = tid >> 6, lane = tid & 63;
    const int row0 = blockIdx.x * 256;
    f32x4 acc[4][4] = {};
    for (int k0 = 0; k0 < K; k0 += 32) {
        {   // A: each thread stages one row's 32 elems
            int gr = row0 + tid;
            bf16x8 v0 = {}, v1 = {}, v2 = {}, v3 = {};
            if (gr < M) {
                const short* src = A + (size_t)gr * K + k0;
                v0 = *(const bf16x8*)(src);
                v1 = *(const bf16x8*)(src + 8);
                v2 = *(const bf16x8*)(src + 16);
                v3 = *(const bf16x8*)(src + 24);
            }
            *(bf16x8*)&As[tid][0] = v0;
            *(bf16x8*)&As[tid][8] = v1;
            *(bf16x8*)&As[tid][16] = v2;
            *(bf16x8*)&As[tid][24] = v3;
        }
        {   // B: 64 rows x 32 k
            int r = tid >> 2, c8 = (tid & 3) * 8;
            *(bf16x8*)&Bs[r][c8] = *(const bf16x8*)(Bt + (size_t)r * K + k0 + c8);
        }
        __syncthreads();
        const int kg = (lane >> 4) * 8;
        bf16x8 af[4], bfr[4];
#pragma unroll
        for (int m = 0; m < 4; m++)
            af[m] = *(const bf16x8*)&As[wid * 64 + m * 16 + (lane & 15)][kg];
#pragma unroll
        for (int n = 0; n < 4; n++)
            bfr[n] = *(const bf16x8*)&Bs[n * 16 + (lane & 15)][kg];
#pragma unroll
        for (int m = 0; m < 4; m++)
#pragma unroll
            for (int n = 0; n < 4; n++)
                acc[m][n] = __builtin_amdgcn_mfma_f32_16x16x32_bf16(af[m], bfr[n],
                                                                   acc[m][n], 0, 0, 0);
        __syncthreads();
    }
    const int colb = lane & 15;
    const int rowb = row0 + wid * 64 + (lane >> 4) * 4;
#pragma unroll
    for (int n = 0; n < 4; n++) {
        int gc = colb + n * 16;
        float bv = bias[gc];
#pragma unroll
        for (int m = 0; m < 4; m++) {
            int gr = rowb + m * 16;
#pragma unroll
            for (int r = 0; r < 4; r++)
                if (gr + r < M) C[(size_t)(gr + r) * 64 + gc] = acc[m][n][r] + bv;
        }
    }
}

// ======================= combined U-weights: (Wq@Wu) and bq@Wu =======================
// out[hf][kk] (Bt layout [64][K]) = sum_c Wq[kk, h*C+c] * We[f, h*C+c]
template <int C, int K>
__global__ __launch_bounds__(256) void wqu_combine(const float* __restrict__ Wq,
                                                   const float* __restrict__ We,
                                                   short* __restrict__ out) {
    int i = blockIdx.x * 256 + threadIdx.x;
    if (i >= 64 * K) return;
    int hf = i / K, kk = i - hf * K;
    int h = hf >> 4, f = hf & 15;
    const float* wq = Wq + (size_t)kk * (4 * C) + h * C;
    const float* we = We + (size_t)f * (4 * C) + h * C;
    float s0 = 0.f, s1 = 0.f, s2 = 0.f, s3 = 0.f;
    for (int c = 0; c < C; c += 4) {
        float4 a = *(const float4*)(wq + c);
        float4 b = *(const float4*)(we + c);
        s0 = fmaf(a.x, b.x, s0);
        s1 = fmaf(a.y, b.y, s1);
        s2 = fmaf(a.z, b.z, s2);
        s3 = fmaf(a.w, b.w, s3);
    }
    out[i] = f2b1((s0 + s1) + (s2 + s3));
}
template <int C>
__global__ void bu_combine(const float* __restrict__ bq, const float* __restrict__ We,
                           float* __restrict__ bu) {
    int hf = threadIdx.x;  // 64
    int h = hf >> 4, f = hf & 15;
    float s = 0.f;
    for (int c = 0; c < C; c++) s = fmaf(bq[h * C + c], We[(size_t)f * 4 * C + h * C + c], s);
    bu[hf] = s;
}

// ======================= small-M row GEMM (head) =======================
template <bool RELU>
__global__ __launch_bounds__(256) void gemm_row(const float* __restrict__ A,
                                                const float* __restrict__ B,
                                                const float* __restrict__ bias,
                                                float* __restrict__ C, int N, int K,
                                                int lda, int ldc) {
    int g = blockIdx.x;
    int col = threadIdx.x & 127;
    int half = threadIdx.x >> 7;
    int kh = K >> 1;
    int k0 = half * kh, k1 = k0 + kh;
    const float* a = A + (size_t)g * lda;
    float s0 = 0.f, s1 = 0.f, s2 = 0.f, s3 = 0.f;
    int kk = k0;
    for (; kk + 4 <= k1; kk += 4) {
        s0 = fmaf(a[kk], B[(size_t)kk * N + col], s0);
        s1 = fmaf(a[kk + 1], B[(size_t)(kk + 1) * N + col], s1);
        s2 = fmaf(a[kk + 2], B[(size_t)(kk + 2) * N + col], s2);
        s3 = fmaf(a[kk + 3], B[(size_t)(kk + 3) * N + col], s3);
    }
    for (; kk < k1; kk++) s0 = fmaf(a[kk], B[(size_t)kk * N + col], s0);
    float s = (s0 + s1) + (s2 + s3);
    __shared__ float red[128];
    if (half == 1) red[col] = s;
    __syncthreads();
    if (half == 0) {
        s += red[col] + bias[col];
        if (RELU) s = fmaxf(s, 0.f);
        C[(size_t)g * ldc + col] = s;
    }
}

// ======================= conversions =======================
__global__ __launch_bounds__(256) void f2b_vec(const float* __restrict__ in,
                                               short* __restrict__ out, int n4) {
    int i = blockIdx.x * 256 + threadIdx.x;
    if (i >= n4) return;
    float4 v = ((const float4*)in)[i];
    short4 o;
    o.x = f2b1(v.x); o.y = f2b1(v.y); o.z = f2b1(v.z); o.w = f2b1(v.w);
    ((short4*)out)[i] = o;
}
// W[K,N] fp32 -> Wt[N,K] bf16 via 32x32 LDS tile (coalesced both sides)
__global__ __launch_bounds__(256) void f2b_T(const float* __restrict__ in,
                                             short* __restrict__ out, int K, int N) {
    __shared__ short tile[32][33];
    int kb = blockIdx.y * 32, nb = blockIdx.x * 32;
    int tx = threadIdx.x & 31, ty = threadIdx.x >> 5;  // 8 rows per pass
#pragma unroll
    for (int i = 0; i < 32; i += 8) {
        int kk = kb + ty + i, n = nb + tx;
        if (kk < K && n < N) tile[ty + i][tx] = f2b1(in[(size_t)kk * N + n]);
    }
    __syncthreads();
#pragma unroll
    for (int i = 0; i < 32; i += 8) {
        int n = nb + ty + i, kk = kb + tx;
        if (n < N && kk < K) out[(size_t)n * K + kk] = tile[tx][ty + i];
    }
}
// block-diag expansion of We as Bt-layout bf16: out[d][h'*16+f] = (head(d)==h')?We[f][d]:0
template <int D, int C>
__global__ __launch_bounds__(256) void build_wub(const float* __restrict__ We,
                                                 short* __restrict__ out) {
    int i = blockIdx.x * 256 + threadIdx.x;
    if (i >= D * 64) return;
    int d = i >> 6, hf = i & 63;
    int hp = hf >> 4, f = hf & 15;
    float v = ((d / C) == hp) ? We[(size_t)f * D + d] : 0.f;
    out[i] = f2b1(v);
}

// ======================= CSR build (by dst) =======================
__global__ __launch_bounds__(256) void count_deg(const int* __restrict__ dst,
                                                 int* __restrict__ deg, int E) {
    int e = blockIdx.x * 256 + threadIdx.x;
    if (e < E) atomicAdd(&deg[dst[e]], 1);
}

__global__ __launch_bounds__(1024) void scan_deg(const int* __restrict__ deg,
                                                 int* __restrict__ rs,
                                                 int* __restrict__ cursor, int n) {
    __shared__ int part[1024];
    int t = threadIdx.x;
    int ch = (n + 1023) / 1024;
    int b0 = min(t * ch, n), b1 = min(b0 + ch, n);
    int s = 0;
    for (int i = b0; i < b1; i++) s += deg[i];
    part[t] = s;
    __syncthreads();
    for (int off = 1; off < 1024; off <<= 1) {
        int tmp = (t >= off) ? part[t - off] : 0;
        __syncthreads();
        part[t] += tmp;
        __syncthreads();
    }
    int run = part[t] - s;
    for (int i = b0; i < b1; i++) {
        rs[i] = run;
        cursor[i] = run;
        run += deg[i];
    }
    if (t == 1023) rs[n] = part[1023];
}

__global__ __launch_bounds__(256) void fill_csr(const int* __restrict__ dst,
                                                int* __restrict__ cursor,
                                                int* __restrict__ eids, int E) {
    int e = blockIdx.x * 256 + threadIdx.x;
    if (e < E) {
        int pos = atomicAdd(&cursor[dst[e]], 1);
        eids[pos] = e;
    }
}

// ======================= per-node attention =======================
// Pass A: fused alpha + segment softmax (per-node wave, no atomics)
template <int C>
__global__ __launch_bounds__(256) void node_alpha(
    const short* __restrict__ q, const short* __restrict__ k,
    const float* __restrict__ U, const float* __restrict__ ea,
    const int* __restrict__ src, const int* __restrict__ rs,
    const int* __restrict__ eids, float* __restrict__ ab,
    float* __restrict__ den, int Nn) {
    constexpr int D = 4 * C;
    constexpr int P = D / 64;
    int node = (blockIdx.x * 256 + threadIdx.x) >> 6;
    int lane = threadIdx.x & 63;
    if (node >= Nn) return;
    int e0 = rs[node], e1 = rs[node + 1];
    float qr[P];
    const short* qp = q + (size_t)node * D + lane * P;
#pragma unroll
    for (int j0 = 0; j0 < P; j0 += 8) {
        bf16x8 v = *(const bf16x8*)(qp + j0);
#pragma unroll
        for (int j = 0; j < 8; j++) qr[j0 + j] = b2f(v[j]);
    }
    float Urow = U[(size_t)node * 64 + lane];
    const float rsC = rsqrtf((float)C);
    float m = -3.402823466e38f;
    for (int ii = e0; ii < e1; ii++) {
        int e = eids[ii];
        int s = src[e];
        float val = ea[(size_t)e * 16 + (lane & 15)] * Urow;
        const short* kp = k + (size_t)s * D + lane * P;
#pragma unroll
        for (int j0 = 0; j0 < P; j0 += 8) {
            bf16x8 kv = *(const bf16x8*)(kp + j0);
#pragma unroll
            for (int j = 0; j < 8; j++) val = fmaf(qr[j0 + j], b2f(kv[j]), val);
        }
#pragma unroll
        for (int off = 1; off < 16; off <<= 1) val += __shfl_xor(val, off);
        val *= rsC;
        if ((lane & 15) == 0) ab[(size_t)ii * 4 + (lane >> 4)] = val;
        m = fmaxf(m, val);
    }
    float dsum = 0.f;
    for (int ii = e0; ii < e1; ii++) {
        float a = ab[(size_t)ii * 4 + (lane >> 4)];
        float ex = __expf(a - m);
        dsum += ex;
        if ((lane & 15) == 0) ab[(size_t)ii * 4 + (lane >> 4)] = ex;
    }
    if ((lane & 15) == 0) den[(size_t)node * 4 + (lane >> 4)] = dsum;
}

// Pass B: h[node] += (sum ex*v[src])/den (fp32);  Tb[node] = (sum ex*ea)/den (bf16)
template <int C>
__global__ __launch_bounds__(256) void node_scatter(
    const short* __restrict__ v, const float* __restrict__ ea,
    const int* __restrict__ src, const int* __restrict__ rs,
    const int* __restrict__ eids, const float* __restrict__ ab,
    const float* __restrict__ den, float* __restrict__ hout,
    short* __restrict__ Tb, int Nn) {
    constexpr int D = 4 * C;
    constexpr int P = D / 64;
    int node = (blockIdx.x * 256 + threadIdx.x) >> 6;
    int lane = threadIdx.x & 63;
    if (node >= Nn) return;
    int e0 = rs[node], e1 = rs[node + 1];
    float acc[P] = {};
    float tacc = 0.f;
    for (int ii = e0; ii < e1; ii++) {
        int e = eids[ii];
        int s = src[e];
        float ex = ab[(size_t)ii * 4 + (lane >> 4)];
        tacc = fmaf(ex, ea[(size_t)e * 16 + (lane & 15)], tacc);
        const short* vp = v + (size_t)s * D + lane * P;
#pragma unroll
        for (int j0 = 0; j0 < P; j0 += 8) {
            bf16x8 t8 = *(const bf16x8*)(vp + j0);
#pragma unroll
            for (int j = 0; j < 8; j++) acc[j0 + j] = fmaf(ex, b2f(t8[j]), acc[j0 + j]);
        }
    }
    float inv = 1.f / (den[(size_t)node * 4 + (lane >> 4)] + 1e-16f);
    Tb[(size_t)node * 64 + lane] = f2b1(tacc * inv);
    float* hp = hout + (size_t)node * D + lane * P;
#pragma unroll
    for (int j = 0; j < P; j += 4) {
        float4 t4 = *(float4*)(hp + j);
        t4.x = fmaf(acc[j], inv, t4.x);
        t4.y = fmaf(acc[j + 1], inv, t4.y);
        t4.z = fmaf(acc[j + 2], inv, t4.z);
        t4.w = fmaf(acc[j + 3], inv, t4.w);
        *(float4*)(hp + j) = t4;
    }
}

// ======================= batch norm =======================
__global__ __launch_bounds__(256) void bn_stats(const float* __restrict__ h,
                                                float* __restrict__ s1,
                                                float* __restrict__ s2, int Nrows,
                                                int D) {
    int col = blockIdx.x * 256 + threadIdx.x;
    int chunk = (Nrows + gridDim.y - 1) / gridDim.y;
    int r0 = blockIdx.y * chunk;
    int r1 = min(r0 + chunk, Nrows);
    float a = 0.f, b = 0.f;
    for (int r = r0; r < r1; r++) {
        float v = h[(size_t)r * D + col];
        a += v;
        b += v * v;
    }
    atomicAdd(&s1[col], a);
    atomicAdd(&s2[col], b);
}
__global__ void bn_finalize(float* __restrict__ s1, float* __restrict__ s2,
                            const float* __restrict__ g, const float* __restrict__ b,
                            int Nrows, int D) {
    int c = blockIdx.x * 256 + threadIdx.x;
    if (c >= D) return;
    float mean = s1[c] / (float)Nrows;
    float var = fmaxf(s2[c] / (float)Nrows - mean * mean, 0.f);
    float scale = g[c] / sqrtf(var + 1e-5f);
    s1[c] = scale;
    s2[c] = b[c] - mean * scale;
}
__global__ __launch_bounds__(256) void bn_apply_relu_f32(float* __restrict__ h,
                                                         const float* __restrict__ scale,
                                                         const float* __restrict__ shift,
                                                         int total4, int D) {
    int i = blockIdx.x * 256 + threadIdx.x;
    if (i >= total4) return;
    float4 v = ((float4*)h)[i];
    int c = (i * 4) % D;
    v.x = fmaxf(fmaf(v.x, scale[c], shift[c]), 0.f);
    v.y = fmaxf(fmaf(v.y, scale[c + 1], shift[c + 1]), 0.f);
    v.z = fmaxf(fmaf(v.z, scale[c + 2], shift[c + 2]), 0.f);
    v.w = fmaxf(fmaf(v.w, scale[c + 3], shift[c + 3]), 0.f);
    ((float4*)h)[i] = v;
}
__global__ __launch_bounds__(256) void bn_apply_relu_b16(const float* __restrict__ h,
                                                         const float* __restrict__ scale,
                                                         const float* __restrict__ shift,
                                                         short* __restrict__ out,
                                                         int total4, int D) {
    int i = blockIdx.x * 256 + threadIdx.x;
    if (i >= total4) return;
    float4 v = ((const float4*)h)[i];
    int c = (i * 4) % D;
    short4 o;
    o.x = f2b1(fmaxf(fmaf(v.x, scale[c], shift[c]), 0.f));
    o.y = f2b1(fmaxf(fmaf(v.y, scale[c + 1], shift[c + 1]), 0.f));
    o.z = f2b1(fmaxf(fmaf(v.z, scale[c + 2], shift[c + 2]), 0.f));
    o.w = f2b1(fmaxf(fmaf(v.w, scale[c + 3], shift[c + 3]), 0.f));
    ((short4*)out)[i] = o;
}

// ======================= pooling (batch is sorted) =======================
__global__ __launch_bounds__(256) void pool_kernel(const float* __restrict__ h,
                                                   const int* __restrict__ batch,
                                                   float* __restrict__ z, int Nrows,
                                                   int D, int ldz) {
    int g = blockIdx.y;
    int c = blockIdx.x * 256 + threadIdx.x;
    int lo = 0, hi = Nrows;
    while (lo < hi) {
        int m = (lo + hi) >> 1;
        if (batch[m] < g) lo = m + 1; else hi = m;
    }
    int s0 = lo;
    hi = Nrows;
    while (lo < hi) {
        int m = (lo + hi) >> 1;
        if (batch[m] < g + 1) lo = m + 1; else hi = m;
    }
    int s1 = lo;
    float sum = 0.f, mx = -3.402823466e38f;
    for (int r = s0; r < s1; r++) {
        float v = h[(size_t)r * D + c];
        sum += v;
        mx = fmaxf(mx, v);
    }
    int cnt = s1 - s0;
    z[(size_t)g * ldz + c] = sum / (float)max(cnt, 1);
    z[(size_t)g * ldz + D + c] = (cnt > 0) ? mx : 0.f;
}

// ======================= tiny MLP head =======================
__global__ __launch_bounds__(128) void bn_small_apply(const float* __restrict__ y,
                                                      const float* __restrict__ g,
                                                      const float* __restrict__ b,
                                                      float* __restrict__ y2) {
    int c = threadIdx.x;
    float m = 0.f;
    for (int r = 0; r < 64; r++) m += y[r * 128 + c];
    m *= (1.f / 64.f);
    float v = 0.f;
    for (int r = 0; r < 64; r++) {
        float d = y[r * 128 + c] - m;
        v += d * d;
    }
    v *= (1.f / 64.f);
    float sc = g[c] / sqrtf(v + 1e-5f);
    float sh = b[c] - m * sc;
    for (int r = 0; r < 64; r++) y2[r * 128 + c] = fmaxf(fmaf(y[r * 128 + c], sc, sh), 0.f);
}
__global__ __launch_bounds__(128) void fc2_small(const float* __restrict__ y2,
                                                 const float* __restrict__ W,
                                                 const float* __restrict__ b,
                                                 float* __restrict__ out) {
    int t = threadIdx.x;
    int g = t >> 1, o = t & 1;
    float s = b[o];
    for (int kk = 0; kk < 128; kk++) s = fmaf(y2[g * 128 + kk], W[kk * 2 + o], s);
    out[g * 2 + o] = s;
}

// ======================= launch =======================
extern "C" void kernel_launch(void* const* d_in, const int* in_sizes, int n_in,
                              void* d_out, int out_size, void* d_ws, size_t ws_size,
                              hipStream_t stream) {
    const float* x     = (const float*)d_in[0];
    const float* ea    = (const float*)d_in[1];
    const float* sol   = (const float*)d_in[2];
    const int*   eidx  = (const int*)d_in[3];
    const int*   batch = (const int*)d_in[4];
    const float* Wq1 = (const float*)d_in[5];  const float* bq1 = (const float*)d_in[6];
    const float* Wk1 = (const float*)d_in[7];  const float* bk1 = (const float*)d_in[8];
    const float* Wv1 = (const float*)d_in[9];  const float* bv1 = (const float*)d_in[10];
    const float* We1 = (const float*)d_in[11];
    const float* Ws1 = (const float*)d_in[12]; const float* bs1 = (const float*)d_in[13];
    const float* g1  = (const float*)d_in[14]; const float* be1 = (const float*)d_in[15];
    const float* Wq2 = (const float*)d_in[16]; const float* bq2 = (const float*)d_in[17];
    const float* Wk2 = (const float*)d_in[18]; const float* bk2 = (const float*)d_in[19];
    const float* Wv2 = (const float*)d_in[20]; const float* bv2 = (const float*)d_in[21];
    const float* We2 = (const float*)d_in[22];
    const float* Ws2 = (const float*)d_in[23]; const float* bs2 = (const float*)d_in[24];
    const float* g2  = (const float*)d_in[25]; const float* be2 = (const float*)d_in[26];
    const float* Wsol = (const float*)d_in[27]; const float* bsol = (const float*)d_in[28];
    const float* Wfc1 = (const float*)d_in[29]; const float* bfc1 = (const float*)d_in[30];
    const float* gf   = (const float*)d_in[31]; const float* bf = (const float*)d_in[32];
    const float* Wfc2 = (const float*)d_in[33]; const float* bfc2 = (const float*)d_in[34];

    const int* srcp = eidx;
    const int* dstp = eidx + EE;

    // ---------------- workspace (peak ~155 MB) ----------------
    char* p = (char*)d_ws;
    auto alloc = [&](size_t bytes) -> char* {
        char* r = p;
        p += (bytes + 255) & ~(size_t)255;
        return r;
    };
    float* R0   = (float*)alloc((size_t)NN * 1024 * 4);  // h1 fp32 (1st half) -> h2 fp32
    short* h1b  = (short*)alloc((size_t)NN * 512 * 2);
    short* bufAb = (short*)alloc((size_t)NN * 1024 * 2); // q1b -> v1b -> q2b -> v2b
    short* bufBb = (short*)alloc((size_t)NN * 1024 * 2); // k1b -> k2b
    float* U    = (float*)alloc((size_t)NN * 64 * 4);
    short* Tb   = (short*)alloc((size_t)NN * 64 * 2);
    float* ab   = (float*)alloc((size_t)EE * 4 * 4);
    float* den  = (float*)alloc((size_t)NN * 4 * 4);
    short* wub  = (short*)alloc((size_t)1024 * 64 * 2);
    short* wq1t = (short*)alloc((size_t)512 * 64 * 2);
    short* wk1t = (short*)alloc((size_t)512 * 64 * 2);
    short* wv1t = (short*)alloc((size_t)512 * 64 * 2);
    short* ws1t = (short*)alloc((size_t)512 * 64 * 2);
    short* wq2t = (short*)alloc((size_t)1024 * 512 * 2);
    short* wk2t = (short*)alloc((size_t)1024 * 512 * 2);
    short* wv2t = (short*)alloc((size_t)1024 * 512 * 2);
    short* ws2t = (short*)alloc((size_t)1024 * 512 * 2);
    short* xb   = (short*)alloc((size_t)NN * 64 * 2);
    short* wqu1t = (short*)alloc((size_t)64 * 64 * 2);
    short* wqu2t = (short*)alloc((size_t)64 * 512 * 2);
    float* bu1  = (float*)alloc(64 * 4);
    float* bu2  = (float*)alloc(64 * 4);
    int* deg    = (int*)alloc((size_t)NN * 4);
    int* cursor = (int*)alloc((size_t)NN * 4);
    int* rs     = (int*)alloc((size_t)(NN + 1) * 4);
    int* eids   = (int*)alloc((size_t)EE * 4);
    float* bnA  = (float*)alloc(1024 * 4);
    float* bnB  = (float*)alloc(1024 * 4);
    float* z  = (float*)alloc((size_t)64 * 2176 * 4);
    float* y  = (float*)alloc((size_t)64 * 128 * 4);
    float* y2 = (float*)alloc((size_t)64 * 128 * 4);
    if ((size_t)(p - (char*)d_ws) > ws_size) return;  // refuse rather than fault

    float* h1 = R0;   // fp32, dead after bn_apply_relu_b16
    float* h2 = R0;   // fp32, live from skip2 onward

    const int GRM = (NN + 127) / 128;       // 118 MFMA row-tiles
    const int GRU = (NN + 255) / 256;       // 59 U-GEMM row-tiles
    const int NWB = (NN * 64 + 255) / 256;  // node-wave blocks
    dim3 blk(256);

    // ---------------- CSR + conversions + weight prep ----------------
    hipMemsetAsync(deg, 0, (size_t)NN * 4, stream);
    count_deg<<<(EE + 255) / 256, blk, 0, stream>>>(dstp, deg, EE);
    scan_deg<<<1, 1024, 0, stream>>>(deg, rs, cursor, NN);
    fill_csr<<<(EE + 255) / 256, blk, 0, stream>>>(dstp, cursor, eids, EE);

    f2b_vec<<<(NN * 64 / 4 + 255) / 256, blk, 0, stream>>>(x, xb, NN * 64 / 4);
    f2b_T<<<dim3(512 / 32, 2), blk, 0, stream>>>(Wq1, wq1t, 64, 512);
    f2b_T<<<dim3(512 / 32, 2), blk, 0, stream>>>(Wk1, wk1t, 64, 512);
    f2b_T<<<dim3(512 / 32, 2), blk, 0, stream>>>(Wv1, wv1t, 64, 512);
    f2b_T<<<dim3(512 / 32, 2), blk, 0, stream>>>(Ws1, ws1t, 64, 512);
    f2b_T<<<dim3(1024 / 32, 512 / 32), blk, 0, stream>>>(Wq2, wq2t, 512, 1024);
    f2b_T<<<dim3(1024 / 32, 512 / 32), blk, 0, stream>>>(Wk2, wk2t, 512, 1024);
    f2b_T<<<dim3(1024 / 32, 512 / 32), blk, 0, stream>>>(Wv2, wv2t, 512, 1024);
    f2b_T<<<dim3(1024 / 32, 512 / 32), blk, 0, stream>>>(Ws2, ws2t, 512, 1024);
    wqu_combine<128, 64><<<(64 * 64 + 255) / 256, blk, 0, stream>>>(Wq1, We1, wqu1t);
    wqu_combine<256, 512><<<(64 * 512 + 255) / 256, blk, 0, stream>>>(Wq2, We2, wqu2t);
    bu_combine<128><<<1, 64, 0, stream>>>(bq1, We1, bu1);
    bu_combine<256><<<1, 64, 0, stream>>>(bq2, We2, bu2);

    hipMemsetAsync(bnA, 0, 1024 * 4, stream);
    hipMemsetAsync(bnB, 0, 1024 * 4, stream);

    // ---------------- layer 1 (D=512, C=128) ----------------
    gemm_mfma<true, false, true><<<dim3(4, GRM), blk, 0, stream>>>(xb, wq1t, bq1, bufAb, NN, 512, 64);  // q1b
    gemm_mfma<true, false, true><<<dim3(4, GRM), blk, 0, stream>>>(xb, wk1t, bk1, bufBb, NN, 512, 64);  // k1b
    gemm_mfma_n64<<<GRU, blk, 0, stream>>>(xb, wqu1t, bu1, U, NN, 64);                                  // U1
    node_alpha<128><<<NWB, blk, 0, stream>>>(bufAb, bufBb, U, ea, srcp, rs, eids, ab, den, NN);
    gemm_mfma<true, false, true><<<dim3(4, GRM), blk, 0, stream>>>(xb, wv1t, bv1, bufAb, NN, 512, 64);  // v1b (q1b dead)
    gemm_mfma<true, false, false><<<dim3(4, GRM), blk, 0, stream>>>(xb, ws1t, bs1, h1, NN, 512, 64);    // skip1 fp32
    node_scatter<128><<<NWB, blk, 0, stream>>>(bufAb, ea, srcp, rs, eids, ab, den, h1, Tb, NN);
    build_wub<512, 128><<<(512 * 64 + 255) / 256, blk, 0, stream>>>(We1, wub);
    gemm_mfma<false, true, false><<<dim3(4, GRM), blk, 0, stream>>>(Tb, wub, nullptr, h1, NN, 512, 64); // h1 += T@Wt
    bn_stats<<<dim3(2, 64), blk, 0, stream>>>(h1, bnA, bnB, NN, 512);
    bn_finalize<<<2, blk, 0, stream>>>(bnA, bnB, g1, be1, NN, 512);
    bn_apply_relu_b16<<<NN * 512 / 4 / 256, blk, 0, stream>>>(h1, bnA, bnB, h1b, NN * 512 / 4, 512);

    // ---------------- layer 2 (D=1024, C=256) ----------------
    hipMemsetAsync(bnA, 0, 1024 * 4, stream);
    hipMemsetAsync(bnB, 0, 1024 * 4, stream);
    gemm_mfma<true, false, true><<<dim3(8, GRM), blk, 0, stream>>>(h1b, wq2t, bq2, bufAb, NN, 1024, 512); // q2b
    gemm_mfma<true, false, true><<<dim3(8, GRM), blk, 0, stream>>>(h1b, wk2t, bk2, bufBb, NN, 1024, 512); // k2b
    gemm_mfma_n64<<<GRU, blk, 0, stream>>>(h1b, wqu2t, bu2, U, NN, 512);                                  // U2
    node_alpha<256><<<NWB, blk, 0, stream>>>(bufAb, bufBb, U, ea, srcp, rs, eids, ab, den, NN);
    gemm_mfma<true, false, true><<<dim3(8, GRM), blk, 0, stream>>>(h1b, wv2t, bv2, bufAb, NN, 1024, 512); // v2b (q2b dead)
    gemm_mfma<true, false, false><<<dim3(8, GRM), blk, 0, stream>>>(h1b, ws2t, bs2, h2, NN, 1024, 512);   // skip2 fp32 (h1 dead)
    node_scatter<256><<<NWB, blk, 0, stream>>>(bufAb, ea, srcp, rs, eids, ab, den, h2, Tb, NN);
    build_wub<1024, 256><<<(1024 * 64 + 255) / 256, blk, 0, stream>>>(We2, wub);
    gemm_mfma<false, true, false><<<dim3(8, GRM), blk, 0, stream>>>(Tb, wub, nullptr, h2, NN, 1024, 64);  // h2 += T@Wt
    bn_stats<<<dim3(4, 64), blk, 0, stream>>>(h2, bnA, bnB, NN, 1024);
    bn_finalize<<<4, blk, 0, stream>>>(bnA, bnB, g2, be2, NN, 1024);
    bn_apply_relu_f32<<<NN * 1024 / 4 / 256, blk, 0, stream>>>(h2, bnA, bnB, NN * 1024 / 4, 1024);

    // ---------------- head ----------------
    pool_kernel<<<dim3(4, 64), blk, 0, stream>>>(h2, batch, z, NN, 1024, 2176);
    gemm_row<true><<<64, blk, 0, stream>>>(sol, Wsol, bsol, z + 2048, 128, 128, 128, 2176);
    gemm_row<false><<<64, blk, 0, stream>>>(z, Wfc1, bfc1, y, 128, 2176, 2176, 128);
    bn_small_apply<<<1, 128, 0, stream>>>(y, gf, bf, y2);
    fc2_small<<<1, 128, 0, stream>>>(y2, Wfc2, bfc2, (float*)d_out);
}

// Round 10
// 1042.967 us; speedup vs baseline: 11.9070x; 1.0808x over previous
//
#include <hip/hip_runtime.h>
#include <cstdint>
#include <cstddef>

#define DEV __device__ __forceinline__

static constexpr int NN = 15000;   // nodes
static constexpr int EE = 150000;  // edges
static constexpr int GG = 64;      // graphs

typedef __attribute__((ext_vector_type(8))) short bf16x8;
typedef __attribute__((ext_vector_type(4))) float f32x4;

DEV short f2b1(float f) {  // fp32 -> bf16 bits, round-nearest-even
    unsigned u = __float_as_uint(f);
    unsigned r = (u + 0x7fffu + ((u >> 16) & 1u)) >> 16;
    return (short)r;
}
DEV float b2f(short s) { return __uint_as_float(((unsigned)(unsigned short)s) << 16); }

// ======================= bf16 MFMA GEMM (128x128 tile) =======================
// C[M,N] = A[M,K](bf16) @ B[K,N] (+bias) (+=C) ; B given TRANSPOSED: Bt[N][K].
// 256 threads = 4 waves, each wave 64x64 (4x4 frags of 16x16). N%128==0, K%32==0.
// Staging via global_load_lds(16B): linear LDS [128][32] shorts; chunk swizzle
// p = c ^ ((row>>1)&3) applied on the global SOURCE and on the LDS READ side.
template <bool BIAS, bool ACCUM, bool BF16OUT>
__global__ __launch_bounds__(256) void gemm_mfma(const short* __restrict__ A,
                                                 const short* __restrict__ Bt,
                                                 const float* __restrict__ bias,
                                                 void* __restrict__ Cv, int M, int N,
                                                 int K) {
    __shared__ short As[128 * 32];
    __shared__ short Bs[128 * 32];
    const int tid = threadIdx.x;
    const int wid = tid >> 6, lane = tid & 63;
    const int wr = wid >> 1, wc = wid & 1;
    const int row0 = blockIdx.y * 128, col0 = blockIdx.x * 128;

    // staging geometry: op o (0..7) covers rows o*16..o*16+15 of the tile;
    // lane l -> row_local = o*16 + (l>>2), physical chunk = l&3,
    // logical k-chunk = (l&3) ^ (((row)>>1)&3). Wave w issues ops {2w, 2w+1}.
    const int o0 = wid * 2, o1 = wid * 2 + 1;
    const int rA0 = o0 * 16 + (lane >> 2), rA1 = o1 * 16 + (lane >> 2);
    const int c0 = (lane & 3) ^ ((rA0 >> 1) & 3);
    const int c1 = (lane & 3) ^ ((rA1 >> 1) & 3);
    const short* gA0 = A + (size_t)(row0 + rA0) * K + c0 * 8;
    const short* gA1 = A + (size_t)(row0 + rA1) * K + c1 * 8;
    const short* gB0 = Bt + (size_t)(col0 + rA0) * K + c0 * 8;
    const short* gB1 = Bt + (size_t)(col0 + rA1) * K + c1 * 8;
    const bool okA0 = (row0 + rA0) < M, okA1 = (row0 + rA1) < M;

    f32x4 acc[4][4] = {};
    for (int k0 = 0; k0 < K; k0 += 32) {
        if (okA0) __builtin_amdgcn_global_load_lds(gA0 + k0, &As[o0 * 512], 16, 0, 0);
        if (okA1) __builtin_amdgcn_global_load_lds(gA1 + k0, &As[o1 * 512], 16, 0, 0);
        __builtin_amdgcn_global_load_lds(gB0 + k0, &Bs[o0 * 512], 16, 0, 0);
        __builtin_amdgcn_global_load_lds(gB1 + k0, &Bs[o1 * 512], 16, 0, 0);
        __syncthreads();
        const int kg4 = lane >> 4;  // which 8-elem k-chunk this lane consumes
        bf16x8 af[4], bfv[4];
#pragma unroll
        for (int m = 0; m < 4; m++) {
            int ar = wr * 64 + m * 16 + (lane & 15);
            af[m] = *(const bf16x8*)&As[ar * 32 + (kg4 ^ ((ar >> 1) & 3)) * 8];
        }
#pragma unroll
        for (int n = 0; n < 4; n++) {
            int br = wc * 64 + n * 16 + (lane & 15);
            bfv[n] = *(const bf16x8*)&Bs[br * 32 + (kg4 ^ ((br >> 1) & 3)) * 8];
        }
#pragma unroll
        for (int m = 0; m < 4; m++)
#pragma unroll
            for (int n = 0; n < 4; n++)
                acc[m][n] = __builtin_amdgcn_mfma_f32_16x16x32_bf16(af[m], bfv[n],
                                                                   acc[m][n], 0, 0, 0);
        __syncthreads();
    }
    // epilogue: C/D frag layout col=lane&15, row=(lane>>4)*4+reg
    const int colb = col0 + wc * 64 + (lane & 15);
    const int rowb = row0 + wr * 64 + (lane >> 4) * 4;
    float* Cf = (float*)Cv;
    short* Cb = (short*)Cv;
#pragma unroll
    for (int n = 0; n < 4; n++) {
        int gc = colb + n * 16;
        float bv = BIAS ? bias[gc] : 0.f;
#pragma unroll
        for (int m = 0; m < 4; m++) {
            int gr = rowb + m * 16;
#pragma unroll
            for (int r = 0; r < 4; r++) {
                if (gr + r < M) {
                    float v = acc[m][n][r] + bv;
                    if constexpr (ACCUM) v += Cf[(size_t)(gr + r) * N + gc];
                    if constexpr (BF16OUT)
                        Cb[(size_t)(gr + r) * N + gc] = f2b1(v);
                    else
                        Cf[(size_t)(gr + r) * N + gc] = v;
                }
            }
        }
    }
}

// ======================= bf16 MFMA GEMM (256x64 tile, fp32 out) =======================
// U[M,64] = A[M,K](bf16) @ Bt[64][K](bf16) + bias. 4 waves stacked in M.
__global__ __launch_bounds__(256) void gemm_mfma_n64(const short* __restrict__ A,
                                                     const short* __restrict__ Bt,
                                                     const float* __restrict__ bias,
                                                     float* __restrict__ C, int M,
                                                     int K) {
    __shared__ short As[256][40];
    __shared__ short Bs[64][40];
    const int tid = threadIdx.x;
    const int wid = tid >> 6, lane = tid & 63;
    const int row0 = blockIdx.x * 256;
    f32x4 acc[4][4] = {};
    for (int k0 = 0; k0 < K; k0 += 32) {
        {   // A: each thread stages one row's 32 elems
            int gr = row0 + tid;
            bf16x8 v0 = {}, v1 = {}, v2 = {}, v3 = {};
            if (gr < M) {
                const short* src = A + (size_t)gr * K + k0;
                v0 = *(const bf16x8*)(src);
                v1 = *(const bf16x8*)(src + 8);
                v2 = *(const bf16x8*)(src + 16);
                v3 = *(const bf16x8*)(src + 24);
            }
            *(bf16x8*)&As[tid][0] = v0;
            *(bf16x8*)&As[tid][8] = v1;
            *(bf16x8*)&As[tid][16] = v2;
            *(bf16x8*)&As[tid][24] = v3;
        }
        {   // B: 64 rows x 32 k
            int r = tid >> 2, c8 = (tid & 3) * 8;
            *(bf16x8*)&Bs[r][c8] = *(const bf16x8*)(Bt + (size_t)r * K + k0 + c8);
        }
        __syncthreads();
        const int kg = (lane >> 4) * 8;
        bf16x8 af[4], bfr[4];
#pragma unroll
        for (int m = 0; m < 4; m++)
            af[m] = *(const bf16x8*)&As[wid * 64 + m * 16 + (lane & 15)][kg];
#pragma unroll
        for (int n = 0; n < 4; n++)
            bfr[n] = *(const bf16x8*)&Bs[n * 16 + (lane & 15)][kg];
#pragma unroll
        for (int m = 0; m < 4; m++)
#pragma unroll
            for (int n = 0; n < 4; n++)
                acc[m][n] = __builtin_amdgcn_mfma_f32_16x16x32_bf16(af[m], bfr[n],
                                                                   acc[m][n], 0, 0, 0);
        __syncthreads();
    }
    const int colb = lane & 15;
    const int rowb = row0 + wid * 64 + (lane >> 4) * 4;
#pragma unroll
    for (int n = 0; n < 4; n++) {
        int gc = colb + n * 16;
        float bv = bias[gc];
#pragma unroll
        for (int m = 0; m < 4; m++) {
            int gr = rowb + m * 16;
#pragma unroll
            for (int r = 0; r < 4; r++)
                if (gr + r < M) C[(size_t)(gr + r) * 64 + gc] = acc[m][n][r] + bv;
        }
    }
}

// ======================= combined U-weights: (Wq@Wu) and bq@Wu =======================
template <int C, int K>
__global__ __launch_bounds__(256) void wqu_combine(const float* __restrict__ Wq,
                                                   const float* __restrict__ We,
                                                   short* __restrict__ out) {
    int i = blockIdx.x * 256 + threadIdx.x;
    if (i >= 64 * K) return;
    int hf = i / K, kk = i - hf * K;
    int h = hf >> 4, f = hf & 15;
    const float* wq = Wq + (size_t)kk * (4 * C) + h * C;
    const float* we = We + (size_t)f * (4 * C) + h * C;
    float s0 = 0.f, s1 = 0.f, s2 = 0.f, s3 = 0.f;
    for (int c = 0; c < C; c += 4) {
        float4 a = *(const float4*)(wq + c);
        float4 b = *(const float4*)(we + c);
        s0 = fmaf(a.x, b.x, s0);
        s1 = fmaf(a.y, b.y, s1);
        s2 = fmaf(a.z, b.z, s2);
        s3 = fmaf(a.w, b.w, s3);
    }
    out[i] = f2b1((s0 + s1) + (s2 + s3));
}
template <int C>
__global__ void bu_combine(const float* __restrict__ bq, const float* __restrict__ We,
                           float* __restrict__ bu) {
    int hf = threadIdx.x;  // 64
    int h = hf >> 4, f = hf & 15;
    float s = 0.f;
    for (int c = 0; c < C; c++) s = fmaf(bq[h * C + c], We[(size_t)f * 4 * C + h * C + c], s);
    bu[hf] = s;
}

// ======================= small-M row GEMM (head) =======================
template <bool RELU>
__global__ __launch_bounds__(256) void gemm_row(const float* __restrict__ A,
                                                const float* __restrict__ B,
                                                const float* __restrict__ bias,
                                                float* __restrict__ C, int N, int K,
                                                int lda, int ldc) {
    int g = blockIdx.x;
    int col = threadIdx.x & 127;
    int half = threadIdx.x >> 7;
    int kh = K >> 1;
    int k0 = half * kh, k1 = k0 + kh;
    const float* a = A + (size_t)g * lda;
    float s0 = 0.f, s1 = 0.f, s2 = 0.f, s3 = 0.f;
    int kk = k0;
    for (; kk + 4 <= k1; kk += 4) {
        s0 = fmaf(a[kk], B[(size_t)kk * N + col], s0);
        s1 = fmaf(a[kk + 1], B[(size_t)(kk + 1) * N + col], s1);
        s2 = fmaf(a[kk + 2], B[(size_t)(kk + 2) * N + col], s2);
        s3 = fmaf(a[kk + 3], B[(size_t)(kk + 3) * N + col], s3);
    }
    for (; kk < k1; kk++) s0 = fmaf(a[kk], B[(size_t)kk * N + col], s0);
    float s = (s0 + s1) + (s2 + s3);
    __shared__ float red[128];
    if (half == 1) red[col] = s;
    __syncthreads();
    if (half == 0) {
        s += red[col] + bias[col];
        if (RELU) s = fmaxf(s, 0.f);
        C[(size_t)g * ldc + col] = s;
    }
}

// ======================= split-K row GEMM (fc1, K=2176) =======================
// Partial P[s][g][128] = A[g, kb..ke) @ B chunk. grid (64, nsplit), 256 thr.
__global__ __launch_bounds__(256) void gemm_row_part(const float* __restrict__ A,
                                                     const float* __restrict__ B,
                                                     float* __restrict__ P, int K,
                                                     int lda, int chunk) {
    int g = blockIdx.x, s = blockIdx.y;
    int col = threadIdx.x & 127, half = threadIdx.x >> 7;
    int kb = s * chunk + half * (chunk >> 1);
    int ke = min(kb + (chunk >> 1), K);
    const float* a = A + (size_t)g * lda;
    float s0 = 0.f, s1 = 0.f, s2 = 0.f, s3 = 0.f;
    int kk = kb;
    for (; kk + 4 <= ke; kk += 4) {
        s0 = fmaf(a[kk], B[(size_t)kk * 128 + col], s0);
        s1 = fmaf(a[kk + 1], B[(size_t)(kk + 1) * 128 + col], s1);
        s2 = fmaf(a[kk + 2], B[(size_t)(kk + 2) * 128 + col], s2);
        s3 = fmaf(a[kk + 3], B[(size_t)(kk + 3) * 128 + col], s3);
    }
    for (; kk < ke; kk++) s0 = fmaf(a[kk], B[(size_t)kk * 128 + col], s0);
    float v = (s0 + s1) + (s2 + s3);
    __shared__ float red[128];
    if (half == 1) red[col] = v;
    __syncthreads();
    if (half == 0) P[((size_t)s * 64 + g) * 128 + col] = v + red[col];
}
__global__ __launch_bounds__(128) void gemm_row_reduce(const float* __restrict__ P,
                                                       const float* __restrict__ bias,
                                                       float* __restrict__ C, int nsplit) {
    int g = blockIdx.x, col = threadIdx.x;
    float sum = bias[col];
    for (int s = 0; s < nsplit; s++) sum += P[((size_t)s * 64 + g) * 128 + col];
    C[(size_t)g * 128 + col] = sum;
}

// ======================= conversions =======================
__global__ __launch_bounds__(256) void f2b_vec(const float* __restrict__ in,
                                               short* __restrict__ out, int n4) {
    int i = blockIdx.x * 256 + threadIdx.x;
    if (i >= n4) return;
    float4 v = ((const float4*)in)[i];
    short4 o;
    o.x = f2b1(v.x); o.y = f2b1(v.y); o.z = f2b1(v.z); o.w = f2b1(v.w);
    ((short4*)out)[i] = o;
}
// W[K,N] fp32 -> Wt[N,K] bf16 via 32x32 LDS tile (coalesced both sides)
__global__ __launch_bounds__(256) void f2b_T(const float* __restrict__ in,
                                             short* __restrict__ out, int K, int N) {
    __shared__ short tile[32][33];
    int kb = blockIdx.y * 32, nb = blockIdx.x * 32;
    int tx = threadIdx.x & 31, ty = threadIdx.x >> 5;  // 8 rows per pass
#pragma unroll
    for (int i = 0; i < 32; i += 8) {
        int kk = kb + ty + i, n = nb + tx;
        if (kk < K && n < N) tile[ty + i][tx] = f2b1(in[(size_t)kk * N + n]);
    }
    __syncthreads();
#pragma unroll
    for (int i = 0; i < 32; i += 8) {
        int n = nb + ty + i, kk = kb + tx;
        if (n < N && kk < K) out[(size_t)n * K + kk] = tile[tx][ty + i];
    }
}
// block-diag expansion of We as Bt-layout bf16: out[d][h'*16+f] = (head(d)==h')?We[f][d]:0
template <int D, int C>
__global__ __launch_bounds__(256) void build_wub(const float* __restrict__ We,
                                                 short* __restrict__ out) {
    int i = blockIdx.x * 256 + threadIdx.x;
    if (i >= D * 64) return;
    int d = i >> 6, hf = i & 63;
    int hp = hf >> 4, f = hf & 15;
    float v = ((d / C) == hp) ? We[(size_t)f * D + d] : 0.f;
    out[i] = f2b1(v);
}

// ======================= CSR build (by dst) =======================
__global__ __launch_bounds__(256) void count_deg(const int* __restrict__ dst,
                                                 int* __restrict__ deg, int E) {
    int e = blockIdx.x * 256 + threadIdx.x;
    if (e < E) atomicAdd(&deg[dst[e]], 1);
}

__global__ __launch_bounds__(1024) void scan_deg(const int* __restrict__ deg,
                                                 int* __restrict__ rs,
                                                 int* __restrict__ cursor, int n) {
    __shared__ int part[1024];
    int t = threadIdx.x;
    int ch = (n + 1023) / 1024;
    int b0 = min(t * ch, n), b1 = min(b0 + ch, n);
    int s = 0;
    for (int i = b0; i < b1; i++) s += deg[i];
    part[t] = s;
    __syncthreads();
    for (int off = 1; off < 1024; off <<= 1) {
        int tmp = (t >= off) ? part[t - off] : 0;
        __syncthreads();
        part[t] += tmp;
        __syncthreads();
    }
    int run = part[t] - s;
    for (int i = b0; i < b1; i++) {
        rs[i] = run;
        cursor[i] = run;
        run += deg[i];
    }
    if (t == 1023) rs[n] = part[1023];
}

__global__ __launch_bounds__(256) void fill_csr(const int* __restrict__ dst,
                                                int* __restrict__ cursor,
                                                int* __restrict__ eids, int E) {
    int e = blockIdx.x * 256 + threadIdx.x;
    if (e < E) {
        int pos = atomicAdd(&cursor[dst[e]], 1);
        eids[pos] = e;
    }
}

// ======================= per-node attention =======================
// Pass A: fused alpha + segment softmax (per-node wave, no atomics)
template <int C>
__global__ __launch_bounds__(256) void node_alpha(
    const short* __restrict__ q, const short* __restrict__ k,
    const float* __restrict__ U, const float* __restrict__ ea,
    const int* __restrict__ src, const int* __restrict__ rs,
    const int* __restrict__ eids, float* __restrict__ ab,
    float* __restrict__ den, int Nn) {
    constexpr int D = 4 * C;
    constexpr int P = D / 64;
    int node = (blockIdx.x * 256 + threadIdx.x) >> 6;
    int lane = threadIdx.x & 63;
    if (node >= Nn) return;
    int e0 = rs[node], e1 = rs[node + 1];
    float qr[P];
    const short* qp = q + (size_t)node * D + lane * P;
#pragma unroll
    for (int j0 = 0; j0 < P; j0 += 8) {
        bf16x8 v = *(const bf16x8*)(qp + j0);
#pragma unroll
        for (int j = 0; j < 8; j++) qr[j0 + j] = b2f(v[j]);
    }
    float Urow = U[(size_t)node * 64 + lane];
    const float rsC = rsqrtf((float)C);
    float m = -3.402823466e38f;
    for (int ii = e0; ii < e1; ii++) {
        int e = eids[ii];
        int s = src[e];
        float val = ea[(size_t)e * 16 + (lane & 15)] * Urow;
        const short* kp = k + (size_t)s * D + lane * P;
#pragma unroll
        for (int j0 = 0; j0 < P; j0 += 8) {
            bf16x8 kv = *(const bf16x8*)(kp + j0);
#pragma unroll
            for (int j = 0; j < 8; j++) val = fmaf(qr[j0 + j], b2f(kv[j]), val);
        }
#pragma unroll
        for (int off = 1; off < 16; off <<= 1) val += __shfl_xor(val, off);
        val *= rsC;
        if ((lane & 15) == 0) ab[(size_t)ii * 4 + (lane >> 4)] = val;
        m = fmaxf(m, val);
    }
    float dsum = 0.f;
    for (int ii = e0; ii < e1; ii++) {
        float a = ab[(size_t)ii * 4 + (lane >> 4)];
        float ex = __expf(a - m);
        dsum += ex;
        if ((lane & 15) == 0) ab[(size_t)ii * 4 + (lane >> 4)] = ex;
    }
    if ((lane & 15) == 0) den[(size_t)node * 4 + (lane >> 4)] = dsum;
}

// Pass B: h[node] += (sum ex*v[src])/den (fp32);  Tb[node] = (sum ex*ea)/den (bf16)
template <int C>
__global__ __launch_bounds__(256) void node_scatter(
    const short* __restrict__ v, const float* __restrict__ ea,
    const int* __restrict__ src, const int* __restrict__ rs,
    const int* __restrict__ eids, const float* __restrict__ ab,
    const float* __restrict__ den, float* __restrict__ hout,
    short* __restrict__ Tb, int Nn) {
    constexpr int D = 4 * C;
    constexpr int P = D / 64;
    int node = (blockIdx.x * 256 + threadIdx.x) >> 6;
    int lane = threadIdx.x & 63;
    if (node >= Nn) return;
    int e0 = rs[node], e1 = rs[node + 1];
    float acc[P] = {};
    float tacc = 0.f;
    for (int ii = e0; ii < e1; ii++) {
        int e = eids[ii];
        int s = src[e];
        float ex = ab[(size_t)ii * 4 + (lane >> 4)];
        tacc = fmaf(ex, ea[(size_t)e * 16 + (lane & 15)], tacc);
        const short* vp = v + (size_t)s * D + lane * P;
#pragma unroll
        for (int j0 = 0; j0 < P; j0 += 8) {
            bf16x8 t8 = *(const bf16x8*)(vp + j0);
#pragma unroll
            for (int j = 0; j < 8; j++) acc[j0 + j] = fmaf(ex, b2f(t8[j]), acc[j0 + j]);
        }
    }
    float inv = 1.f / (den[(size_t)node * 4 + (lane >> 4)] + 1e-16f);
    Tb[(size_t)node * 64 + lane] = f2b1(tacc * inv);
    float* hp = hout + (size_t)node * D + lane * P;
#pragma unroll
    for (int j = 0; j < P; j += 4) {
        float4 t4 = *(float4*)(hp + j);
        t4.x = fmaf(acc[j], inv, t4.x);
        t4.y = fmaf(acc[j + 1], inv, t4.y);
        t4.z = fmaf(acc[j + 2], inv, t4.z);
        t4.w = fmaf(acc[j + 3], inv, t4.w);
        *(float4*)(hp + j) = t4;
    }
}

// ======================= batch norm =======================
__global__ __launch_bounds__(256) void bn_stats(const float* __restrict__ h,
                                                float* __restrict__ s1,
                                                float* __restrict__ s2, int Nrows,
                                                int D) {
    int col = blockIdx.x * 256 + threadIdx.x;
    int chunk = (Nrows + gridDim.y - 1) / gridDim.y;
    int r0 = blockIdx.y * chunk;
    int r1 = min(r0 + chunk, Nrows);
    float a = 0.f, b = 0.f;
    for (int r = r0; r < r1; r++) {
        float v = h[(size_t)r * D + col];
        a += v;
        b += v * v;
    }
    atomicAdd(&s1[col], a);
    atomicAdd(&s2[col], b);
}
__global__ void bn_finalize(float* __restrict__ s1, float* __restrict__ s2,
                            const float* __restrict__ g, const float* __restrict__ b,
                            int Nrows, int D) {
    int c = blockIdx.x * 256 + threadIdx.x;
    if (c >= D) return;
    float mean = s1[c] / (float)Nrows;
    float var = fmaxf(s2[c] / (float)Nrows - mean * mean, 0.f);
    float scale = g[c] / sqrtf(var + 1e-5f);
    s1[c] = scale;
    s2[c] = b[c] - mean * scale;
}
__global__ __launch_bounds__(256) void bn_apply_relu_f32(float* __restrict__ h,
                                                         const float* __restrict__ scale,
                                                         const float* __restrict__ shift,
                                                         int total4, int D) {
    int i = blockIdx.x * 256 + threadIdx.x;
    if (i >= total4) return;
    float4 v = ((float4*)h)[i];
    int c = (i * 4) % D;
    v.x = fmaxf(fmaf(v.x, scale[c], shift[c]), 0.f);
    v.y = fmaxf(fmaf(v.y, scale[c + 1], shift[c + 1]), 0.f);
    v.z = fmaxf(fmaf(v.z, scale[c + 2], shift[c + 2]), 0.f);
    v.w = fmaxf(fmaf(v.w, scale[c + 3], shift[c + 3]), 0.f);
    ((float4*)h)[i] = v;
}
__global__ __launch_bounds__(256) void bn_apply_relu_b16(const float* __restrict__ h,
                                                         const float* __restrict__ scale,
                                                         const float* __restrict__ shift,
                                                         short* __restrict__ out,
                                                         int total4, int D) {
    int i = blockIdx.x * 256 + threadIdx.x;
    if (i >= total4) return;
    float4 v = ((const float4*)h)[i];
    int c = (i * 4) % D;
    short4 o;
    o.x = f2b1(fmaxf(fmaf(v.x, scale[c], shift[c]), 0.f));
    o.y = f2b1(fmaxf(fmaf(v.y, scale[c + 1], shift[c + 1]), 0.f));
    o.z = f2b1(fmaxf(fmaf(v.z, scale[c + 2], shift[c + 2]), 0.f));
    o.w = f2b1(fmaxf(fmaf(v.w, scale[c + 3], shift[c + 3]), 0.f));
    ((short4*)out)[i] = o;
}

// ======================= pooling (batch is sorted) =======================
__global__ __launch_bounds__(256) void pool_kernel(const float* __restrict__ h,
                                                   const int* __restrict__ batch,
                                                   float* __restrict__ z, int Nrows,
                                                   int D, int ldz) {
    int g = blockIdx.y;
    int c = blockIdx.x * 256 + threadIdx.x;
    int lo = 0, hi = Nrows;
    while (lo < hi) {
        int m = (lo + hi) >> 1;
        if (batch[m] < g) lo = m + 1; else hi = m;
    }
    int s0 = lo;
    hi = Nrows;
    while (lo < hi) {
        int m = (lo + hi) >> 1;
        if (batch[m] < g + 1) lo = m + 1; else hi = m;
    }
    int s1 = lo;
    float sum = 0.f, mx = -3.402823466e38f;
    for (int r = s0; r < s1; r++) {
        float v = h[(size_t)r * D + c];
        sum += v;
        mx = fmaxf(mx, v);
    }
    int cnt = s1 - s0;
    z[(size_t)g * ldz + c] = sum / (float)max(cnt, 1);
    z[(size_t)g * ldz + D + c] = (cnt > 0) ? mx : 0.f;
}

// ======================= tiny MLP head =======================
__global__ __launch_bounds__(128) void bn_small_apply(const float* __restrict__ y,
                                                      const float* __restrict__ g,
                                                      const float* __restrict__ b,
                                                      float* __restrict__ y2) {
    int c = threadIdx.x;
    float m = 0.f;
    for (int r = 0; r < 64; r++) m += y[r * 128 + c];
    m *= (1.f / 64.f);
    float v = 0.f;
    for (int r = 0; r < 64; r++) {
        float d = y[r * 128 + c] - m;
        v += d * d;
    }
    v *= (1.f / 64.f);
    float sc = g[c] / sqrtf(v + 1e-5f);
    float sh = b[c] - m * sc;
    for (int r = 0; r < 64; r++) y2[r * 128 + c] = fmaxf(fmaf(y[r * 128 + c], sc, sh), 0.f);
}
__global__ __launch_bounds__(128) void fc2_small(const float* __restrict__ y2,
                                                 const float* __restrict__ W,
                                                 const float* __restrict__ b,
                                                 float* __restrict__ out) {
    int t = threadIdx.x;
    int g = t >> 1, o = t & 1;
    float s = b[o];
    for (int kk = 0; kk < 128; kk++) s = fmaf(y2[g * 128 + kk], W[kk * 2 + o], s);
    out[g * 2 + o] = s;
}

// ======================= launch =======================
extern "C" void kernel_launch(void* const* d_in, const int* in_sizes, int n_in,
                              void* d_out, int out_size, void* d_ws, size_t ws_size,
                              hipStream_t stream) {
    const float* x     = (const float*)d_in[0];
    const float* ea    = (const float*)d_in[1];
    const float* sol   = (const float*)d_in[2];
    const int*   eidx  = (const int*)d_in[3];
    const int*   batch = (const int*)d_in[4];
    const float* Wq1 = (const float*)d_in[5];  const float* bq1 = (const float*)d_in[6];
    const float* Wk1 = (const float*)d_in[7];  const float* bk1 = (const float*)d_in[8];
    const float* Wv1 = (const float*)d_in[9];  const float* bv1 = (const float*)d_in[10];
    const float* We1 = (const float*)d_in[11];
    const float* Ws1 = (const float*)d_in[12]; const float* bs1 = (const float*)d_in[13];
    const float* g1  = (const float*)d_in[14]; const float* be1 = (const float*)d_in[15];
    const float* Wq2 = (const float*)d_in[16]; const float* bq2 = (const float*)d_in[17];
    const float* Wk2 = (const float*)d_in[18]; const float* bk2 = (const float*)d_in[19];
    const float* Wv2 = (const float*)d_in[20]; const float* bv2 = (const float*)d_in[21];
    const float* We2 = (const float*)d_in[22];
    const float* Ws2 = (const float*)d_in[23]; const float* bs2 = (const float*)d_in[24];
    const float* g2  = (const float*)d_in[25]; const float* be2 = (const float*)d_in[26];
    const float* Wsol = (const float*)d_in[27]; const float* bsol = (const float*)d_in[28];
    const float* Wfc1 = (const float*)d_in[29]; const float* bfc1 = (const float*)d_in[30];
    const float* gf   = (const float*)d_in[31]; const float* bf = (const float*)d_in[32];
    const float* Wfc2 = (const float*)d_in[33]; const float* bfc2 = (const float*)d_in[34];

    const int* srcp = eidx;
    const int* dstp = eidx + EE;

    // ---------------- workspace (peak ~156 MB) ----------------
    char* p = (char*)d_ws;
    auto alloc = [&](size_t bytes) -> char* {
        char* r = p;
        p += (bytes + 255) & ~(size_t)255;
        return r;
    };
    float* R0   = (float*)alloc((size_t)NN * 1024 * 4);  // h1 fp32 (1st half) -> h2 fp32
    short* h1b  = (short*)alloc((size_t)NN * 512 * 2);
    short* bufAb = (short*)alloc((size_t)NN * 1024 * 2); // q1b -> v1b -> q2b -> v2b
    short* bufBb = (short*)alloc((size_t)NN * 1024 * 2); // k1b -> k2b
    float* U    = (float*)alloc((size_t)NN * 64 * 4);
    short* Tb   = (short*)alloc((size_t)NN * 64 * 2);
    float* ab   = (float*)alloc((size_t)EE * 4 * 4);
    float* den  = (float*)alloc((size_t)NN * 4 * 4);
    short* wub  = (short*)alloc((size_t)1024 * 64 * 2);
    short* wq1t = (short*)alloc((size_t)512 * 64 * 2);
    short* wk1t = (short*)alloc((size_t)512 * 64 * 2);
    short* wv1t = (short*)alloc((size_t)512 * 64 * 2);
    short* ws1t = (short*)alloc((size_t)512 * 64 * 2);
    short* wq2t = (short*)alloc((size_t)1024 * 512 * 2);
    short* wk2t = (short*)alloc((size_t)1024 * 512 * 2);
    short* wv2t = (short*)alloc((size_t)1024 * 512 * 2);
    short* ws2t = (short*)alloc((size_t)1024 * 512 * 2);
    short* xb   = (short*)alloc((size_t)NN * 64 * 2);
    short* wqu1t = (short*)alloc((size_t)64 * 64 * 2);
    short* wqu2t = (short*)alloc((size_t)64 * 512 * 2);
    float* bu1  = (float*)alloc(64 * 4);
    float* bu2  = (float*)alloc(64 * 4);
    int* deg    = (int*)alloc((size_t)NN * 4);
    int* cursor = (int*)alloc((size_t)NN * 4);
    int* rs     = (int*)alloc((size_t)(NN + 1) * 4);
    int* eids   = (int*)alloc((size_t)EE * 4);
    float* bnA  = (float*)alloc(1024 * 4);
    float* bnB  = (float*)alloc(1024 * 4);
    float* z  = (float*)alloc((size_t)64 * 2176 * 4);
    float* y  = (float*)alloc((size_t)64 * 128 * 4);
    float* y2 = (float*)alloc((size_t)64 * 128 * 4);
    float* yP = (float*)alloc((size_t)17 * 64 * 128 * 4);
    if ((size_t)(p - (char*)d_ws) > ws_size) return;  // refuse rather than fault

    float* h1 = R0;   // fp32, dead after bn_apply_relu_b16
    float* h2 = R0;   // fp32, live from skip2 onward

    const int GRM = (NN + 127) / 128;       // 118 MFMA row-tiles
    const int GRU = (NN + 255) / 256;       // 59 U-GEMM row-tiles
    const int NWB = (NN * 64 + 255) / 256;  // node-wave blocks
    dim3 blk(256);

    // ---------------- CSR + conversions + weight prep ----------------
    hipMemsetAsync(deg, 0, (size_t)NN * 4, stream);
    count_deg<<<(EE + 255) / 256, blk, 0, stream>>>(dstp, deg, EE);
    scan_deg<<<1, 1024, 0, stream>>>(deg, rs, cursor, NN);
    fill_csr<<<(EE + 255) / 256, blk, 0, stream>>>(dstp, cursor, eids, EE);

    f2b_vec<<<(NN * 64 / 4 + 255) / 256, blk, 0, stream>>>(x, xb, NN * 64 / 4);
    f2b_T<<<dim3(512 / 32, 2), blk, 0, stream>>>(Wq1, wq1t, 64, 512);
    f2b_T<<<dim3(512 / 32, 2), blk, 0, stream>>>(Wk1, wk1t, 64, 512);
    f2b_T<<<dim3(512 / 32, 2), blk, 0, stream>>>(Wv1, wv1t, 64, 512);
    f2b_T<<<dim3(512 / 32, 2), blk, 0, stream>>>(Ws1, ws1t, 64, 512);
    f2b_T<<<dim3(1024 / 32, 512 / 32), blk, 0, stream>>>(Wq2, wq2t, 512, 1024);
    f2b_T<<<dim3(1024 / 32, 512 / 32), blk, 0, stream>>>(Wk2, wk2t, 512, 1024);
    f2b_T<<<dim3(1024 / 32, 512 / 32), blk, 0, stream>>>(Wv2, wv2t, 512, 1024);
    f2b_T<<<dim3(1024 / 32, 512 / 32), blk, 0, stream>>>(Ws2, ws2t, 512, 1024);
    wqu_combine<128, 64><<<(64 * 64 + 255) / 256, blk, 0, stream>>>(Wq1, We1, wqu1t);
    wqu_combine<256, 512><<<(64 * 512 + 255) / 256, blk, 0, stream>>>(Wq2, We2, wqu2t);
    bu_combine<128><<<1, 64, 0, stream>>>(bq1, We1, bu1);
    bu_combine<256><<<1, 64, 0, stream>>>(bq2, We2, bu2);

    hipMemsetAsync(bnA, 0, 1024 * 4, stream);
    hipMemsetAsync(bnB, 0, 1024 * 4, stream);

    // ---------------- layer 1 (D=512, C=128) ----------------
    gemm_mfma<true, false, true><<<dim3(4, GRM), blk, 0, stream>>>(xb, wq1t, bq1, bufAb, NN, 512, 64);  // q1b
    gemm_mfma<true, false, true><<<dim3(4, GRM), blk, 0, stream>>>(xb, wk1t, bk1, bufBb, NN, 512, 64);  // k1b
    gemm_mfma_n64<<<GRU, blk, 0, stream>>>(xb, wqu1t, bu1, U, NN, 64);                                  // U1
    node_alpha<128><<<NWB, blk, 0, stream>>>(bufAb, bufBb, U, ea, srcp, rs, eids, ab, den, NN);
    gemm_mfma<true, false, true><<<dim3(4, GRM), blk, 0, stream>>>(xb, wv1t, bv1, bufAb, NN, 512, 64);  // v1b (q1b dead)
    gemm_mfma<true, false, false><<<dim3(4, GRM), blk, 0, stream>>>(xb, ws1t, bs1, h1, NN, 512, 64);    // skip1 fp32
    node_scatter<128><<<NWB, blk, 0, stream>>>(bufAb, ea, srcp, rs, eids, ab, den, h1, Tb, NN);
    build_wub<512, 128><<<(512 * 64 + 255) / 256, blk, 0, stream>>>(We1, wub);
    gemm_mfma<false, true, false><<<dim3(4, GRM), blk, 0, stream>>>(Tb, wub, nullptr, h1, NN, 512, 64); // h1 += T@Wt
    bn_stats<<<dim3(2, 64), blk, 0, stream>>>(h1, bnA, bnB, NN, 512);
    bn_finalize<<<2, blk, 0, stream>>>(bnA, bnB, g1, be1, NN, 512);
    bn_apply_relu_b16<<<NN * 512 / 4 / 256, blk, 0, stream>>>(h1, bnA, bnB, h1b, NN * 512 / 4, 512);

    // ---------------- layer 2 (D=1024, C=256) ----------------
    hipMemsetAsync(bnA, 0, 1024 * 4, stream);
    hipMemsetAsync(bnB, 0, 1024 * 4, stream);
    gemm_mfma<true, false, true><<<dim3(8, GRM), blk, 0, stream>>>(h1b, wq2t, bq2, bufAb, NN, 1024, 512); // q2b
    gemm_mfma<true, false, true><<<dim3(8, GRM), blk, 0, stream>>>(h1b, wk2t, bk2, bufBb, NN, 1024, 512); // k2b
    gemm_mfma_n64<<<GRU, blk, 0, stream>>>(h1b, wqu2t, bu2, U, NN, 512);                                  // U2
    node_alpha<256><<<NWB, blk, 0, stream>>>(bufAb, bufBb, U, ea, srcp, rs, eids, ab, den, NN);
    gemm_mfma<true, false, true><<<dim3(8, GRM), blk, 0, stream>>>(h1b, wv2t, bv2, bufAb, NN, 1024, 512); // v2b (q2b dead)
    gemm_mfma<true, false, false><<<dim3(8, GRM), blk, 0, stream>>>(h1b, ws2t, bs2, h2, NN, 1024, 512);   // skip2 fp32 (h1 dead)
    node_scatter<256><<<NWB, blk, 0, stream>>>(bufAb, ea, srcp, rs, eids, ab, den, h2, Tb, NN);
    build_wub<1024, 256><<<(1024 * 64 + 255) / 256, blk, 0, stream>>>(We2, wub);
    gemm_mfma<false, true, false><<<dim3(8, GRM), blk, 0, stream>>>(Tb, wub, nullptr, h2, NN, 1024, 64);  // h2 += T@Wt
    bn_stats<<<dim3(4, 64), blk, 0, stream>>>(h2, bnA, bnB, NN, 1024);
    bn_finalize<<<4, blk, 0, stream>>>(bnA, bnB, g2, be2, NN, 1024);
    bn_apply_relu_f32<<<NN * 1024 / 4 / 256, blk, 0, stream>>>(h2, bnA, bnB, NN * 1024 / 4, 1024);

    // ---------------- head ----------------
    pool_kernel<<<dim3(4, 64), blk, 0, stream>>>(h2, batch, z, NN, 1024, 2176);
    gemm_row<true><<<64, blk, 0, stream>>>(sol, Wsol, bsol, z + 2048, 128, 128, 128, 2176);
    gemm_row_part<<<dim3(64, 17), blk, 0, stream>>>(z, Wfc1, yP, 2176, 2176, 128);
    gemm_row_reduce<<<64, 128, 0, stream>>>(yP, bfc1, y, 17);
    bn_small_apply<<<1, 128, 0, stream>>>(y, gf, bf, y2);
    fc2_small<<<1, 128, 0, stream>>>(y2, Wfc2, bfc2, (float*)d_out);
}

// Round 12
// 900.085 us; speedup vs baseline: 13.7971x; 1.1587x over previous
//
#include <hip/hip_runtime.h>
#include <cstdint>
#include <cstddef>

#define DEV __device__ __forceinline__

static constexpr int NN = 15000;   // nodes
static constexpr int EE = 150000;  // edges
static constexpr int GG = 64;      // graphs

typedef __attribute__((ext_vector_type(8))) short bf16x8;
typedef __attribute__((ext_vector_type(4))) float f32x4;

DEV short f2b1(float f) {  // fp32 -> bf16 bits, round-nearest-even
    unsigned u = __float_as_uint(f);
    unsigned r = (u + 0x7fffu + ((u >> 16) & 1u)) >> 16;
    return (short)r;
}
DEV float b2f(short s) { return __uint_as_float(((unsigned)(unsigned short)s) << 16); }

// ======================= bf16 MFMA GEMM (128x128 tile) =======================
// C[M,N] = A[M,K](bf16) @ B[K,N] (+bias) (+=C) ; B given TRANSPOSED: Bt[N][K].
// 256 threads = 4 waves, each wave 64x64 (4x4 frags of 16x16). N%128==0, K%32==0.
// ldc = C row stride (elements). Staging via global_load_lds(16B): linear LDS
// [128][32] shorts; chunk swizzle p = c ^ ((row>>1)&3) on SOURCE and READ sides.
template <bool BIAS, bool ACCUM, bool BF16OUT>
__global__ __launch_bounds__(256) void gemm_mfma(const short* __restrict__ A,
                                                 const short* __restrict__ Bt,
                                                 const float* __restrict__ bias,
                                                 void* __restrict__ Cv, int M, int N,
                                                 int K, int ldc) {
    __shared__ short As[128 * 32];
    __shared__ short Bs[128 * 32];
    const int tid = threadIdx.x;
    const int wid = tid >> 6, lane = tid & 63;
    const int wr = wid >> 1, wc = wid & 1;
    const int row0 = blockIdx.y * 128, col0 = blockIdx.x * 128;

    const int o0 = wid * 2, o1 = wid * 2 + 1;
    const int rA0 = o0 * 16 + (lane >> 2), rA1 = o1 * 16 + (lane >> 2);
    const int c0 = (lane & 3) ^ ((rA0 >> 1) & 3);
    const int c1 = (lane & 3) ^ ((rA1 >> 1) & 3);
    const short* gA0 = A + (size_t)(row0 + rA0) * K + c0 * 8;
    const short* gA1 = A + (size_t)(row0 + rA1) * K + c1 * 8;
    const short* gB0 = Bt + (size_t)(col0 + rA0) * K + c0 * 8;
    const short* gB1 = Bt + (size_t)(col0 + rA1) * K + c1 * 8;
    const bool okA0 = (row0 + rA0) < M, okA1 = (row0 + rA1) < M;

    f32x4 acc[4][4] = {};
    for (int k0 = 0; k0 < K; k0 += 32) {
        if (okA0) __builtin_amdgcn_global_load_lds(gA0 + k0, &As[o0 * 512], 16, 0, 0);
        if (okA1) __builtin_amdgcn_global_load_lds(gA1 + k0, &As[o1 * 512], 16, 0, 0);
        __builtin_amdgcn_global_load_lds(gB0 + k0, &Bs[o0 * 512], 16, 0, 0);
        __builtin_amdgcn_global_load_lds(gB1 + k0, &Bs[o1 * 512], 16, 0, 0);
        __syncthreads();
        const int kg4 = lane >> 4;
        bf16x8 af[4], bfv[4];
#pragma unroll
        for (int m = 0; m < 4; m++) {
            int ar = wr * 64 + m * 16 + (lane & 15);
            af[m] = *(const bf16x8*)&As[ar * 32 + (kg4 ^ ((ar >> 1) & 3)) * 8];
        }
#pragma unroll
        for (int n = 0; n < 4; n++) {
            int br = wc * 64 + n * 16 + (lane & 15);
            bfv[n] = *(const bf16x8*)&Bs[br * 32 + (kg4 ^ ((br >> 1) & 3)) * 8];
        }
#pragma unroll
        for (int m = 0; m < 4; m++)
#pragma unroll
            for (int n = 0; n < 4; n++)
                acc[m][n] = __builtin_amdgcn_mfma_f32_16x16x32_bf16(af[m], bfv[n],
                                                                   acc[m][n], 0, 0, 0);
        __syncthreads();
    }
    const int colb = col0 + wc * 64 + (lane & 15);
    const int rowb = row0 + wr * 64 + (lane >> 4) * 4;
    float* Cf = (float*)Cv;
    short* Cb = (short*)Cv;
#pragma unroll
    for (int n = 0; n < 4; n++) {
        int gc = colb + n * 16;
        float bv = BIAS ? bias[gc] : 0.f;
#pragma unroll
        for (int m = 0; m < 4; m++) {
            int gr = rowb + m * 16;
#pragma unroll
            for (int r = 0; r < 4; r++) {
                if (gr + r < M) {
                    float v = acc[m][n][r] + bv;
                    if constexpr (ACCUM) v += Cf[(size_t)(gr + r) * ldc + gc];
                    if constexpr (BF16OUT)
                        Cb[(size_t)(gr + r) * ldc + gc] = f2b1(v);
                    else
                        Cf[(size_t)(gr + r) * ldc + gc] = v;
                }
            }
        }
    }
}

// ======================= bf16 MFMA GEMM (256x64 tile, fp32 out) =======================
__global__ __launch_bounds__(256) void gemm_mfma_n64(const short* __restrict__ A,
                                                     const short* __restrict__ Bt,
                                                     const float* __restrict__ bias,
                                                     float* __restrict__ C, int M,
                                                     int K) {
    __shared__ short As[256][40];
    __shared__ short Bs[64][40];
    const int tid = threadIdx.x;
    const int wid = tid >> 6, lane = tid & 63;
    const int row0 = blockIdx.x * 256;
    f32x4 acc[4][4] = {};
    for (int k0 = 0; k0 < K; k0 += 32) {
        {
            int gr = row0 + tid;
            bf16x8 v0 = {}, v1 = {}, v2 = {}, v3 = {};
            if (gr < M) {
                const short* src = A + (size_t)gr * K + k0;
                v0 = *(const bf16x8*)(src);
                v1 = *(const bf16x8*)(src + 8);
                v2 = *(const bf16x8*)(src + 16);
                v3 = *(const bf16x8*)(src + 24);
            }
            *(bf16x8*)&As[tid][0] = v0;
            *(bf16x8*)&As[tid][8] = v1;
            *(bf16x8*)&As[tid][16] = v2;
            *(bf16x8*)&As[tid][24] = v3;
        }
        {
            int r = tid >> 2, c8 = (tid & 3) * 8;
            *(bf16x8*)&Bs[r][c8] = *(const bf16x8*)(Bt + (size_t)r * K + k0 + c8);
        }
        __syncthreads();
        const int kg = (lane >> 4) * 8;
        bf16x8 af[4], bfr[4];
#pragma unroll
        for (int m = 0; m < 4; m++)
            af[m] = *(const bf16x8*)&As[wid * 64 + m * 16 + (lane & 15)][kg];
#pragma unroll
        for (int n = 0; n < 4; n++)
            bfr[n] = *(const bf16x8*)&Bs[n * 16 + (lane & 15)][kg];
#pragma unroll
        for (int m = 0; m < 4; m++)
#pragma unroll
            for (int n = 0; n < 4; n++)
                acc[m][n] = __builtin_amdgcn_mfma_f32_16x16x32_bf16(af[m], bfr[n],
                                                                   acc[m][n], 0, 0, 0);
        __syncthreads();
    }
    const int colb = lane & 15;
    const int rowb = row0 + wid * 64 + (lane >> 4) * 4;
#pragma unroll
    for (int n = 0; n < 4; n++) {
        int gc = colb + n * 16;
        float bv = bias[gc];
#pragma unroll
        for (int m = 0; m < 4; m++) {
            int gr = rowb + m * 16;
#pragma unroll
            for (int r = 0; r < 4; r++)
                if (gr + r < M) C[(size_t)(gr + r) * 64 + gc] = acc[m][n][r] + bv;
        }
    }
}

// ======================= combined U-weights: (Wq@Wu) and bq@Wu =======================
template <int C, int K>
__global__ __launch_bounds__(256) void wqu_combine(const float* __restrict__ Wq,
                                                   const float* __restrict__ We,
                                                   short* __restrict__ out) {
    int i = blockIdx.x * 256 + threadIdx.x;
    if (i >= 64 * K) return;
    int hf = i / K, kk = i - hf * K;
    int h = hf >> 4, f = hf & 15;
    const float* wq = Wq + (size_t)kk * (4 * C) + h * C;
    const float* we = We + (size_t)f * (4 * C) + h * C;
    float s0 = 0.f, s1 = 0.f, s2 = 0.f, s3 = 0.f;
    for (int c = 0; c < C; c += 4) {
        float4 a = *(const float4*)(wq + c);
        float4 b = *(const float4*)(we + c);
        s0 = fmaf(a.x, b.x, s0);
        s1 = fmaf(a.y, b.y, s1);
        s2 = fmaf(a.z, b.z, s2);
        s3 = fmaf(a.w, b.w, s3);
    }
    out[i] = f2b1((s0 + s1) + (s2 + s3));
}
template <int C>
__global__ void bu_combine(const float* __restrict__ bq, const float* __restrict__ We,
                           float* __restrict__ bu) {
    int hf = threadIdx.x;  // 64
    int h = hf >> 4, f = hf & 15;
    float s = 0.f;
    for (int c = 0; c < C; c++) s = fmaf(bq[h * C + c], We[(size_t)f * 4 * C + h * C + c], s);
    bu[hf] = s;
}

// concat two bias vectors [n] -> [2n]
__global__ void concat2(const float* __restrict__ a, const float* __restrict__ b,
                        float* __restrict__ o, int n) {
    int i = blockIdx.x * 256 + threadIdx.x;
    if (i < n) o[i] = a[i];
    else if (i < 2 * n) o[i] = b[i - n];
}

// ======================= small-M row GEMM (head) =======================
template <bool RELU>
__global__ __launch_bounds__(256) void gemm_row(const float* __restrict__ A,
                                                const float* __restrict__ B,
                                                const float* __restrict__ bias,
                                                float* __restrict__ C, int N, int K,
                                                int lda, int ldc) {
    int g = blockIdx.x;
    int col = threadIdx.x & 127;
    int half = threadIdx.x >> 7;
    int kh = K >> 1;
    int k0 = half * kh, k1 = k0 + kh;
    const float* a = A + (size_t)g * lda;
    float s0 = 0.f, s1 = 0.f, s2 = 0.f, s3 = 0.f;
    int kk = k0;
    for (; kk + 4 <= k1; kk += 4) {
        s0 = fmaf(a[kk], B[(size_t)kk * N + col], s0);
        s1 = fmaf(a[kk + 1], B[(size_t)(kk + 1) * N + col], s1);
        s2 = fmaf(a[kk + 2], B[(size_t)(kk + 2) * N + col], s2);
        s3 = fmaf(a[kk + 3], B[(size_t)(kk + 3) * N + col], s3);
    }
    for (; kk < k1; kk++) s0 = fmaf(a[kk], B[(size_t)kk * N + col], s0);
    float s = (s0 + s1) + (s2 + s3);
    __shared__ float red[128];
    if (half == 1) red[col] = s;
    __syncthreads();
    if (half == 0) {
        s += red[col] + bias[col];
        if (RELU) s = fmaxf(s, 0.f);
        C[(size_t)g * ldc + col] = s;
    }
}

// ======================= split-K row GEMM (fc1, K=2176) =======================
__global__ __launch_bounds__(256) void gemm_row_part(const float* __restrict__ A,
                                                     const float* __restrict__ B,
                                                     float* __restrict__ P, int K,
                                                     int lda, int chunk) {
    int g = blockIdx.x, s = blockIdx.y;
    int col = threadIdx.x & 127, half = threadIdx.x >> 7;
    int kb = s * chunk + half * (chunk >> 1);
    int ke = min(kb + (chunk >> 1), K);
    const float* a = A + (size_t)g * lda;
    float s0 = 0.f, s1 = 0.f, s2 = 0.f, s3 = 0.f;
    int kk = kb;
    for (; kk + 4 <= ke; kk += 4) {
        s0 = fmaf(a[kk], B[(size_t)kk * 128 + col], s0);
        s1 = fmaf(a[kk + 1], B[(size_t)(kk + 1) * 128 + col], s1);
        s2 = fmaf(a[kk + 2], B[(size_t)(kk + 2) * 128 + col], s2);
        s3 = fmaf(a[kk + 3], B[(size_t)(kk + 3) * 128 + col], s3);
    }
    for (; kk < ke; kk++) s0 = fmaf(a[kk], B[(size_t)kk * 128 + col], s0);
    float v = (s0 + s1) + (s2 + s3);
    __shared__ float red[128];
    if (half == 1) red[col] = v;
    __syncthreads();
    if (half == 0) P[((size_t)s * 64 + g) * 128 + col] = v + red[col];
}
__global__ __launch_bounds__(128) void gemm_row_reduce(const float* __restrict__ P,
                                                       const float* __restrict__ bias,
                                                       float* __restrict__ C, int nsplit) {
    int g = blockIdx.x, col = threadIdx.x;
    float sum = bias[col];
    for (int s = 0; s < nsplit; s++) sum += P[((size_t)s * 64 + g) * 128 + col];
    C[(size_t)g * 128 + col] = sum;
}

// ======================= conversions =======================
__global__ __launch_bounds__(256) void f2b_vec(const float* __restrict__ in,
                                               short* __restrict__ out, int n4) {
    int i = blockIdx.x * 256 + threadIdx.x;
    if (i >= n4) return;
    float4 v = ((const float4*)in)[i];
    short4 o;
    o.x = f2b1(v.x); o.y = f2b1(v.y); o.z = f2b1(v.z); o.w = f2b1(v.w);
    ((short4*)out)[i] = o;
}
__global__ __launch_bounds__(256) void f2b_T(const float* __restrict__ in,
                                             short* __restrict__ out, int K, int N) {
    __shared__ short tile[32][33];
    int kb = blockIdx.y * 32, nb = blockIdx.x * 32;
    int tx = threadIdx.x & 31, ty = threadIdx.x >> 5;
#pragma unroll
    for (int i = 0; i < 32; i += 8) {
        int kk = kb + ty + i, n = nb + tx;
        if (kk < K && n < N) tile[ty + i][tx] = f2b1(in[(size_t)kk * N + n]);
    }
    __syncthreads();
#pragma unroll
    for (int i = 0; i < 32; i += 8) {
        int n = nb + ty + i, kk = kb + tx;
        if (n < N && kk < K) out[(size_t)n * K + kk] = tile[tx][ty + i];
    }
}
template <int D, int C>
__global__ __launch_bounds__(256) void build_wub(const float* __restrict__ We,
                                                 short* __restrict__ out) {
    int i = blockIdx.x * 256 + threadIdx.x;
    if (i >= D * 64) return;
    int d = i >> 6, hf = i & 63;
    int hp = hf >> 4, f = hf & 15;
    float v = ((d / C) == hp) ? We[(size_t)f * D + d] : 0.f;
    out[i] = f2b1(v);
}

// ======================= CSR build (by dst) =======================
__global__ __launch_bounds__(256) void count_deg(const int* __restrict__ dst,
                                                 int* __restrict__ deg, int E) {
    int e = blockIdx.x * 256 + threadIdx.x;
    if (e < E) atomicAdd(&deg[dst[e]], 1);
}

__global__ __launch_bounds__(1024) void scan_deg(const int* __restrict__ deg,
                                                 int* __restrict__ rs,
                                                 int* __restrict__ cursor, int n) {
    __shared__ int part[1024];
    int t = threadIdx.x;
    int ch = (n + 1023) / 1024;
    int b0 = min(t * ch, n), b1 = min(b0 + ch, n);
    int s = 0;
    for (int i = b0; i < b1; i++) s += deg[i];
    part[t] = s;
    __syncthreads();
    for (int off = 1; off < 1024; off <<= 1) {
        int tmp = (t >= off) ? part[t - off] : 0;
        __syncthreads();
        part[t] += tmp;
        __syncthreads();
    }
    int run = part[t] - s;
    for (int i = b0; i < b1; i++) {
        rs[i] = run;
        cursor[i] = run;
        run += deg[i];
    }
    if (t == 1023) rs[n] = part[1023];
}

__global__ __launch_bounds__(256) void fill_csr(const int* __restrict__ dst,
                                                int* __restrict__ cursor,
                                                int* __restrict__ eids, int E) {
    int e = blockIdx.x * 256 + threadIdx.x;
    if (e < E) {
        int pos = atomicAdd(&cursor[dst[e]], 1);
        eids[pos] = e;
    }
}

// ======================= per-node attention =======================
// q/k/v are rows of stride ld (fused qk|v layout). D = per-tensor width.
template <int C>
__global__ __launch_bounds__(256) void node_alpha(
    const short* __restrict__ q, const short* __restrict__ k, int ld,
    const float* __restrict__ U, const float* __restrict__ ea,
    const int* __restrict__ src, const int* __restrict__ rs,
    const int* __restrict__ eids, float* __restrict__ ab,
    float* __restrict__ den, int Nn) {
    constexpr int D = 4 * C;
    constexpr int P = D / 64;
    int node = (blockIdx.x * 256 + threadIdx.x) >> 6;
    int lane = threadIdx.x & 63;
    if (node >= Nn) return;
    int e0 = rs[node], e1 = rs[node + 1];
    float qr[P];
    const short* qp = q + (size_t)node * ld + lane * P;
#pragma unroll
    for (int j0 = 0; j0 < P; j0 += 8) {
        bf16x8 v = *(const bf16x8*)(qp + j0);
#pragma unroll
        for (int j = 0; j < 8; j++) qr[j0 + j] = b2f(v[j]);
    }
    float Urow = U[(size_t)node * 64 + lane];
    const float rsC = rsqrtf((float)C);
    float m = -3.402823466e38f;
    for (int ii = e0; ii < e1; ii++) {
        int e = eids[ii];
        int s = src[e];
        float val = ea[(size_t)e * 16 + (lane & 15)] * Urow;
        const short* kp = k + (size_t)s * ld + lane * P;
#pragma unroll
        for (int j0 = 0; j0 < P; j0 += 8) {
            bf16x8 kv = *(const bf16x8*)(kp + j0);
#pragma unroll
            for (int j = 0; j < 8; j++) val = fmaf(qr[j0 + j], b2f(kv[j]), val);
        }
#pragma unroll
        for (int off = 1; off < 16; off <<= 1) val += __shfl_xor(val, off);
        val *= rsC;
        if ((lane & 15) == 0) ab[(size_t)ii * 4 + (lane >> 4)] = val;
        m = fmaxf(m, val);
    }
    float dsum = 0.f;
    for (int ii = e0; ii < e1; ii++) {
        float a = ab[(size_t)ii * 4 + (lane >> 4)];
        float ex = __expf(a - m);
        dsum += ex;
        if ((lane & 15) == 0) ab[(size_t)ii * 4 + (lane >> 4)] = ex;
    }
    if ((lane & 15) == 0) den[(size_t)node * 4 + (lane >> 4)] = dsum;
}

template <int C>
__global__ __launch_bounds__(256) void node_scatter(
    const short* __restrict__ v, int ld, const float* __restrict__ ea,
    const int* __restrict__ src, const int* __restrict__ rs,
    const int* __restrict__ eids, const float* __restrict__ ab,
    const float* __restrict__ den, float* __restrict__ hout,
    short* __restrict__ Tb, int Nn) {
    constexpr int D = 4 * C;
    constexpr int P = D / 64;
    int node = (blockIdx.x * 256 + threadIdx.x) >> 6;
    int lane = threadIdx.x & 63;
    if (node >= Nn) return;
    int e0 = rs[node], e1 = rs[node + 1];
    float acc[P] = {};
    float tacc = 0.f;
    for (int ii = e0; ii < e1; ii++) {
        int e = eids[ii];
        int s = src[e];
        float ex = ab[(size_t)ii * 4 + (lane >> 4)];
        tacc = fmaf(ex, ea[(size_t)e * 16 + (lane & 15)], tacc);
        const short* vp = v + (size_t)s * ld + lane * P;
#pragma unroll
        for (int j0 = 0; j0 < P; j0 += 8) {
            bf16x8 t8 = *(const bf16x8*)(vp + j0);
#pragma unroll
            for (int j = 0; j < 8; j++) acc[j0 + j] = fmaf(ex, b2f(t8[j]), acc[j0 + j]);
        }
    }
    float inv = 1.f / (den[(size_t)node * 4 + (lane >> 4)] + 1e-16f);
    Tb[(size_t)node * 64 + lane] = f2b1(tacc * inv);
    float* hp = hout + (size_t)node * D + lane * P;
#pragma unroll
    for (int j = 0; j < P; j += 4) {
        float4 t4 = *(float4*)(hp + j);
        t4.x = fmaf(acc[j], inv, t4.x);
        t4.y = fmaf(acc[j + 1], inv, t4.y);
        t4.z = fmaf(acc[j + 2], inv, t4.z);
        t4.w = fmaf(acc[j + 3], inv, t4.w);
        *(float4*)(hp + j) = t4;
    }
}

// ======================= batch norm =======================
__global__ __launch_bounds__(256) void bn_stats(const float* __restrict__ h,
                                                float* __restrict__ s1,
                                                float* __restrict__ s2, int Nrows,
                                                int D) {
    int col = blockIdx.x * 256 + threadIdx.x;
    int chunk = (Nrows + gridDim.y - 1) / gridDim.y;
    int r0 = blockIdx.y * chunk;
    int r1 = min(r0 + chunk, Nrows);
    float a = 0.f, b = 0.f;
    for (int r = r0; r < r1; r++) {
        float v = h[(size_t)r * D + col];
        a += v;
        b += v * v;
    }
    atomicAdd(&s1[col], a);
    atomicAdd(&s2[col], b);
}
__global__ void bn_finalize(float* __restrict__ s1, float* __restrict__ s2,
                            const float* __restrict__ g, const float* __restrict__ b,
                            int Nrows, int D) {
    int c = blockIdx.x * 256 + threadIdx.x;
    if (c >= D) return;
    float mean = s1[c] / (float)Nrows;
    float var = fmaxf(s2[c] / (float)Nrows - mean * mean, 0.f);
    float scale = g[c] / sqrtf(var + 1e-5f);
    s1[c] = scale;
    s2[c] = b[c] - mean * scale;
}
__global__ __launch_bounds__(256) void bn_apply_relu_f32(float* __restrict__ h,
                                                         const float* __restrict__ scale,
                                                         const float* __restrict__ shift,
                                                         int total4, int D) {
    int i = blockIdx.x * 256 + threadIdx.x;
    if (i >= total4) return;
    float4 v = ((float4*)h)[i];
    int c = (i * 4) % D;
    v.x = fmaxf(fmaf(v.x, scale[c], shift[c]), 0.f);
    v.y = fmaxf(fmaf(v.y, scale[c + 1], shift[c + 1]), 0.f);
    v.z = fmaxf(fmaf(v.z, scale[c + 2], shift[c + 2]), 0.f);
    v.w = fmaxf(fmaf(v.w, scale[c + 3], shift[c + 3]), 0.f);
    ((float4*)h)[i] = v;
}
__global__ __launch_bounds__(256) void bn_apply_relu_b16(const float* __restrict__ h,
                                                         const float* __restrict__ scale,
                                                         const float* __restrict__ shift,
                                                         short* __restrict__ out,
                                                         int total4, int D) {
    int i = blockIdx.x * 256 + threadIdx.x;
    if (i >= total4) return;
    float4 v = ((const float4*)h)[i];
    int c = (i * 4) % D;
    short4 o;
    o.x = f2b1(fmaxf(fmaf(v.x, scale[c], shift[c]), 0.f));
    o.y = f2b1(fmaxf(fmaf(v.y, scale[c + 1], shift[c + 1]), 0.f));
    o.z = f2b1(fmaxf(fmaf(v.z, scale[c + 2], shift[c + 2]), 0.f));
    o.w = f2b1(fmaxf(fmaf(v.w, scale[c + 3], shift[c + 3]), 0.f));
    ((short4*)out)[i] = o;
}

// ======================= pooling (batch is sorted) =======================
// grid (D/64, GG); block 256 = 64 cols x 4 row-chunks; LDS combine.
__global__ __launch_bounds__(256) void pool_kernel(const float* __restrict__ h,
                                                   const int* __restrict__ batch,
                                                   float* __restrict__ z, int Nrows,
                                                   int D, int ldz) {
    int g = blockIdx.y;
    int cl = threadIdx.x & 63;
    int c = blockIdx.x * 64 + cl;
    int chunk = threadIdx.x >> 6;  // 0..3
    int lo = 0, hi = Nrows;
    while (lo < hi) {
        int m = (lo + hi) >> 1;
        if (batch[m] < g) lo = m + 1; else hi = m;
    }
    int s0 = lo;
    hi = Nrows;
    while (lo < hi) {
        int m = (lo + hi) >> 1;
        if (batch[m] < g + 1) lo = m + 1; else hi = m;
    }
    int s1 = lo;
    int cnt = s1 - s0;
    int per = (cnt + 3) >> 2;
    int r0 = s0 + chunk * per;
    int r1 = min(r0 + per, s1);
    float sum = 0.f, mx = -3.402823466e38f;
    for (int r = r0; r < r1; r++) {
        float v = h[(size_t)r * D + c];
        sum += v;
        mx = fmaxf(mx, v);
    }
    __shared__ float ss[4][64], sm[4][64];
    ss[chunk][cl] = sum;
    sm[chunk][cl] = mx;
    __syncthreads();
    if (chunk == 0) {
#pragma unroll
        for (int j = 1; j < 4; j++) {
            sum += ss[j][cl];
            mx = fmaxf(mx, sm[j][cl]);
        }
        z[(size_t)g * ldz + c] = sum / (float)max(cnt, 1);
        z[(size_t)g * ldz + D + c] = (cnt > 0) ? mx : 0.f;
    }
}

// ======================= tiny MLP head =======================
__global__ __launch_bounds__(128) void bn_small_apply(const float* __restrict__ y,
                                                      const float* __restrict__ g,
                                                      const float* __restrict__ b,
                                                      float* __restrict__ y2) {
    int c = threadIdx.x;
    float m = 0.f;
    for (int r = 0; r < 64; r++) m += y[r * 128 + c];
    m *= (1.f / 64.f);
    float v = 0.f;
    for (int r = 0; r < 64; r++) {
        float d = y[r * 128 + c] - m;
        v += d * d;
    }
    v *= (1.f / 64.f);
    float sc = g[c] / sqrtf(v + 1e-5f);
    float sh = b[c] - m * sc;
    for (int r = 0; r < 64; r++) y2[r * 128 + c] = fmaxf(fmaf(y[r * 128 + c], sc, sh), 0.f);
}
__global__ __launch_bounds__(128) void fc2_small(const float* __restrict__ y2,
                                                 const float* __restrict__ W,
                                                 const float* __restrict__ b,
                                                 float* __restrict__ out) {
    int t = threadIdx.x;
    int g = t >> 1, o = t & 1;
    float s = b[o];
    for (int kk = 0; kk < 128; kk++) s = fmaf(y2[g * 128 + kk], W[kk * 2 + o], s);
    out[g * 2 + o] = s;
}

// ======================= launch =======================
extern "C" void kernel_launch(void* const* d_in, const int* in_sizes, int n_in,
                              void* d_out, int out_size, void* d_ws, size_t ws_size,
                              hipStream_t stream) {
    const float* x     = (const float*)d_in[0];
    const float* ea    = (const float*)d_in[1];
    const float* sol   = (const float*)d_in[2];
    const int*   eidx  = (const int*)d_in[3];
    const int*   batch = (const int*)d_in[4];
    const float* Wq1 = (const float*)d_in[5];  const float* bq1 = (const float*)d_in[6];
    const float* Wk1 = (const float*)d_in[7];  const float* bk1 = (const float*)d_in[8];
    const float* Wv1 = (const float*)d_in[9];  const float* bv1 = (const float*)d_in[10];
    const float* We1 = (const float*)d_in[11];
    const float* Ws1 = (const float*)d_in[12]; const float* bs1 = (const float*)d_in[13];
    const float* g1  = (const float*)d_in[14]; const float* be1 = (const float*)d_in[15];
    const float* Wq2 = (const float*)d_in[16]; const float* bq2 = (const float*)d_in[17];
    const float* Wk2 = (const float*)d_in[18]; const float* bk2 = (const float*)d_in[19];
    const float* Wv2 = (const float*)d_in[20]; const float* bv2 = (const float*)d_in[21];
    const float* We2 = (const float*)d_in[22];
    const float* Ws2 = (const float*)d_in[23]; const float* bs2 = (const float*)d_in[24];
    const float* g2  = (const float*)d_in[25]; const float* be2 = (const float*)d_in[26];
    const float* Wsol = (const float*)d_in[27]; const float* bsol = (const float*)d_in[28];
    const float* Wfc1 = (const float*)d_in[29]; const float* bfc1 = (const float*)d_in[30];
    const float* gf   = (const float*)d_in[31]; const float* bf = (const float*)d_in[32];
    const float* Wfc2 = (const float*)d_in[33]; const float* bfc2 = (const float*)d_in[34];

    const int* srcp = eidx;
    const int* dstp = eidx + EE;

    // ---------------- workspace (peak ~156 MB) ----------------
    char* p = (char*)d_ws;
    auto alloc = [&](size_t bytes) -> char* {
        char* r = p;
        p += (bytes + 255) & ~(size_t)255;
        return r;
    };
    float* R0   = (float*)alloc((size_t)NN * 1024 * 4);  // h1 fp32 -> h2 fp32
    short* h1b  = (short*)alloc((size_t)NN * 512 * 2);
    // qkv region: bufAb and bufBb contiguous -> fused qk rows of stride 2048 (L2)
    short* bufAb = (short*)alloc((size_t)NN * 1024 * 2);
    short* bufBb = (short*)alloc((size_t)NN * 1024 * 2);
    (void)bufBb;
    float* U    = (float*)alloc((size_t)NN * 64 * 4);
    short* Tb   = (short*)alloc((size_t)NN * 64 * 2);
    float* ab   = (float*)alloc((size_t)EE * 4 * 4);
    float* den  = (float*)alloc((size_t)NN * 4 * 4);
    short* wub  = (short*)alloc((size_t)1024 * 64 * 2);
    short* wq1t = (short*)alloc((size_t)512 * 64 * 2);   // wq1t|wk1t contiguous
    short* wk1t = (short*)alloc((size_t)512 * 64 * 2);
    short* wv1t = (short*)alloc((size_t)512 * 64 * 2);
    short* ws1t = (short*)alloc((size_t)512 * 64 * 2);
    short* wq2t = (short*)alloc((size_t)1024 * 512 * 2); // wq2t|wk2t contiguous
    short* wk2t = (short*)alloc((size_t)1024 * 512 * 2);
    short* wv2t = (short*)alloc((size_t)1024 * 512 * 2);
    short* ws2t = (short*)alloc((size_t)1024 * 512 * 2);
    short* xb   = (short*)alloc((size_t)NN * 64 * 2);
    short* wqu1t = (short*)alloc((size_t)64 * 64 * 2);
    short* wqu2t = (short*)alloc((size_t)64 * 512 * 2);
    float* bu1  = (float*)alloc(64 * 4);
    float* bu2  = (float*)alloc(64 * 4);
    float* bqk1 = (float*)alloc(1024 * 4);
    float* bqk2 = (float*)alloc(2048 * 4);
    int* deg    = (int*)alloc((size_t)NN * 4);
    int* cursor = (int*)alloc((size_t)NN * 4);
    int* rs     = (int*)alloc((size_t)(NN + 1) * 4);
    int* eids   = (int*)alloc((size_t)EE * 4);
    float* bnA  = (float*)alloc(1024 * 4);
    float* bnB  = (float*)alloc(1024 * 4);
    float* z  = (float*)alloc((size_t)64 * 2176 * 4);
    float* y  = (float*)alloc((size_t)64 * 128 * 4);
    float* y2 = (float*)alloc((size_t)64 * 128 * 4);
    float* yP = (float*)alloc((size_t)17 * 64 * 128 * 4);
    if ((size_t)(p - (char*)d_ws) > ws_size) return;  // refuse rather than fault

    float* h1 = R0;   // fp32, dead after bn_apply_relu_b16
    float* h2 = R0;   // fp32, live from skip2 onward

    const int GRM = (NN + 127) / 128;       // 118 MFMA row-tiles
    const int GRU = (NN + 255) / 256;       // 59 U-GEMM row-tiles
    const int NWB = (NN * 64 + 255) / 256;  // node-wave blocks
    dim3 blk(256);

    // ---------------- CSR + conversions + weight prep ----------------
    hipMemsetAsync(deg, 0, (size_t)NN * 4, stream);
    count_deg<<<(EE + 255) / 256, blk, 0, stream>>>(dstp, deg, EE);
    scan_deg<<<1, 1024, 0, stream>>>(deg, rs, cursor, NN);
    fill_csr<<<(EE + 255) / 256, blk, 0, stream>>>(dstp, cursor, eids, EE);

    f2b_vec<<<(NN * 64 / 4 + 255) / 256, blk, 0, stream>>>(x, xb, NN * 64 / 4);
    f2b_T<<<dim3(512 / 32, 2), blk, 0, stream>>>(Wq1, wq1t, 64, 512);
    f2b_T<<<dim3(512 / 32, 2), blk, 0, stream>>>(Wk1, wk1t, 64, 512);
    f2b_T<<<dim3(512 / 32, 2), blk, 0, stream>>>(Wv1, wv1t, 64, 512);
    f2b_T<<<dim3(512 / 32, 2), blk, 0, stream>>>(Ws1, ws1t, 64, 512);
    f2b_T<<<dim3(1024 / 32, 512 / 32), blk, 0, stream>>>(Wq2, wq2t, 512, 1024);
    f2b_T<<<dim3(1024 / 32, 512 / 32), blk, 0, stream>>>(Wk2, wk2t, 512, 1024);
    f2b_T<<<dim3(1024 / 32, 512 / 32), blk, 0, stream>>>(Wv2, wv2t, 512, 1024);
    f2b_T<<<dim3(1024 / 32, 512 / 32), blk, 0, stream>>>(Ws2, ws2t, 512, 1024);
    wqu_combine<128, 64><<<(64 * 64 + 255) / 256, blk, 0, stream>>>(Wq1, We1, wqu1t);
    wqu_combine<256, 512><<<(64 * 512 + 255) / 256, blk, 0, stream>>>(Wq2, We2, wqu2t);
    bu_combine<128><<<1, 64, 0, stream>>>(bq1, We1, bu1);
    bu_combine<256><<<1, 64, 0, stream>>>(bq2, We2, bu2);
    concat2<<<(1024 + 255) / 256, blk, 0, stream>>>(bq1, bk1, bqk1, 512);
    concat2<<<(2048 + 255) / 256, blk, 0, stream>>>(bq2, bk2, bqk2, 1024);

    hipMemsetAsync(bnA, 0, 1024 * 4, stream);
    hipMemsetAsync(bnB, 0, 1024 * 4, stream);

    // ---------------- layer 1 (D=512, C=128) ----------------
    // fused q|k: N=1024, rows stride 1024 (q cols 0..511, k cols 512..1023)
    gemm_mfma<true, false, true><<<dim3(8, GRM), blk, 0, stream>>>(xb, wq1t, bqk1, bufAb, NN, 1024, 64, 1024);
    gemm_mfma_n64<<<GRU, blk, 0, stream>>>(xb, wqu1t, bu1, U, NN, 64);  // U1
    node_alpha<128><<<NWB, blk, 0, stream>>>(bufAb, bufAb + 512, 1024, U, ea, srcp, rs, eids, ab, den, NN);
    // v1 into dead q columns (ldc=1024)
    gemm_mfma<true, false, true><<<dim3(4, GRM), blk, 0, stream>>>(xb, wv1t, bv1, bufAb, NN, 512, 64, 1024);
    gemm_mfma<true, false, false><<<dim3(4, GRM), blk, 0, stream>>>(xb, ws1t, bs1, h1, NN, 512, 64, 512);  // skip1
    node_scatter<128><<<NWB, blk, 0, stream>>>(bufAb, 1024, ea, srcp, rs, eids, ab, den, h1, Tb, NN);
    build_wub<512, 128><<<(512 * 64 + 255) / 256, blk, 0, stream>>>(We1, wub);
    gemm_mfma<false, true, false><<<dim3(4, GRM), blk, 0, stream>>>(Tb, wub, nullptr, h1, NN, 512, 64, 512);
    bn_stats<<<dim3(2, 256), blk, 0, stream>>>(h1, bnA, bnB, NN, 512);
    bn_finalize<<<2, blk, 0, stream>>>(bnA, bnB, g1, be1, NN, 512);
    bn_apply_relu_b16<<<NN * 512 / 4 / 256, blk, 0, stream>>>(h1, bnA, bnB, h1b, NN * 512 / 4, 512);

    // ---------------- layer 2 (D=1024, C=256) ----------------
    hipMemsetAsync(bnA, 0, 1024 * 4, stream);
    hipMemsetAsync(bnB, 0, 1024 * 4, stream);
    // fused q|k: N=2048, rows stride 2048 across bufAb||bufBb
    gemm_mfma<true, false, true><<<dim3(16, GRM), blk, 0, stream>>>(h1b, wq2t, bqk2, bufAb, NN, 2048, 512, 2048);
    gemm_mfma_n64<<<GRU, blk, 0, stream>>>(h1b, wqu2t, bu2, U, NN, 512);  // U2
    node_alpha<256><<<NWB, blk, 0, stream>>>(bufAb, bufAb + 1024, 2048, U, ea, srcp, rs, eids, ab, den, NN);
    // v2 into dead q columns (ldc=2048)
    gemm_mfma<true, false, true><<<dim3(8, GRM), blk, 0, stream>>>(h1b, wv2t, bv2, bufAb, NN, 1024, 512, 2048);
    gemm_mfma<true, false, false><<<dim3(8, GRM), blk, 0, stream>>>(h1b, ws2t, bs2, h2, NN, 1024, 512, 1024);  // skip2
    node_scatter<256><<<NWB, blk, 0, stream>>>(bufAb, 2048, ea, srcp, rs, eids, ab, den, h2, Tb, NN);
    build_wub<1024, 256><<<(1024 * 64 + 255) / 256, blk, 0, stream>>>(We2, wub);
    gemm_mfma<false, true, false><<<dim3(8, GRM), blk, 0, stream>>>(Tb, wub, nullptr, h2, NN, 1024, 64, 1024);
    bn_stats<<<dim3(4, 256), blk, 0, stream>>>(h2, bnA, bnB, NN, 1024);
    bn_finalize<<<4, blk, 0, stream>>>(bnA, bnB, g2, be2, NN, 1024);
    bn_apply_relu_f32<<<NN * 1024 / 4 / 256, blk, 0, stream>>>(h2, bnA, bnB, NN * 1024 / 4, 1024);

    // ---------------- head ----------------
    pool_kernel<<<dim3(16, 64), blk, 0, stream>>>(h2, batch, z, NN, 1024, 2176);
    gemm_row<true><<<64, blk, 0, stream>>>(sol, Wsol, bsol, z + 2048, 128, 128, 128, 2176);
    gemm_row_part<<<dim3(64, 17), blk, 0, stream>>>(z, Wfc1, yP, 2176, 2176, 128);
    gemm_row_reduce<<<64, 128, 0, stream>>>(yP, bfc1, y, 17);
    bn_small_apply<<<1, 128, 0, stream>>>(y, gf, bf, y2);
    fc2_small<<<1, 128, 0, stream>>>(y2, Wfc2, bfc2, (float*)d_out);
}

// Round 13
// 862.135 us; speedup vs baseline: 14.4044x; 1.0440x over previous
//
#include <hip/hip_runtime.h>
#include <cstdint>
#include <cstddef>

#define DEV __device__ __forceinline__

static constexpr int NN = 15000;   // nodes
static constexpr int EE = 150000;  // edges
static constexpr int GG = 64;      // graphs

typedef __attribute__((ext_vector_type(8))) short bf16x8;
typedef __attribute__((ext_vector_type(4))) float f32x4;

DEV short f2b1(float f) {  // fp32 -> bf16 bits, round-nearest-even
    unsigned u = __float_as_uint(f);
    unsigned r = (u + 0x7fffu + ((u >> 16) & 1u)) >> 16;
    return (short)r;
}
DEV float b2f(short s) { return __uint_as_float(((unsigned)(unsigned short)s) << 16); }

// ======================= bf16 MFMA GEMM (128x128 tile) =======================
// C[M,N] = A[M,K](bf16) @ B[K,N] (+bias) (+=C) ; B given TRANSPOSED: Bt[N][K].
// 256 threads = 4 waves, each wave 64x64 (4x4 frags of 16x16). N%128==0, K%32==0.
// ldc = C row stride. global_load_lds(16B) staging with chunk swizzle; XCD-aware
// bijective block swizzle (contiguous row-tile chunks per XCD -> A-panel L2 reuse);
// BF16OUT epilogue staged through LDS for coalesced 16-B stores.
template <bool BIAS, bool ACCUM, bool BF16OUT>
__global__ __launch_bounds__(256) void gemm_mfma(const short* __restrict__ A,
                                                 const short* __restrict__ Bt,
                                                 const float* __restrict__ bias,
                                                 void* __restrict__ Cv, int M, int N,
                                                 int K, int ldc) {
    __shared__ short As[128 * 32];
    __shared__ short Bs[128 * 32];
    const int tid = threadIdx.x;
    const int wid = tid >> 6, lane = tid & 63;
    const int wr = wid >> 1, wc = wid & 1;

    // XCD-aware bijective remap (m204): each XCD gets a contiguous tile chunk.
    const int gx = gridDim.x;
    const int nwg = gx * gridDim.y;
    const int orig = blockIdx.y * gx + blockIdx.x;
    const int qq = nwg >> 3, r8 = nwg & 7;
    const int xcd = orig & 7, off = orig >> 3;
    const int wgid = (xcd < r8 ? xcd * (qq + 1) : r8 * (qq + 1) + (xcd - r8) * qq) + off;
    const int row0 = (wgid / gx) * 128, col0 = (wgid % gx) * 128;

    const int o0 = wid * 2, o1 = wid * 2 + 1;
    const int rA0 = o0 * 16 + (lane >> 2), rA1 = o1 * 16 + (lane >> 2);
    const int c0 = (lane & 3) ^ ((rA0 >> 1) & 3);
    const int c1 = (lane & 3) ^ ((rA1 >> 1) & 3);
    const short* gA0 = A + (size_t)(row0 + rA0) * K + c0 * 8;
    const short* gA1 = A + (size_t)(row0 + rA1) * K + c1 * 8;
    const short* gB0 = Bt + (size_t)(col0 + rA0) * K + c0 * 8;
    const short* gB1 = Bt + (size_t)(col0 + rA1) * K + c1 * 8;
    const bool okA0 = (row0 + rA0) < M, okA1 = (row0 + rA1) < M;

    f32x4 acc[4][4] = {};
    for (int k0 = 0; k0 < K; k0 += 32) {
        if (okA0) __builtin_amdgcn_global_load_lds(gA0 + k0, &As[o0 * 512], 16, 0, 0);
        if (okA1) __builtin_amdgcn_global_load_lds(gA1 + k0, &As[o1 * 512], 16, 0, 0);
        __builtin_amdgcn_global_load_lds(gB0 + k0, &Bs[o0 * 512], 16, 0, 0);
        __builtin_amdgcn_global_load_lds(gB1 + k0, &Bs[o1 * 512], 16, 0, 0);
        __syncthreads();
        const int kg4 = lane >> 4;
        bf16x8 af[4], bfv[4];
#pragma unroll
        for (int m = 0; m < 4; m++) {
            int ar = wr * 64 + m * 16 + (lane & 15);
            af[m] = *(const bf16x8*)&As[ar * 32 + (kg4 ^ ((ar >> 1) & 3)) * 8];
        }
#pragma unroll
        for (int n = 0; n < 4; n++) {
            int br = wc * 64 + n * 16 + (lane & 15);
            bfv[n] = *(const bf16x8*)&Bs[br * 32 + (kg4 ^ ((br >> 1) & 3)) * 8];
        }
#pragma unroll
        for (int m = 0; m < 4; m++)
#pragma unroll
            for (int n = 0; n < 4; n++)
                acc[m][n] = __builtin_amdgcn_mfma_f32_16x16x32_bf16(af[m], bfv[n],
                                                                   acc[m][n], 0, 0, 0);
        __syncthreads();
    }

    if constexpr (BF16OUT) {
        // LDS-staged epilogue: 4 passes of 32 rows through As (32x128 shorts),
        // then cooperative coalesced bf16x8 stores. XOR swizzle vs bank clash.
        short* Cb = (short*)Cv;
#pragma unroll
        for (int ph = 0; ph < 4; ph++) {
            if (wr == (ph >> 1)) {
                int mbase = (ph & 1) * 2;
#pragma unroll
                for (int mm = 0; mm < 2; mm++) {
#pragma unroll
                    for (int n = 0; n < 4; n++) {
                        int lc = wc * 64 + n * 16 + (lane & 15);
                        float bv = BIAS ? bias[col0 + lc] : 0.f;
#pragma unroll
                        for (int r = 0; r < 4; r++) {
                            int lr = mm * 16 + (lane >> 4) * 4 + r;  // 0..31
                            As[lr * 128 + (lc ^ (((lr >> 2) & 7) << 3))] =
                                f2b1(acc[mbase + mm][n][r] + bv);
                        }
                    }
                }
            }
            __syncthreads();
#pragma unroll
            for (int it = 0; it < 2; it++) {
                int idx = it * 2048 + tid * 8;
                int lr = idx >> 7, lc = idx & 127;
                int gr = row0 + ph * 32 + lr;
                if (gr < M) {
                    bf16x8 val = *(bf16x8*)&As[lr * 128 + (lc ^ (((lr >> 2) & 7) << 3))];
                    *(bf16x8*)&Cb[(size_t)gr * ldc + col0 + lc] = val;
                }
            }
            __syncthreads();
        }
    } else {
        const int colb = col0 + wc * 64 + (lane & 15);
        const int rowb = row0 + wr * 64 + (lane >> 4) * 4;
        float* Cf = (float*)Cv;
#pragma unroll
        for (int n = 0; n < 4; n++) {
            int gc = colb + n * 16;
            float bv = BIAS ? bias[gc] : 0.f;
#pragma unroll
            for (int m = 0; m < 4; m++) {
                int gr = rowb + m * 16;
#pragma unroll
                for (int r = 0; r < 4; r++) {
                    if (gr + r < M) {
                        float v = acc[m][n][r] + bv;
                        if constexpr (ACCUM) v += Cf[(size_t)(gr + r) * ldc + gc];
                        Cf[(size_t)(gr + r) * ldc + gc] = v;
                    }
                }
            }
        }
    }
}

// ======================= bf16 MFMA GEMM (256x64 tile, fp32 out) =======================
__global__ __launch_bounds__(256) void gemm_mfma_n64(const short* __restrict__ A,
                                                     const short* __restrict__ Bt,
                                                     const float* __restrict__ bias,
                                                     float* __restrict__ C, int M,
                                                     int K) {
    __shared__ short As[256][40];
    __shared__ short Bs[64][40];
    const int tid = threadIdx.x;
    const int wid = tid >> 6, lane = tid & 63;
    const int row0 = blockIdx.x * 256;
    f32x4 acc[4][4] = {};
    for (int k0 = 0; k0 < K; k0 += 32) {
        {
            int gr = row0 + tid;
            bf16x8 v0 = {}, v1 = {}, v2 = {}, v3 = {};
            if (gr < M) {
                const short* src = A + (size_t)gr * K + k0;
                v0 = *(const bf16x8*)(src);
                v1 = *(const bf16x8*)(src + 8);
                v2 = *(const bf16x8*)(src + 16);
                v3 = *(const bf16x8*)(src + 24);
            }
            *(bf16x8*)&As[tid][0] = v0;
            *(bf16x8*)&As[tid][8] = v1;
            *(bf16x8*)&As[tid][16] = v2;
            *(bf16x8*)&As[tid][24] = v3;
        }
        {
            int r = tid >> 2, c8 = (tid & 3) * 8;
            *(bf16x8*)&Bs[r][c8] = *(const bf16x8*)(Bt + (size_t)r * K + k0 + c8);
        }
        __syncthreads();
        const int kg = (lane >> 4) * 8;
        bf16x8 af[4], bfr[4];
#pragma unroll
        for (int m = 0; m < 4; m++)
            af[m] = *(const bf16x8*)&As[wid * 64 + m * 16 + (lane & 15)][kg];
#pragma unroll
        for (int n = 0; n < 4; n++)
            bfr[n] = *(const bf16x8*)&Bs[n * 16 + (lane & 15)][kg];
#pragma unroll
        for (int m = 0; m < 4; m++)
#pragma unroll
            for (int n = 0; n < 4; n++)
                acc[m][n] = __builtin_amdgcn_mfma_f32_16x16x32_bf16(af[m], bfr[n],
                                                                   acc[m][n], 0, 0, 0);
        __syncthreads();
    }
    const int colb = lane & 15;
    const int rowb = row0 + wid * 64 + (lane >> 4) * 4;
#pragma unroll
    for (int n = 0; n < 4; n++) {
        int gc = colb + n * 16;
        float bv = bias[gc];
#pragma unroll
        for (int m = 0; m < 4; m++) {
            int gr = rowb + m * 16;
#pragma unroll
            for (int r = 0; r < 4; r++)
                if (gr + r < M) C[(size_t)(gr + r) * 64 + gc] = acc[m][n][r] + bv;
        }
    }
}

// ======================= combined U-weights: (Wq@Wu) and bq@Wu =======================
template <int C, int K>
__global__ __launch_bounds__(256) void wqu_combine(const float* __restrict__ Wq,
                                                   const float* __restrict__ We,
                                                   short* __restrict__ out) {
    int i = blockIdx.x * 256 + threadIdx.x;
    if (i >= 64 * K) return;
    int hf = i / K, kk = i - hf * K;
    int h = hf >> 4, f = hf & 15;
    const float* wq = Wq + (size_t)kk * (4 * C) + h * C;
    const float* we = We + (size_t)f * (4 * C) + h * C;
    float s0 = 0.f, s1 = 0.f, s2 = 0.f, s3 = 0.f;
    for (int c = 0; c < C; c += 4) {
        float4 a = *(const float4*)(wq + c);
        float4 b = *(const float4*)(we + c);
        s0 = fmaf(a.x, b.x, s0);
        s1 = fmaf(a.y, b.y, s1);
        s2 = fmaf(a.z, b.z, s2);
        s3 = fmaf(a.w, b.w, s3);
    }
    out[i] = f2b1((s0 + s1) + (s2 + s3));
}
template <int C>
__global__ void bu_combine(const float* __restrict__ bq, const float* __restrict__ We,
                           float* __restrict__ bu) {
    int hf = threadIdx.x;  // 64
    int h = hf >> 4, f = hf & 15;
    float s = 0.f;
    for (int c = 0; c < C; c++) s = fmaf(bq[h * C + c], We[(size_t)f * 4 * C + h * C + c], s);
    bu[hf] = s;
}

// concat two bias vectors [n] -> [2n]
__global__ void concat2(const float* __restrict__ a, const float* __restrict__ b,
                        float* __restrict__ o, int n) {
    int i = blockIdx.x * 256 + threadIdx.x;
    if (i < n) o[i] = a[i];
    else if (i < 2 * n) o[i] = b[i - n];
}

// ======================= small-M row GEMM (head) =======================
template <bool RELU>
__global__ __launch_bounds__(256) void gemm_row(const float* __restrict__ A,
                                                const float* __restrict__ B,
                                                const float* __restrict__ bias,
                                                float* __restrict__ C, int N, int K,
                                                int lda, int ldc) {
    int g = blockIdx.x;
    int col = threadIdx.x & 127;
    int half = threadIdx.x >> 7;
    int kh = K >> 1;
    int k0 = half * kh, k1 = k0 + kh;
    const float* a = A + (size_t)g * lda;
    float s0 = 0.f, s1 = 0.f, s2 = 0.f, s3 = 0.f;
    int kk = k0;
    for (; kk + 4 <= k1; kk += 4) {
        s0 = fmaf(a[kk], B[(size_t)kk * N + col], s0);
        s1 = fmaf(a[kk + 1], B[(size_t)(kk + 1) * N + col], s1);
        s2 = fmaf(a[kk + 2], B[(size_t)(kk + 2) * N + col], s2);
        s3 = fmaf(a[kk + 3], B[(size_t)(kk + 3) * N + col], s3);
    }
    for (; kk < k1; kk++) s0 = fmaf(a[kk], B[(size_t)kk * N + col], s0);
    float s = (s0 + s1) + (s2 + s3);
    __shared__ float red[128];
    if (half == 1) red[col] = s;
    __syncthreads();
    if (half == 0) {
        s += red[col] + bias[col];
        if (RELU) s = fmaxf(s, 0.f);
        C[(size_t)g * ldc + col] = s;
    }
}

// ======================= split-K row GEMM (fc1, K=2176) =======================
__global__ __launch_bounds__(256) void gemm_row_part(const float* __restrict__ A,
                                                     const float* __restrict__ B,
                                                     float* __restrict__ P, int K,
                                                     int lda, int chunk) {
    int g = blockIdx.x, s = blockIdx.y;
    int col = threadIdx.x & 127, half = threadIdx.x >> 7;
    int kb = s * chunk + half * (chunk >> 1);
    int ke = min(kb + (chunk >> 1), K);
    const float* a = A + (size_t)g * lda;
    float s0 = 0.f, s1 = 0.f, s2 = 0.f, s3 = 0.f;
    int kk = kb;
    for (; kk + 4 <= ke; kk += 4) {
        s0 = fmaf(a[kk], B[(size_t)kk * 128 + col], s0);
        s1 = fmaf(a[kk + 1], B[(size_t)(kk + 1) * 128 + col], s1);
        s2 = fmaf(a[kk + 2], B[(size_t)(kk + 2) * 128 + col], s2);
        s3 = fmaf(a[kk + 3], B[(size_t)(kk + 3) * 128 + col], s3);
    }
    for (; kk < ke; kk++) s0 = fmaf(a[kk], B[(size_t)kk * 128 + col], s0);
    float v = (s0 + s1) + (s2 + s3);
    __shared__ float red[128];
    if (half == 1) red[col] = v;
    __syncthreads();
    if (half == 0) P[((size_t)s * 64 + g) * 128 + col] = v + red[col];
}
__global__ __launch_bounds__(128) void gemm_row_reduce(const float* __restrict__ P,
                                                       const float* __restrict__ bias,
                                                       float* __restrict__ C, int nsplit) {
    int g = blockIdx.x, col = threadIdx.x;
    float sum = bias[col];
    for (int s = 0; s < nsplit; s++) sum += P[((size_t)s * 64 + g) * 128 + col];
    C[(size_t)g * 128 + col] = sum;
}

// ======================= conversions =======================
__global__ __launch_bounds__(256) void f2b_vec(const float* __restrict__ in,
                                               short* __restrict__ out, int n4) {
    int i = blockIdx.x * 256 + threadIdx.x;
    if (i >= n4) return;
    float4 v = ((const float4*)in)[i];
    short4 o;
    o.x = f2b1(v.x); o.y = f2b1(v.y); o.z = f2b1(v.z); o.w = f2b1(v.w);
    ((short4*)out)[i] = o;
}
__global__ __launch_bounds__(256) void f2b_T(const float* __restrict__ in,
                                             short* __restrict__ out, int K, int N) {
    __shared__ short tile[32][33];
    int kb = blockIdx.y * 32, nb = blockIdx.x * 32;
    int tx = threadIdx.x & 31, ty = threadIdx.x >> 5;
#pragma unroll
    for (int i = 0; i < 32; i += 8) {
        int kk = kb + ty + i, n = nb + tx;
        if (kk < K && n < N) tile[ty + i][tx] = f2b1(in[(size_t)kk * N + n]);
    }
    __syncthreads();
#pragma unroll
    for (int i = 0; i < 32; i += 8) {
        int n = nb + ty + i, kk = kb + tx;
        if (n < N && kk < K) out[(size_t)n * K + kk] = tile[tx][ty + i];
    }
}
template <int D, int C>
__global__ __launch_bounds__(256) void build_wub(const float* __restrict__ We,
                                                 short* __restrict__ out) {
    int i = blockIdx.x * 256 + threadIdx.x;
    if (i >= D * 64) return;
    int d = i >> 6, hf = i & 63;
    int hp = hf >> 4, f = hf & 15;
    float v = ((d / C) == hp) ? We[(size_t)f * D + d] : 0.f;
    out[i] = f2b1(v);
}

// ======================= CSR build (by dst) =======================
__global__ __launch_bounds__(256) void count_deg(const int* __restrict__ dst,
                                                 int* __restrict__ deg, int E) {
    int e = blockIdx.x * 256 + threadIdx.x;
    if (e < E) atomicAdd(&deg[dst[e]], 1);
}

__global__ __launch_bounds__(1024) void scan_deg(const int* __restrict__ deg,
                                                 int* __restrict__ rs,
                                                 int* __restrict__ cursor, int n) {
    __shared__ int part[1024];
    int t = threadIdx.x;
    int ch = (n + 1023) / 1024;
    int b0 = min(t * ch, n), b1 = min(b0 + ch, n);
    int s = 0;
    for (int i = b0; i < b1; i++) s += deg[i];
    part[t] = s;
    __syncthreads();
    for (int off = 1; off < 1024; off <<= 1) {
        int tmp = (t >= off) ? part[t - off] : 0;
        __syncthreads();
        part[t] += tmp;
        __syncthreads();
    }
    int run = part[t] - s;
    for (int i = b0; i < b1; i++) {
        rs[i] = run;
        cursor[i] = run;
        run += deg[i];
    }
    if (t == 1023) rs[n] = part[1023];
}

__global__ __launch_bounds__(256) void fill_csr(const int* __restrict__ dst,
                                                int* __restrict__ cursor,
                                                int* __restrict__ eids, int E) {
    int e = blockIdx.x * 256 + threadIdx.x;
    if (e < E) {
        int pos = atomicAdd(&cursor[dst[e]], 1);
        eids[pos] = e;
    }
}

// ======================= per-node attention =======================
// q/k/v are rows of stride ld (fused qk|v layout). D = per-tensor width.
template <int C>
__global__ __launch_bounds__(256) void node_alpha(
    const short* __restrict__ q, const short* __restrict__ k, int ld,
    const float* __restrict__ U, const float* __restrict__ ea,
    const int* __restrict__ src, const int* __restrict__ rs,
    const int* __restrict__ eids, float* __restrict__ ab,
    float* __restrict__ den, int Nn) {
    constexpr int D = 4 * C;
    constexpr int P = D / 64;
    int node = (blockIdx.x * 256 + threadIdx.x) >> 6;
    int lane = threadIdx.x & 63;
    if (node >= Nn) return;
    int e0 = rs[node], e1 = rs[node + 1];
    float qr[P];
    const short* qp = q + (size_t)node * ld + lane * P;
#pragma unroll
    for (int j0 = 0; j0 < P; j0 += 8) {
        bf16x8 v = *(const bf16x8*)(qp + j0);
#pragma unroll
        for (int j = 0; j < 8; j++) qr[j0 + j] = b2f(v[j]);
    }
    float Urow = U[(size_t)node * 64 + lane];
    const float rsC = rsqrtf((float)C);
    float m = -3.402823466e38f;
    for (int ii = e0; ii < e1; ii++) {
        int e = eids[ii];
        int s = src[e];
        float val = ea[(size_t)e * 16 + (lane & 15)] * Urow;
        const short* kp = k + (size_t)s * ld + lane * P;
#pragma unroll
        for (int j0 = 0; j0 < P; j0 += 8) {
            bf16x8 kv = *(const bf16x8*)(kp + j0);
#pragma unroll
            for (int j = 0; j < 8; j++) val = fmaf(qr[j0 + j], b2f(kv[j]), val);
        }
#pragma unroll
        for (int off = 1; off < 16; off <<= 1) val += __shfl_xor(val, off);
        val *= rsC;
        if ((lane & 15) == 0) ab[(size_t)ii * 4 + (lane >> 4)] = val;
        m = fmaxf(m, val);
    }
    float dsum = 0.f;
    for (int ii = e0; ii < e1; ii++) {
        float a = ab[(size_t)ii * 4 + (lane >> 4)];
        float ex = __expf(a - m);
        dsum += ex;
        if ((lane & 15) == 0) ab[(size_t)ii * 4 + (lane >> 4)] = ex;
    }
    if ((lane & 15) == 0) den[(size_t)node * 4 + (lane >> 4)] = dsum;
}

template <int C>
__global__ __launch_bounds__(256) void node_scatter(
    const short* __restrict__ v, int ld, const float* __restrict__ ea,
    const int* __restrict__ src, const int* __restrict__ rs,
    const int* __restrict__ eids, const float* __restrict__ ab,
    const float* __restrict__ den, float* __restrict__ hout,
    short* __restrict__ Tb, int Nn) {
    constexpr int D = 4 * C;
    constexpr int P = D / 64;
    int node = (blockIdx.x * 256 + threadIdx.x) >> 6;
    int lane = threadIdx.x & 63;
    if (node >= Nn) return;
    int e0 = rs[node], e1 = rs[node + 1];
    float acc[P] = {};
    float tacc = 0.f;
    for (int ii = e0; ii < e1; ii++) {
        int e = eids[ii];
        int s = src[e];
        float ex = ab[(size_t)ii * 4 + (lane >> 4)];
        tacc = fmaf(ex, ea[(size_t)e * 16 + (lane & 15)], tacc);
        const short* vp = v + (size_t)s * ld + lane * P;
#pragma unroll
        for (int j0 = 0; j0 < P; j0 += 8) {
            bf16x8 t8 = *(const bf16x8*)(vp + j0);
#pragma unroll
            for (int j = 0; j < 8; j++) acc[j0 + j] = fmaf(ex, b2f(t8[j]), acc[j0 + j]);
        }
    }
    float inv = 1.f / (den[(size_t)node * 4 + (lane >> 4)] + 1e-16f);
    Tb[(size_t)node * 64 + lane] = f2b1(tacc * inv);
    float* hp = hout + (size_t)node * D + lane * P;
#pragma unroll
    for (int j = 0; j < P; j += 4) {
        float4 t4 = *(float4*)(hp + j);
        t4.x = fmaf(acc[j], inv, t4.x);
        t4.y = fmaf(acc[j + 1], inv, t4.y);
        t4.z = fmaf(acc[j + 2], inv, t4.z);
        t4.w = fmaf(acc[j + 3], inv, t4.w);
        *(float4*)(hp + j) = t4;
    }
}

// ======================= batch norm =======================
__global__ __launch_bounds__(256) void bn_stats(const float* __restrict__ h,
                                                float* __restrict__ s1,
                                                float* __restrict__ s2, int Nrows,
                                                int D) {
    int col = blockIdx.x * 256 + threadIdx.x;
    int chunk = (Nrows + gridDim.y - 1) / gridDim.y;
    int r0 = blockIdx.y * chunk;
    int r1 = min(r0 + chunk, Nrows);
    float a = 0.f, b = 0.f;
    for (int r = r0; r < r1; r++) {
        float v = h[(size_t)r * D + col];
        a += v;
        b += v * v;
    }
    atomicAdd(&s1[col], a);
    atomicAdd(&s2[col], b);
}
__global__ void bn_finalize(float* __restrict__ s1, float* __restrict__ s2,
                            const float* __restrict__ g, const float* __restrict__ b,
                            int Nrows, int D) {
    int c = blockIdx.x * 256 + threadIdx.x;
    if (c >= D) return;
    float mean = s1[c] / (float)Nrows;
    float var = fmaxf(s2[c] / (float)Nrows - mean * mean, 0.f);
    float scale = g[c] / sqrtf(var + 1e-5f);
    s1[c] = scale;
    s2[c] = b[c] - mean * scale;
}
__global__ __launch_bounds__(256) void bn_apply_relu_f32(float* __restrict__ h,
                                                         const float* __restrict__ scale,
                                                         const float* __restrict__ shift,
                                                         int total4, int D) {
    int i = blockIdx.x * 256 + threadIdx.x;
    if (i >= total4) return;
    float4 v = ((float4*)h)[i];
    int c = (i * 4) % D;
    v.x = fmaxf(fmaf(v.x, scale[c], shift[c]), 0.f);
    v.y = fmaxf(fmaf(v.y, scale[c + 1], shift[c + 1]), 0.f);
    v.z = fmaxf(fmaf(v.z, scale[c + 2], shift[c + 2]), 0.f);
    v.w = fmaxf(fmaf(v.w, scale[c + 3], shift[c + 3]), 0.f);
    ((float4*)h)[i] = v;
}
__global__ __launch_bounds__(256) void bn_apply_relu_b16(const float* __restrict__ h,
                                                         const float* __restrict__ scale,
                                                         const float* __restrict__ shift,
                                                         short* __restrict__ out,
                                                         int total4, int D) {
    int i = blockIdx.x * 256 + threadIdx.x;
    if (i >= total4) return;
    float4 v = ((const float4*)h)[i];
    int c = (i * 4) % D;
    short4 o;
    o.x = f2b1(fmaxf(fmaf(v.x, scale[c], shift[c]), 0.f));
    o.y = f2b1(fmaxf(fmaf(v.y, scale[c + 1], shift[c + 1]), 0.f));
    o.z = f2b1(fmaxf(fmaf(v.z, scale[c + 2], shift[c + 2]), 0.f));
    o.w = f2b1(fmaxf(fmaf(v.w, scale[c + 3], shift[c + 3]), 0.f));
    ((short4*)out)[i] = o;
}

// ======================= pooling (batch is sorted) =======================
// grid (D/64, GG); block 256 = 64 cols x 4 row-chunks; LDS combine.
__global__ __launch_bounds__(256) void pool_kernel(const float* __restrict__ h,
                                                   const int* __restrict__ batch,
                                                   float* __restrict__ z, int Nrows,
                                                   int D, int ldz) {
    int g = blockIdx.y;
    int cl = threadIdx.x & 63;
    int c = blockIdx.x * 64 + cl;
    int chunk = threadIdx.x >> 6;  // 0..3
    int lo = 0, hi = Nrows;
    while (lo < hi) {
        int m = (lo + hi) >> 1;
        if (batch[m] < g) lo = m + 1; else hi = m;
    }
    int s0 = lo;
    hi = Nrows;
    while (lo < hi) {
        int m = (lo + hi) >> 1;
        if (batch[m] < g + 1) lo = m + 1; else hi = m;
    }
    int s1 = lo;
    int cnt = s1 - s0;
    int per = (cnt + 3) >> 2;
    int r0 = s0 + chunk * per;
    int r1 = min(r0 + per, s1);
    float sum = 0.f, mx = -3.402823466e38f;
    for (int r = r0; r < r1; r++) {
        float v = h[(size_t)r * D + c];
        sum += v;
        mx = fmaxf(mx, v);
    }
    __shared__ float ss[4][64], sm[4][64];
    ss[chunk][cl] = sum;
    sm[chunk][cl] = mx;
    __syncthreads();
    if (chunk == 0) {
#pragma unroll
        for (int j = 1; j < 4; j++) {
            sum += ss[j][cl];
            mx = fmaxf(mx, sm[j][cl]);
        }
        z[(size_t)g * ldz + c] = sum / (float)max(cnt, 1);
        z[(size_t)g * ldz + D + c] = (cnt > 0) ? mx : 0.f;
    }
}

// ======================= tiny MLP head =======================
__global__ __launch_bounds__(128) void bn_small_apply(const float* __restrict__ y,
                                                      const float* __restrict__ g,
                                                      const float* __restrict__ b,
                                                      float* __restrict__ y2) {
    int c = threadIdx.x;
    float m = 0.f;
    for (int r = 0; r < 64; r++) m += y[r * 128 + c];
    m *= (1.f / 64.f);
    float v = 0.f;
    for (int r = 0; r < 64; r++) {
        float d = y[r * 128 + c] - m;
        v += d * d;
    }
    v *= (1.f / 64.f);
    float sc = g[c] / sqrtf(v + 1e-5f);
    float sh = b[c] - m * sc;
    for (int r = 0; r < 64; r++) y2[r * 128 + c] = fmaxf(fmaf(y[r * 128 + c], sc, sh), 0.f);
}
__global__ __launch_bounds__(128) void fc2_small(const float* __restrict__ y2,
                                                 const float* __restrict__ W,
                                                 const float* __restrict__ b,
                                                 float* __restrict__ out) {
    int t = threadIdx.x;
    int g = t >> 1, o = t & 1;
    float s = b[o];
    for (int kk = 0; kk < 128; kk++) s = fmaf(y2[g * 128 + kk], W[kk * 2 + o], s);
    out[g * 2 + o] = s;
}

// ======================= launch =======================
extern "C" void kernel_launch(void* const* d_in, const int* in_sizes, int n_in,
                              void* d_out, int out_size, void* d_ws, size_t ws_size,
                              hipStream_t stream) {
    const float* x     = (const float*)d_in[0];
    const float* ea    = (const float*)d_in[1];
    const float* sol   = (const float*)d_in[2];
    const int*   eidx  = (const int*)d_in[3];
    const int*   batch = (const int*)d_in[4];
    const float* Wq1 = (const float*)d_in[5];  const float* bq1 = (const float*)d_in[6];
    const float* Wk1 = (const float*)d_in[7];  const float* bk1 = (const float*)d_in[8];
    const float* Wv1 = (const float*)d_in[9];  const float* bv1 = (const float*)d_in[10];
    const float* We1 = (const float*)d_in[11];
    const float* Ws1 = (const float*)d_in[12]; const float* bs1 = (const float*)d_in[13];
    const float* g1  = (const float*)d_in[14]; const float* be1 = (const float*)d_in[15];
    const float* Wq2 = (const float*)d_in[16]; const float* bq2 = (const float*)d_in[17];
    const float* Wk2 = (const float*)d_in[18]; const float* bk2 = (const float*)d_in[19];
    const float* Wv2 = (const float*)d_in[20]; const float* bv2 = (const float*)d_in[21];
    const float* We2 = (const float*)d_in[22];
    const float* Ws2 = (const float*)d_in[23]; const float* bs2 = (const float*)d_in[24];
    const float* g2  = (const float*)d_in[25]; const float* be2 = (const float*)d_in[26];
    const float* Wsol = (const float*)d_in[27]; const float* bsol = (const float*)d_in[28];
    const float* Wfc1 = (const float*)d_in[29]; const float* bfc1 = (const float*)d_in[30];
    const float* gf   = (const float*)d_in[31]; const float* bf = (const float*)d_in[32];
    const float* Wfc2 = (const float*)d_in[33]; const float* bfc2 = (const float*)d_in[34];

    const int* srcp = eidx;
    const int* dstp = eidx + EE;

    // ---------------- workspace (peak ~156 MB) ----------------
    char* p = (char*)d_ws;
    auto alloc = [&](size_t bytes) -> char* {
        char* r = p;
        p += (bytes + 255) & ~(size_t)255;
        return r;
    };
    float* R0   = (float*)alloc((size_t)NN * 1024 * 4);  // h1 fp32 -> h2 fp32
    short* h1b  = (short*)alloc((size_t)NN * 512 * 2);
    // qkv region: bufAb and bufBb contiguous -> fused qk rows of stride 2048 (L2)
    short* bufAb = (short*)alloc((size_t)NN * 1024 * 2);
    short* bufBb = (short*)alloc((size_t)NN * 1024 * 2);
    (void)bufBb;
    float* U    = (float*)alloc((size_t)NN * 64 * 4);
    short* Tb   = (short*)alloc((size_t)NN * 64 * 2);
    float* ab   = (float*)alloc((size_t)EE * 4 * 4);
    float* den  = (float*)alloc((size_t)NN * 4 * 4);
    short* wub  = (short*)alloc((size_t)1024 * 64 * 2);
    short* wq1t = (short*)alloc((size_t)512 * 64 * 2);   // wq1t|wk1t contiguous
    short* wk1t = (short*)alloc((size_t)512 * 64 * 2);
    short* wv1t = (short*)alloc((size_t)512 * 64 * 2);
    short* ws1t = (short*)alloc((size_t)512 * 64 * 2);
    short* wq2t = (short*)alloc((size_t)1024 * 512 * 2); // wq2t|wk2t contiguous
    short* wk2t = (short*)alloc((size_t)1024 * 512 * 2);
    short* wv2t = (short*)alloc((size_t)1024 * 512 * 2);
    short* ws2t = (short*)alloc((size_t)1024 * 512 * 2);
    short* xb   = (short*)alloc((size_t)NN * 64 * 2);
    short* wqu1t = (short*)alloc((size_t)64 * 64 * 2);
    short* wqu2t = (short*)alloc((size_t)64 * 512 * 2);
    float* bu1  = (float*)alloc(64 * 4);
    float* bu2  = (float*)alloc(64 * 4);
    float* bqk1 = (float*)alloc(1024 * 4);
    float* bqk2 = (float*)alloc(2048 * 4);
    int* deg    = (int*)alloc((size_t)NN * 4);
    int* cursor = (int*)alloc((size_t)NN * 4);
    int* rs     = (int*)alloc((size_t)(NN + 1) * 4);
    int* eids   = (int*)alloc((size_t)EE * 4);
    float* bnA  = (float*)alloc(1024 * 4);
    float* bnB  = (float*)alloc(1024 * 4);
    float* z  = (float*)alloc((size_t)64 * 2176 * 4);
    float* y  = (float*)alloc((size_t)64 * 128 * 4);
    float* y2 = (float*)alloc((size_t)64 * 128 * 4);
    float* yP = (float*)alloc((size_t)17 * 64 * 128 * 4);
    if ((size_t)(p - (char*)d_ws) > ws_size) return;  // refuse rather than fault

    float* h1 = R0;   // fp32, dead after bn_apply_relu_b16
    float* h2 = R0;   // fp32, live from skip2 onward

    const int GRM = (NN + 127) / 128;       // 118 MFMA row-tiles
    const int GRU = (NN + 255) / 256;       // 59 U-GEMM row-tiles
    const int NWB = (NN * 64 + 255) / 256;  // node-wave blocks
    dim3 blk(256);

    // ---------------- CSR + conversions + weight prep ----------------
    hipMemsetAsync(deg, 0, (size_t)NN * 4, stream);
    count_deg<<<(EE + 255) / 256, blk, 0, stream>>>(dstp, deg, EE);
    scan_deg<<<1, 1024, 0, stream>>>(deg, rs, cursor, NN);
    fill_csr<<<(EE + 255) / 256, blk, 0, stream>>>(dstp, cursor, eids, EE);

    f2b_vec<<<(NN * 64 / 4 + 255) / 256, blk, 0, stream>>>(x, xb, NN * 64 / 4);
    f2b_T<<<dim3(512 / 32, 2), blk, 0, stream>>>(Wq1, wq1t, 64, 512);
    f2b_T<<<dim3(512 / 32, 2), blk, 0, stream>>>(Wk1, wk1t, 64, 512);
    f2b_T<<<dim3(512 / 32, 2), blk, 0, stream>>>(Wv1, wv1t, 64, 512);
    f2b_T<<<dim3(512 / 32, 2), blk, 0, stream>>>(Ws1, ws1t, 64, 512);
    f2b_T<<<dim3(1024 / 32, 512 / 32), blk, 0, stream>>>(Wq2, wq2t, 512, 1024);
    f2b_T<<<dim3(1024 / 32, 512 / 32), blk, 0, stream>>>(Wk2, wk2t, 512, 1024);
    f2b_T<<<dim3(1024 / 32, 512 / 32), blk, 0, stream>>>(Wv2, wv2t, 512, 1024);
    f2b_T<<<dim3(1024 / 32, 512 / 32), blk, 0, stream>>>(Ws2, ws2t, 512, 1024);
    wqu_combine<128, 64><<<(64 * 64 + 255) / 256, blk, 0, stream>>>(Wq1, We1, wqu1t);
    wqu_combine<256, 512><<<(64 * 512 + 255) / 256, blk, 0, stream>>>(Wq2, We2, wqu2t);
    bu_combine<128><<<1, 64, 0, stream>>>(bq1, We1, bu1);
    bu_combine<256><<<1, 64, 0, stream>>>(bq2, We2, bu2);
    concat2<<<(1024 + 255) / 256, blk, 0, stream>>>(bq1, bk1, bqk1, 512);
    concat2<<<(2048 + 255) / 256, blk, 0, stream>>>(bq2, bk2, bqk2, 1024);

    hipMemsetAsync(bnA, 0, 1024 * 4, stream);
    hipMemsetAsync(bnB, 0, 1024 * 4, stream);

    // ---------------- layer 1 (D=512, C=128) ----------------
    // fused q|k: N=1024, rows stride 1024 (q cols 0..511, k cols 512..1023)
    gemm_mfma<true, false, true><<<dim3(8, GRM), blk, 0, stream>>>(xb, wq1t, bqk1, bufAb, NN, 1024, 64, 1024);
    gemm_mfma_n64<<<GRU, blk, 0, stream>>>(xb, wqu1t, bu1, U, NN, 64);  // U1
    node_alpha<128><<<NWB, blk, 0, stream>>>(bufAb, bufAb + 512, 1024, U, ea, srcp, rs, eids, ab, den, NN);
    // v1 into dead q columns (ldc=1024)
    gemm_mfma<true, false, true><<<dim3(4, GRM), blk, 0, stream>>>(xb, wv1t, bv1, bufAb, NN, 512, 64, 1024);
    gemm_mfma<true, false, false><<<dim3(4, GRM), blk, 0, stream>>>(xb, ws1t, bs1, h1, NN, 512, 64, 512);  // skip1
    node_scatter<128><<<NWB, blk, 0, stream>>>(bufAb, 1024, ea, srcp, rs, eids, ab, den, h1, Tb, NN);
    build_wub<512, 128><<<(512 * 64 + 255) / 256, blk, 0, stream>>>(We1, wub);
    gemm_mfma<false, true, false><<<dim3(4, GRM), blk, 0, stream>>>(Tb, wub, nullptr, h1, NN, 512, 64, 512);
    bn_stats<<<dim3(2, 256), blk, 0, stream>>>(h1, bnA, bnB, NN, 512);
    bn_finalize<<<2, blk, 0, stream>>>(bnA, bnB, g1, be1, NN, 512);
    bn_apply_relu_b16<<<NN * 512 / 4 / 256, blk, 0, stream>>>(h1, bnA, bnB, h1b, NN * 512 / 4, 512);

    // ---------------- layer 2 (D=1024, C=256) ----------------
    hipMemsetAsync(bnA, 0, 1024 * 4, stream);
    hipMemsetAsync(bnB, 0, 1024 * 4, stream);
    // fused q|k: N=2048, rows stride 2048 across bufAb||bufBb
    gemm_mfma<true, false, true><<<dim3(16, GRM), blk, 0, stream>>>(h1b, wq2t, bqk2, bufAb, NN, 2048, 512, 2048);
    gemm_mfma_n64<<<GRU, blk, 0, stream>>>(h1b, wqu2t, bu2, U, NN, 512);  // U2
    node_alpha<256><<<NWB, blk, 0, stream>>>(bufAb, bufAb + 1024, 2048, U, ea, srcp, rs, eids, ab, den, NN);
    // v2 into dead q columns (ldc=2048)
    gemm_mfma<true, false, true><<<dim3(8, GRM), blk, 0, stream>>>(h1b, wv2t, bv2, bufAb, NN, 1024, 512, 2048);
    gemm_mfma<true, false, false><<<dim3(8, GRM), blk, 0, stream>>>(h1b, ws2t, bs2, h2, NN, 1024, 512, 1024);  // skip2
    node_scatter<256><<<NWB, blk, 0, stream>>>(bufAb, 2048, ea, srcp, rs, eids, ab, den, h2, Tb, NN);
    build_wub<1024, 256><<<(1024 * 64 + 255) / 256, blk, 0, stream>>>(We2, wub);
    gemm_mfma<false, true, false><<<dim3(8, GRM), blk, 0, stream>>>(Tb, wub, nullptr, h2, NN, 1024, 64, 1024);
    bn_stats<<<dim3(4, 256), blk, 0, stream>>>(h2, bnA, bnB, NN, 1024);
    bn_finalize<<<4, blk, 0, stream>>>(bnA, bnB, g2, be2, NN, 1024);
    bn_apply_relu_f32<<<NN * 1024 / 4 / 256, blk, 0, stream>>>(h2, bnA, bnB, NN * 1024 / 4, 1024);

    // ---------------- head ----------------
    pool_kernel<<<dim3(16, 64), blk, 0, stream>>>(h2, batch, z, NN, 1024, 2176);
    gemm_row<true><<<64, blk, 0, stream>>>(sol, Wsol, bsol, z + 2048, 128, 128, 128, 2176);
    gemm_row_part<<<dim3(64, 17), blk, 0, stream>>>(z, Wfc1, yP, 2176, 2176, 128);
    gemm_row_reduce<<<64, 128, 0, stream>>>(yP, bfc1, y, 17);
    bn_small_apply<<<1, 128, 0, stream>>>(y, gf, bf, y2);
    fc2_small<<<1, 128, 0, stream>>>(y2, Wfc2, bfc2, (float*)d_out);
}